// Round 13
// baseline (276.983 us; speedup 1.0000x reference)
//
#include <hip/hip_runtime.h>
#include <hip/hip_bf16.h>
#include <cstdint>
#include <cstddef>

// Problem constants
#define BB   2
#define SS   2048
#define HIDD 2048
#define HH   16
#define KVH  4
#define DD   128
#define NQKV 5120   // H*2*D + KV*D + KV*D = 4096 + 512 + 512
#define MM   4096   // B*S

typedef unsigned short u16t;
typedef __attribute__((ext_vector_type(8))) short s16x8;
typedef __attribute__((ext_vector_type(4))) short s16x4;
typedef __attribute__((ext_vector_type(4))) float f32x4;

__device__ __forceinline__ u16t f2bf(float f) {
  unsigned u = __float_as_uint(f);
  u += 0x7fffu + ((u >> 16) & 1u);
  return (u16t)(u >> 16);
}
__device__ __forceinline__ float bf2f(u16t h) {
  return __uint_as_float(((unsigned)h) << 16);
}
__device__ __forceinline__ void gload_lds16(const void* g, void* l) {
  __builtin_amdgcn_global_load_lds(
      (const __attribute__((address_space(1))) unsigned int*)g,
      (__attribute__((address_space(3))) unsigned int*)l, 16, 0, 0);
}
__device__ __forceinline__ unsigned cvtpk_bf16(float lo, float hi) {
  unsigned r;
  asm("v_cvt_pk_bf16_f32 %0, %1, %2" : "=v"(r) : "v"(lo), "v"(hi));
  return r;
}
__device__ __forceinline__ f32x4 fmax4(f32x4 a, f32x4 b) {
  f32x4 r;
  r[0] = fmaxf(a[0], b[0]); r[1] = fmaxf(a[1], b[1]);
  r[2] = fmaxf(a[2], b[2]); r[3] = fmaxf(a[3], b[3]);
  return r;
}
// counted vmcnt via literal asm (compiler-ordering fence through "memory" clobber).
// Round-11 lesson: __builtin_amdgcn_s_waitcnt is NOT a memory fence -> race.
template <int N>
__device__ __forceinline__ void waitvm() {
  static_assert(N == 0 || N == 3 || N == 4 || N == 6 || N == 8, "add literal");
  if constexpr (N == 0)      asm volatile("s_waitcnt vmcnt(0)" ::: "memory");
  else if constexpr (N == 3) asm volatile("s_waitcnt vmcnt(3)" ::: "memory");
  else if constexpr (N == 4) asm volatile("s_waitcnt vmcnt(4)" ::: "memory");
  else if constexpr (N == 6) asm volatile("s_waitcnt vmcnt(6)" ::: "memory");
  else if constexpr (N == 8) asm volatile("s_waitcnt vmcnt(8)" ::: "memory");
}

// ----------------------------------------- fused prep: cast hidden + transpose-cast all weights
__global__ __launch_bounds__(256) void prep_all(const float* __restrict__ hidden,
                                                const float* __restrict__ Wq,
                                                const float* __restrict__ Wk,
                                                const float* __restrict__ Wv,
                                                const float* __restrict__ Wo,
                                                u16t* __restrict__ Xb,
                                                u16t* __restrict__ Wt,
                                                u16t* __restrict__ Wot) {
  __shared__ float lds[64 * 65];
  int bid = blockIdx.x;
  int t = threadIdx.x;
  if (bid < 8192) {
    size_t i = ((size_t)bid * 256 + t) * 4;
    f32x4 v = *(const f32x4*)(hidden + i);
    s16x4 o;
    o[0] = (short)f2bf(v[0]); o[1] = (short)f2bf(v[1]);
    o[2] = (short)f2bf(v[2]); o[3] = (short)f2bf(v[3]);
    *(s16x4*)(Xb + i) = o;
    return;
  }
  bid -= 8192;
  const float* src; u16t* dst; int N;
  if (bid < 2048)      { src = Wq; dst = Wt;                         N = 4096; }
  else if (bid < 2304) { src = Wk; dst = Wt + (size_t)4096 * HIDD;   N = 512;  bid -= 2048; }
  else if (bid < 2560) { src = Wv; dst = Wt + (size_t)4608 * HIDD;   N = 512;  bid -= 2304; }
  else                 { src = Wo; dst = Wot;                        N = 2048; bid -= 2560; }
  const int ktiles = HIDD / 64; // 32
  int n0 = (bid / ktiles) << 6;
  int k0 = (bid % ktiles) << 6;
#pragma unroll
  for (int i = 0; i < 16; i++) {
    int idx = i * 256 + t;
    int r = idx >> 6, c = idx & 63;
    lds[c * 65 + r] = src[(size_t)(k0 + r) * N + n0 + c];
  }
  __syncthreads();
#pragma unroll
  for (int i = 0; i < 16; i++) {
    int idx = i * 256 + t;
    int rr = idx >> 6, kk = idx & 63;
    dst[(size_t)(n0 + rr) * HIDD + k0 + kk] = f2bf(lds[rr * 65 + kk]);
  }
}

// ---------------------------------------------------------------- 256xBN 8-phase bf16 GEMM
// C(M x n, CT; row-stride N) = A(MxK) @ Bt(nxK)^T.  BK=64 (2 K-halves of 32).
// BN in {256,128}. grid = (M/256)*(n/BN); M/256 must be 16.
__device__ __forceinline__ s16x8 ldsfrag(const char* half, int r, int g) {
  return *(const s16x8*)(half + r * 64 + ((g ^ ((r >> 1) & 3)) << 4));
}
template <int NL>
__device__ __forceinline__ void stage_half(char* ldsbase, const u16t* gbase,
                                           int K, int kcol, int tid) {
#pragma unroll
  for (int i = 0; i < NL; i++) {
    int o16 = i * 512 + tid;
    int r = o16 >> 2;
    int cs = (o16 & 3) ^ ((r >> 1) & 3);
    gload_lds16(gbase + (size_t)r * K + kcol + cs * 8, ldsbase + o16 * 16);
  }
}

template <int BN, typename CT>
__global__ __launch_bounds__(512, 2) void gemm8(const u16t* __restrict__ A,
                                                const u16t* __restrict__ Bt,
                                                CT* __restrict__ C,
                                                int M, int N, int K) {
  constexpr int NLB = BN / 128;            // B-half loads/thread
  constexpr int AHALF = 16384, ASLOT = 32768;
  constexpr int BHALF = BN * 64, BSLOT = 2 * BHALF;
  constexpr int PAIR = 2 + NLB;            // loads per (A,B) half-tile pair
  constexpr int NI = BN / 64;              // B frags per wave
  extern __shared__ __align__(16) char lds[];
  char* As = lds;
  char* Bs = lds + 2 * ASLOT;
  int tid = threadIdx.x, lane = tid & 63, w = tid >> 6;
  int wm = w >> 2, wn = w & 3;
  int cpx = gridDim.x >> 3;                       // grid % 8 == 0
  int wgid = (blockIdx.x & 7) * cpx + (blockIdx.x >> 3);
  int bm = wgid & 15, bn = wgid >> 4;             // M/256 == 16
  int m0 = bm << 8, n0 = bn * BN;
  const u16t* Ag = A + (size_t)m0 * K;
  const u16t* Bg = Bt + (size_t)n0 * K;
  const int NT = K >> 6;

  stage_half<2>(As, Ag, K, 0, tid);
  stage_half<NLB>(Bs, Bg, K, 0, tid);
  stage_half<2>(As + AHALF, Ag, K, 32, tid);
  stage_half<NLB>(Bs + BHALF, Bg, K, 32, tid);
  stage_half<2>(As + ASLOT, Ag, K, 64, tid);
  stage_half<NLB>(Bs + BSLOT, Bg, K, 64, tid);
  waitvm<2 * PAIR>();
  __builtin_amdgcn_s_barrier();

  const f32x4 fz = {0.f, 0.f, 0.f, 0.f};
  f32x4 acc[8][NI];
#pragma unroll
  for (int i = 0; i < 8; i++)
#pragma unroll
    for (int j = 0; j < NI; j++) acc[i][j] = fz;
  s16x8 afr[4], bfr[NI];
  int g = lane >> 4;
  int rA = (lane & 15) + wm * 128;
  int rB = (lane & 15) + wn * (BN / 4);

  for (int kt = 0; kt < NT; kt++) {
    int cur = kt & 1;
    char* Acur = As + cur * ASLOT;
    char* Bcur = Bs + cur * BSLOT;
    char* Anxt = As + (cur ^ 1) * ASLOT;
    char* Bnxt = Bs + (cur ^ 1) * BSLOT;
    // ---- phase 0: (kk0, mh0); stage Ah1(kt+1)
#pragma unroll
    for (int ni = 0; ni < NI; ni++) bfr[ni] = ldsfrag(Bcur, rB + ni * 16, g);
#pragma unroll
    for (int mi = 0; mi < 4; mi++) afr[mi] = ldsfrag(Acur, rA + mi * 16, g);
    if (kt + 1 < NT) stage_half<2>(Anxt + AHALF, Ag, K, (kt + 1) * 64 + 32, tid);
    __builtin_amdgcn_s_barrier();
    asm volatile("s_waitcnt lgkmcnt(0)" ::: "memory");
    __builtin_amdgcn_s_setprio(1);
#pragma unroll
    for (int mi = 0; mi < 4; mi++)
#pragma unroll
      for (int ni = 0; ni < NI; ni++)
        acc[mi][ni] = __builtin_amdgcn_mfma_f32_16x16x32_bf16(afr[mi], bfr[ni], acc[mi][ni], 0, 0, 0);
    __builtin_amdgcn_s_setprio(0);
    __builtin_amdgcn_s_barrier();
    // ---- phase 1: (kk0, mh1); stage Bh1(kt+1); counted wait
#pragma unroll
    for (int mi = 0; mi < 4; mi++) afr[mi] = ldsfrag(Acur, rA + 64 + mi * 16, g);
    if (kt + 1 < NT) stage_half<NLB>(Bnxt + BHALF, Bg, K, (kt + 1) * 64 + 32, tid);
    __builtin_amdgcn_s_barrier();
    asm volatile("s_waitcnt lgkmcnt(0)" ::: "memory");
    __builtin_amdgcn_s_setprio(1);
#pragma unroll
    for (int mi = 0; mi < 4; mi++)
#pragma unroll
      for (int ni = 0; ni < NI; ni++)
        acc[4 + mi][ni] = __builtin_amdgcn_mfma_f32_16x16x32_bf16(afr[mi], bfr[ni], acc[4 + mi][ni], 0, 0, 0);
    __builtin_amdgcn_s_setprio(0);
    if (kt + 1 < NT) waitvm<2 * PAIR>();
    else             waitvm<0>();
    __builtin_amdgcn_s_barrier();
    // ---- phase 2: (kk1, mh0); stage Ah0(kt+2)
#pragma unroll
    for (int ni = 0; ni < NI; ni++) bfr[ni] = ldsfrag(Bcur + BHALF, rB + ni * 16, g);
#pragma unroll
    for (int mi = 0; mi < 4; mi++) afr[mi] = ldsfrag(Acur + AHALF, rA + mi * 16, g);
    if (kt + 2 < NT) stage_half<2>(Acur, Ag, K, (kt + 2) * 64, tid);
    __builtin_amdgcn_s_barrier();
    asm volatile("s_waitcnt lgkmcnt(0)" ::: "memory");
    __builtin_amdgcn_s_setprio(1);
#pragma unroll
    for (int mi = 0; mi < 4; mi++)
#pragma unroll
      for (int ni = 0; ni < NI; ni++)
        acc[mi][ni] = __builtin_amdgcn_mfma_f32_16x16x32_bf16(afr[mi], bfr[ni], acc[mi][ni], 0, 0, 0);
    __builtin_amdgcn_s_setprio(0);
    __builtin_amdgcn_s_barrier();
    // ---- phase 3: (kk1, mh1); stage Bh0(kt+2); counted wait
#pragma unroll
    for (int mi = 0; mi < 4; mi++) afr[mi] = ldsfrag(Acur + AHALF, rA + 64 + mi * 16, g);
    if (kt + 2 < NT) stage_half<NLB>(Bcur, Bg, K, (kt + 2) * 64, tid);
    __builtin_amdgcn_s_barrier();
    asm volatile("s_waitcnt lgkmcnt(0)" ::: "memory");
    __builtin_amdgcn_s_setprio(1);
#pragma unroll
    for (int mi = 0; mi < 4; mi++)
#pragma unroll
      for (int ni = 0; ni < NI; ni++)
        acc[4 + mi][ni] = __builtin_amdgcn_mfma_f32_16x16x32_bf16(afr[mi], bfr[ni], acc[4 + mi][ni], 0, 0, 0);
    __builtin_amdgcn_s_setprio(0);
    if (kt < NT - 1) {
      if (kt + 2 < NT) waitvm<2 * PAIR>();
      else             waitvm<PAIR>();
    }
    __builtin_amdgcn_s_barrier();
  }
#pragma unroll
  for (int mi = 0; mi < 8; mi++)
#pragma unroll
    for (int ni = 0; ni < NI; ni++) {
      int row0 = m0 + wm * 128 + mi * 16 + ((lane >> 4) << 2);
      int col = n0 + wn * (BN / 4) + ni * 16 + (lane & 15);
#pragma unroll
      for (int j = 0; j < 4; j++) {
        if constexpr (sizeof(CT) == 2)
          C[(size_t)(row0 + j) * N + col] = f2bf(acc[mi][ni][j]);
        else
          C[(size_t)(row0 + j) * N + col] = acc[mi][ni][j];
      }
    }
}

// ---------------------------------------------------------------- 128x128 bf16 GEMM (m97 structure)
template <typename CT>
__global__ __launch_bounds__(256) void gemm_bt(const u16t* __restrict__ A,
                                               const u16t* __restrict__ Bt,
                                               CT* __restrict__ C,
                                               int M, int N, int K) {
  __shared__ __align__(16) char As[128 * 64];
  __shared__ __align__(16) char Bs[128 * 64];
  int tid = threadIdx.x;
  int lane = tid & 63;
  int w = tid >> 6;
  int cpx = gridDim.x >> 3;
  int wgid = ((int)blockIdx.x & 7) * cpx + ((int)blockIdx.x >> 3);
  int mtiles = M >> 7;
  int bm = wgid % mtiles;
  int bn = wgid / mtiles;
  int m0 = bm << 7, n0 = bn << 7;
  int wr = (w >> 1) * 64, wc = (w & 1) * 64;

  const f32x4 fz = {0.f, 0.f, 0.f, 0.f};
  f32x4 acc[4][4];
#pragma unroll
  for (int i = 0; i < 4; i++)
#pragma unroll
    for (int j = 0; j < 4; j++) acc[i][j] = fz;

  for (int k0 = 0; k0 < K; k0 += 32) {
    __syncthreads();
#pragma unroll
    for (int i = 0; i < 2; i++) {
      int idx = i * 256 + tid;
      int r = idx >> 2, c = idx & 3;
      int csrc = c ^ ((r >> 1) & 3);
      gload_lds16(A + (size_t)(m0 + r) * K + k0 + csrc * 8, As + idx * 16);
      gload_lds16(Bt + (size_t)(n0 + r) * K + k0 + csrc * 8, Bs + idx * 16);
    }
    __syncthreads();
    s16x8 af[4], bf[4];
    int g = lane >> 4;
#pragma unroll
    for (int mi = 0; mi < 4; mi++) {
      int r = wr + mi * 16 + (lane & 15);
      af[mi] = *(const s16x8*)(As + r * 64 + ((g ^ ((r >> 1) & 3)) << 4));
    }
#pragma unroll
    for (int ni = 0; ni < 4; ni++) {
      int r = wc + ni * 16 + (lane & 15);
      bf[ni] = *(const s16x8*)(Bs + r * 64 + ((g ^ ((r >> 1) & 3)) << 4));
    }
#pragma unroll
    for (int mi = 0; mi < 4; mi++)
#pragma unroll
      for (int ni = 0; ni < 4; ni++)
        acc[mi][ni] = __builtin_amdgcn_mfma_f32_16x16x32_bf16(af[mi], bf[ni], acc[mi][ni], 0, 0, 0);
  }
#pragma unroll
  for (int mi = 0; mi < 4; mi++)
#pragma unroll
    for (int ni = 0; ni < 4; ni++) {
      int row0 = m0 + wr + mi * 16 + ((lane >> 4) << 2);
      int col = n0 + wc + ni * 16 + (lane & 15);
#pragma unroll
      for (int j = 0; j < 4; j++) {
        if constexpr (sizeof(CT) == 2)
          C[(size_t)(row0 + j) * N + col] = f2bf(acc[mi][ni][j]);
        else
          C[(size_t)(row0 + j) * N + col] = acc[mi][ni][j];
      }
    }
}

// ------------------------------------------------- fused RMSNorm + RoPE for Q and K
__global__ __launch_bounds__(256) void qk_norm_rope(const u16t* __restrict__ Cqkv,
                                                    const float* __restrict__ rope,
                                                    const float* __restrict__ qw,
                                                    const float* __restrict__ kw,
                                                    u16t* __restrict__ Qb,   // (B,H,S,D)
                                                    u16t* __restrict__ Kb,   // (B,KV,S,D)
                                                    u16t* __restrict__ Gs,   // (B,S,H*D)
                                                    float* __restrict__ present) {
  int wid = blockIdx.x * 4 + (threadIdx.x >> 6);
  int lane = threadIdx.x & 63;
  const int NQ = BB * SS * HH; // 65536
  if (wid < NQ) {
    int b = wid >> 15;          // S*H = 32768
    int rem = wid & 32767;
    int s = rem >> 4, h = rem & 15;
    const u16t* base = Cqkv + (size_t)(b * SS + s) * NQKV + h * 256;
    float xlo = bf2f(base[lane]), xhi = bf2f(base[64 + lane]);
    float ss = xlo * xlo + xhi * xhi;
    ss += __shfl_xor(ss, 1);  ss += __shfl_xor(ss, 2);  ss += __shfl_xor(ss, 4);
    ss += __shfl_xor(ss, 8);  ss += __shfl_xor(ss, 16); ss += __shfl_xor(ss, 32);
    float r = rsqrtf(ss * (1.f / 128.f) + 1e-6f);
    float qlo = xlo * r * (1.f + qw[lane]);
    float qhi = xhi * r * (1.f + qw[64 + lane]);
    const float* cs = rope + (size_t)s * 256;
    float clo = cs[lane], chi = cs[64 + lane];
    float slo = cs[128 + lane], shi = cs[192 + lane];
    // 1/sqrt(128) * log2(e): scores land in log2 units -> exp2 in attention
    const float SC = 0.08838834764831845f * 1.4426950408889634f;
    float olo = (qlo * clo - qhi * slo) * SC;
    float ohi = (qhi * chi + qlo * shi) * SC;
    size_t qoff = (((size_t)b * HH + h) * SS + s) * DD;
    Qb[qoff + lane] = f2bf(olo);
    Qb[qoff + 64 + lane] = f2bf(ohi);
    float glo = bf2f(base[128 + lane]), ghi = bf2f(base[192 + lane]);
    size_t goff = ((size_t)(b * SS + s)) * (HH * DD) + h * DD;
    Gs[goff + lane] = f2bf(1.f / (1.f + __expf(-glo)));
    Gs[goff + 64 + lane] = f2bf(1.f / (1.f + __expf(-ghi)));
  } else {
    int wid2 = wid - NQ;        // (b, s, kv): per b = S*KV = 8192
    int b = wid2 >> 13;
    int rem = wid2 & 8191;
    int s = rem >> 2, kv = rem & 3;
    const u16t* base = Cqkv + (size_t)(b * SS + s) * NQKV + 4096 + kv * 128;
    float xlo = bf2f(base[lane]), xhi = bf2f(base[64 + lane]);
    float ss = xlo * xlo + xhi * xhi;
    ss += __shfl_xor(ss, 1);  ss += __shfl_xor(ss, 2);  ss += __shfl_xor(ss, 4);
    ss += __shfl_xor(ss, 8);  ss += __shfl_xor(ss, 16); ss += __shfl_xor(ss, 32);
    float r = rsqrtf(ss * (1.f / 128.f) + 1e-6f);
    float klo = xlo * r * (1.f + kw[lane]);
    float khi = xhi * r * (1.f + kw[64 + lane]);
    const float* cs = rope + (size_t)s * 256;
    float clo = cs[lane], chi = cs[64 + lane];
    float slo = cs[128 + lane], shi = cs[192 + lane];
    float olo = klo * clo - khi * slo;
    float ohi = khi * chi + klo * shi;
    size_t koff = (((size_t)b * KVH + kv) * SS + s) * DD;
    Kb[koff + lane] = f2bf(olo);
    Kb[koff + 64 + lane] = f2bf(ohi);
    size_t poff = (((size_t)(b * 2 * KVH + kv)) * SS + s) * DD;
    present[poff + lane] = olo;
    present[poff + 64 + lane] = ohi;
  }
}

// ------------------------------------------------- V: present write + V^T bf16 (B,KV,D,S)
__global__ __launch_bounds__(256) void v_write(const u16t* __restrict__ Cqkv,
                                               float* __restrict__ present,
                                               u16t* __restrict__ Vtb) {
  __shared__ float lds[128 * 65];
  int t = threadIdx.x;
  int b = blockIdx.x >> 7;
  int kv = (blockIdx.x >> 5) & 3;
  int s0 = (blockIdx.x & 31) << 6;
#pragma unroll
  for (int i = 0; i < 32; i++) {
    int idx = i * 256 + t;
    int sp = idx >> 7, d = idx & 127;
    float v = bf2f(Cqkv[(size_t)(b * SS + s0 + sp) * NQKV + 4608 + kv * 128 + d]);
    present[(((size_t)(b * 2 * KVH + KVH + kv)) * SS + s0 + sp) * DD + d] = v;
    lds[d * 65 + sp] = v;
  }
  __syncthreads();
#pragma unroll
  for (int i = 0; i < 8; i++) {
    int d = i * 16 + (t >> 4);
    int sp = (t & 15) * 4;
    s16x4 pk;
    pk[0] = (short)f2bf(lds[d * 65 + sp + 0]);
    pk[1] = (short)f2bf(lds[d * 65 + sp + 1]);
    pk[2] = (short)f2bf(lds[d * 65 + sp + 2]);
    pk[3] = (short)f2bf(lds[d * 65 + sp + 3]);
    *(s16x4*)(Vtb + ((size_t)(b * KVH + kv) * DD + d) * SS + s0 + sp) = pk;
  }
}

// ---------------------------------------------------------------- flash attention v6
// 8-wave blocks, QBLK=128 (wave w owns rows qt*128 + w*16 ..+15), KVBLK=64.
// One K/V stage + drain serves 128 q-rows (2x amortization vs v5.1).
// Paired q-blocks {15-p, p} -> (32-2p)+(2p+2) = 34 tiles/block, all 256 blocks
// identical = exactly 1 block/CU. LDS 80KB (Ks/Vs dbuf 64K + P 16K).
// Inner math identical to v5.1 (swapped QK^T, in-register softmax, hoisted offs).
// Causal: tiles 0..2qt+1; mask kglob>qglob for kt >= 2qt (waves 0-3 fully masked
// at kt=2qt+1 -> P=0, harmless; tile 0 never fully masked so mrun stays finite).
__global__ __launch_bounds__(512, 2) void attn_kernel(const u16t* __restrict__ Qb,   // (B,H,S,D) pre-scaled
                                                      const u16t* __restrict__ Kb,   // (B,KV,S,D)
                                                      const u16t* __restrict__ Vtb,  // (B,KV,D,S)
                                                      const u16t* __restrict__ Gs,   // (B,S,H*D)
                                                      u16t* __restrict__ AttG) {     // (B,S,H*D)
  __shared__ __align__(16) char Ks[2 * 16384];  // 64 rows x 256B, chunk xor (r&7)
  __shared__ __align__(16) char Vs[2 * 16384];  // V^T: 128 rows x 128B, chunk xor (d&7)
  __shared__ __align__(16) char Ps[8 * 2048];   // per-wave P: [q:16][k-granule xor (q&7)]

  int tid = threadIdx.x, lane = tid & 63, w = tid >> 6;   // w in 0..7
  int x = blockIdx.x & 7;          // XCD grouping: each XCD owns one (b,kv)
  int b = x >> 2, kv = x & 3;
  int rr = blockIdx.x >> 3;        // 0..31
  int h = kv * 4 + (rr & 3);
  int p = rr >> 2;                 // 0..7: pair {15-p, p}

  const u16t* Kbase = Kb + (((size_t)(b * KVH + kv)) * SS) * DD;
  const u16t* Vbase = Vtb + (((size_t)(b * KVH + kv)) * DD) * SS;

  auto stageK = [&](int kt, int buf) {     // 16KB, 512 thr x 16B x 2
#pragma unroll
    for (int i = 0; i < 2; i++) {
      int idx = i * 512 + tid;
      int r_ = idx >> 4, c_ = idx & 15;
      gload_lds16(Kbase + (size_t)(kt * 64 + r_) * DD + (c_ ^ (r_ & 7)) * 8,
                  Ks + buf * 16384 + idx * 16);
    }
  };
  auto stageV = [&](int kt, int buf) {     // 16KB
#pragma unroll
    for (int i = 0; i < 2; i++) {
      int idx = i * 512 + tid;
      int r_ = idx >> 3, c_ = idx & 7;
      gload_lds16(Vbase + (size_t)r_ * SS + kt * 64 + (c_ ^ (r_ & 7)) * 8,
                  Vs + buf * 16384 + idx * 16);
    }
  };

  const f32x4 fz = {0.f, 0.f, 0.f, 0.f};
  int g = lane >> 4;
  int q15 = lane & 15;
  int q7 = q15 & 7;
  char* pq = Ps + w * 2048 + q15 * 128;   // this lane's q-row in P
  int cur = 0;

  // ---- hoisted LDS offsets (loop-invariant; live in VGPRs)
  int ka[4][4];     // K-read: row ni*16+q15, chunk (ks*4+g)^q7
#pragma unroll
  for (int ni = 0; ni < 4; ni++)
#pragma unroll
    for (int ks = 0; ks < 4; ks++)
      ka[ni][ks] = (ni * 16 + q15) * 256 + (((ks * 4 + g) ^ q7) << 4);
  int va[2][8];     // V-read: row f*16+q15, chunk (ks2*4+g)^q7
#pragma unroll
  for (int ks2 = 0; ks2 < 2; ks2++)
#pragma unroll
    for (int f = 0; f < 8; f++)
      va[ks2][f] = (f * 16 + q15) * 128 + (((ks2 * 4 + g) ^ q7) << 4);
  int pr_[2];       // P-read offsets within pq
#pragma unroll
  for (int ks2 = 0; ks2 < 2; ks2++) pr_[ks2] = ((ks2 * 4 + g) ^ q7) << 4;
  int pw_[4];       // P-write offsets within pq
#pragma unroll
  for (int ni = 0; ni < 4; ni++)
    pw_[ni] = (((ni * 2 + (g >> 1)) ^ q7) << 4) + ((g & 1) << 3);

  // prologue: stage tile 0 of segment 0 into buffer 0
  stageK(0, 0);
  stageV(0, 0);

  for (int seg = 0; seg < 2; seg++) {
    int qt = (seg == 0) ? (15 - p) : p;          // q-block of 128 rows
    const int nkt = 2 * qt + 2;
    const u16t* Qbase = Qb + (((size_t)(b * HH + h)) * SS + qt * 128) * DD;
    s16x8 qf[4];
    {
      const u16t* qrow = Qbase + (size_t)(w * 16 + q15) * DD + g * 8;
#pragma unroll
      for (int ks = 0; ks < 4; ks++) qf[ks] = *(const s16x8*)(qrow + ks * 32);
    }
    f32x4 acco[8];
#pragma unroll
    for (int f = 0; f < 8; f++) acco[f] = fz;
    float mrun = -INFINITY, lrun = 0.f;

    if (seg == 0) {
      asm volatile("s_waitcnt vmcnt(0)" ::: "memory");
      __builtin_amdgcn_s_barrier();
    }

    for (int kt = 0; kt < nkt; kt++) {
      bool havenext = (kt + 1 < nkt) || (seg == 0);
      if (havenext) {
        int nk = (kt + 1 < nkt) ? (kt + 1) : 0;   // next tile, or seg1's tile 0
        stageK(nk, cur ^ 1);
        stageV(nk, cur ^ 1);
      }
      const char* kc = Ks + (cur << 14);
      const char* vc = Vs + (cur << 14);
      // ---- swapped QK^T: accs[ni][j] = S[q = lane&15][k = ni*16+g*4+j]
      f32x4 accs[4];
#pragma unroll
      for (int ni = 0; ni < 4; ni++) accs[ni] = fz;
#pragma unroll
      for (int ni = 0; ni < 4; ni++)
#pragma unroll
        for (int ks = 0; ks < 4; ks++) {
          s16x8 bfk = *(const s16x8*)(kc + ka[ni][ks]);
          accs[ni] = __builtin_amdgcn_mfma_f32_16x16x32_bf16(bfk, qf[ks], accs[ni], 0, 0, 0);
        }
      if (kt >= 2 * qt) {                    // diagonal k-tiles
        int ql = qt * 128 + w * 16 + q15;
#pragma unroll
        for (int ni = 0; ni < 4; ni++)
#pragma unroll
          for (int j = 0; j < 4; j++) {
            int kl = kt * 64 + ni * 16 + (g << 2) + j;
            if (kl > ql) accs[ni][j] = -1e30f;
          }
      }
      // ---- per-lane softmax (q = lane&15; 4 lanes/q combine via 2 shuffles)
      f32x4 m4 = fmax4(fmax4(accs[0], accs[1]), fmax4(accs[2], accs[3]));
      float mt = fmaxf(fmaxf(m4[0], m4[1]), fmaxf(m4[2], m4[3]));
      mt = fmaxf(mt, __shfl_xor(mt, 16));
      mt = fmaxf(mt, __shfl_xor(mt, 32));
      float mnew = fmaxf(mrun, mt);
      float alpha = __builtin_amdgcn_exp2f(mrun - mnew);
      mrun = mnew;
#pragma unroll
      for (int ni = 0; ni < 4; ni++)
#pragma unroll
        for (int j = 0; j < 4; j++)
          accs[ni][j] = __builtin_amdgcn_exp2f(accs[ni][j] - mnew);
      f32x4 s4 = (accs[0] + accs[1]) + (accs[2] + accs[3]);
      float rs = (s4[0] + s4[1]) + (s4[2] + s4[3]);
      rs += __shfl_xor(rs, 16);
      rs += __shfl_xor(rs, 32);
      lrun = lrun * alpha + rs;
      // broadcast alpha to acco's q layout (rows q = g*4+j)
      float ar[4];
#pragma unroll
      for (int j = 0; j < 4; j++) ar[j] = __shfl(alpha, (g << 2) + j);
#pragma unroll
      for (int f = 0; f < 8; f++)
#pragma unroll
        for (int j = 0; j < 4; j++) acco[f][j] *= ar[j];

      // ---- P pack (bf16 pairs along k) -> b64 LDS stores
#pragma unroll
      for (int ni = 0; ni < 4; ni++) {
        uint2 pk;
        pk.x = cvtpk_bf16(accs[ni][0], accs[ni][1]);
        pk.y = cvtpk_bf16(accs[ni][2], accs[ni][3]);
        *(uint2*)(pq + pw_[ni]) = pk;
      }
      // ---- PV
#pragma unroll
      for (int ks2 = 0; ks2 < 2; ks2++) {
        s16x8 pa = *(const s16x8*)(pq + pr_[ks2]);
#pragma unroll
        for (int f = 0; f < 8; f++) {
          s16x8 vf = *(const s16x8*)(vc + va[ks2][f]);
          acco[f] = __builtin_amdgcn_mfma_f32_16x16x32_bf16(pa, vf, acco[f], 0, 0, 0);
        }
      }
      // ---- tile boundary: next tile staged, current reads done
      if (havenext) {
        asm volatile("s_waitcnt vmcnt(0)" ::: "memory");
        __builtin_amdgcn_s_barrier();
        cur ^= 1;
      }
    }
    // ---- segment epilogue: gate + store (lrun broadcast to acco layout)
    float lr[4];
#pragma unroll
    for (int j = 0; j < 4; j++) lr[j] = __shfl(lrun, (g << 2) + j);
#pragma unroll
    for (int f = 0; f < 8; f++) {
      int d = f * 16 + q15;
#pragma unroll
      for (int j = 0; j < 4; j++) {
        int srow = qt * 128 + w * 16 + (g << 2) + j;
        float o = acco[f][j] / lr[j];
        size_t off = ((size_t)b * SS + srow) * (HH * DD) + h * DD + d;
        float gt = bf2f(Gs[off]);
        AttG[off] = f2bf(o * gt);
      }
    }
  }
}

// ---------------------------------------------------------------- launcher
extern "C" void kernel_launch(void* const* d_in, const int* in_sizes, int n_in,
                              void* d_out, int out_size, void* d_ws, size_t ws_size,
                              hipStream_t stream) {
  const float* hidden = (const float*)d_in[0];
  const float* rope   = (const float*)d_in[2];
  const float* Wq     = (const float*)d_in[5];
  const float* Wk     = (const float*)d_in[6];
  const float* Wv     = (const float*)d_in[7];
  const float* Wo     = (const float*)d_in[8];
  const float* qw     = (const float*)d_in[9];
  const float* kw     = (const float*)d_in[10];
  float* out = (float*)d_out;
  float* present = out + (size_t)BB * SS * HIDD; // 8,388,608

  char* ws = (char*)d_ws;
  u16t* Xb    = (u16t*)(ws);                              // 4096x2048 bf16   16.78MB
  u16t* Wt    = (u16t*)(ws + 16777216);                   // 5120x2048 bf16   20.97MB
  u16t* Wot   = (u16t*)(ws + 37748736);                   // 2048x2048 bf16    8.39MB
  u16t* Cqkv  = (u16t*)(ws + 46137344);                   // 4096x5120 bf16   41.94MB
  u16t* Qb    = (u16t*)(ws + 88080384);                   // (B,H,S,D) bf16   16.78MB
  u16t* Kb    = (u16t*)(ws + 104857600);                  // (B,KV,S,D) bf16   4.19MB
  u16t* Vtb   = (u16t*)(ws + 109051904);                  // (B,KV,D,S) bf16   4.19MB
  u16t* Gs    = (u16t*)(ws + 113246208);                  // (B,S,H*D) bf16   16.78MB
  u16t* AttG  = Xb;  // alias: Xb dead after QKV GEMM; AttG written by attention

  (void)hipFuncSetAttribute(reinterpret_cast<const void*>(gemm8<256, u16t>),
                            hipFuncAttributeMaxDynamicSharedMemorySize, 131072);
  (void)hipFuncSetAttribute(reinterpret_cast<const void*>(gemm8<128, float>),
                            hipFuncAttributeMaxDynamicSharedMemorySize, 98304);

  // 1+2. fused prep: cast hidden + all weight transposes (one launch)
  prep_all<<<8192 + 3584, 256, 0, stream>>>(hidden, Wq, Wk, Wv, Wo, Xb, Wt, Wot);
  // 3a. Q projection (N=4096): 256^2 8-phase, grid 16x16 = 256 = exactly 1 block/CU
  gemm8<256, u16t><<<(MM / 256) * (4096 / 256), 512, 131072, stream>>>(Xb, Wt, Cqkv, MM, NQKV, HIDD);
  // 3b. K+V projection (N=1024): 128^2 m97, grid 32x8 = 256 = exactly 1 block/CU
  gemm_bt<u16t><<<(MM / 128) * (1024 / 128), 256, 0, stream>>>(
      Xb, Wt + (size_t)4096 * HIDD, Cqkv + 4096, MM, NQKV, HIDD);
  // 4. Q/K norm+rope (+present K, +sigmoid gate); V writer (+present V, +V^T)
  qk_norm_rope<<<(BB * SS * (HH + KVH)) / 4, 256, 0, stream>>>(Cqkv, rope, qw, kw, Qb, Kb, Gs, present);
  v_write<<<BB * KVH * (SS / 64), 256, 0, stream>>>(Cqkv, present, Vtb);
  // 5. flash attention v6: 8-wave QBLK=128, shared stage, paired {15-p, p}
  attn_kernel<<<BB * HH * (SS / 256), 512, 0, stream>>>(Qb, Kb, Vtb, Gs, AttG);
  // 6. output projection -> d_out: 256x128 8-phase, grid 16x16 = 256 = 1 block/CU
  gemm8<128, float><<<(MM / 256) * (HIDD / 128), 512, 98304, stream>>>(AttG, Wot, out, MM, HIDD, HIDD);
}

// Round 15
// 265.682 us; speedup vs baseline: 1.0425x; 1.0425x over previous
//
#include <hip/hip_runtime.h>
#include <hip/hip_bf16.h>
#include <cstdint>
#include <cstddef>

// Problem constants
#define BB   2
#define SS   2048
#define HIDD 2048
#define HH   16
#define KVH  4
#define DD   128
#define NQKV 5120   // H*2*D + KV*D + KV*D = 4096 + 512 + 512
#define MM   4096   // B*S

typedef unsigned short u16t;
typedef __attribute__((ext_vector_type(8))) short s16x8;
typedef __attribute__((ext_vector_type(4))) short s16x4;
typedef __attribute__((ext_vector_type(4))) float f32x4;

__device__ __forceinline__ u16t f2bf(float f) {
  unsigned u = __float_as_uint(f);
  u += 0x7fffu + ((u >> 16) & 1u);
  return (u16t)(u >> 16);
}
__device__ __forceinline__ float bf2f(u16t h) {
  return __uint_as_float(((unsigned)h) << 16);
}
__device__ __forceinline__ void gload_lds16(const void* g, void* l) {
  __builtin_amdgcn_global_load_lds(
      (const __attribute__((address_space(1))) unsigned int*)g,
      (__attribute__((address_space(3))) unsigned int*)l, 16, 0, 0);
}
__device__ __forceinline__ unsigned cvtpk_bf16(float lo, float hi) {
  unsigned r;
  asm("v_cvt_pk_bf16_f32 %0, %1, %2" : "=v"(r) : "v"(lo), "v"(hi));
  return r;
}
__device__ __forceinline__ f32x4 fmax4(f32x4 a, f32x4 b) {
  f32x4 r;
  r[0] = fmaxf(a[0], b[0]); r[1] = fmaxf(a[1], b[1]);
  r[2] = fmaxf(a[2], b[2]); r[3] = fmaxf(a[3], b[3]);
  return r;
}
// counted vmcnt via literal asm (compiler-ordering fence through "memory" clobber).
// Round-11/14 lessons: __builtin_amdgcn_s_waitcnt is NOT a memory fence; and
// defer-max (T13) breaks correctness on this pipelined structure -- banned.
template <int N>
__device__ __forceinline__ void waitvm() {
  static_assert(N == 0 || N == 3 || N == 4 || N == 6 || N == 8, "add literal");
  if constexpr (N == 0)      asm volatile("s_waitcnt vmcnt(0)" ::: "memory");
  else if constexpr (N == 3) asm volatile("s_waitcnt vmcnt(3)" ::: "memory");
  else if constexpr (N == 4) asm volatile("s_waitcnt vmcnt(4)" ::: "memory");
  else if constexpr (N == 6) asm volatile("s_waitcnt vmcnt(6)" ::: "memory");
  else if constexpr (N == 8) asm volatile("s_waitcnt vmcnt(8)" ::: "memory");
}

// ----------------------------------------- fused prep: cast hidden + transpose-cast all weights
// blocks [0,4096): cast hidden f32->bf16, 8 elem/thread (s16x8 stores)
// blocks [4096, 4096+3584): 64x64 transpose-cast tiles; stores vectorized s16x8
__global__ __launch_bounds__(256) void prep_all(const float* __restrict__ hidden,
                                                const float* __restrict__ Wq,
                                                const float* __restrict__ Wk,
                                                const float* __restrict__ Wv,
                                                const float* __restrict__ Wo,
                                                u16t* __restrict__ Xb,
                                                u16t* __restrict__ Wt,
                                                u16t* __restrict__ Wot) {
  __shared__ float lds[64 * 65];
  int bid = blockIdx.x;
  int t = threadIdx.x;
  if (bid < 4096) {
    size_t i = ((size_t)bid * 256 + t) * 8;
    f32x4 v0 = *(const f32x4*)(hidden + i);
    f32x4 v1 = *(const f32x4*)(hidden + i + 4);
    s16x8 o;
    o[0] = (short)f2bf(v0[0]); o[1] = (short)f2bf(v0[1]);
    o[2] = (short)f2bf(v0[2]); o[3] = (short)f2bf(v0[3]);
    o[4] = (short)f2bf(v1[0]); o[5] = (short)f2bf(v1[1]);
    o[6] = (short)f2bf(v1[2]); o[7] = (short)f2bf(v1[3]);
    *(s16x8*)(Xb + i) = o;
    return;
  }
  bid -= 4096;
  const float* src; u16t* dst; int N;
  if (bid < 2048)      { src = Wq; dst = Wt;                         N = 4096; }
  else if (bid < 2304) { src = Wk; dst = Wt + (size_t)4096 * HIDD;   N = 512;  bid -= 2048; }
  else if (bid < 2560) { src = Wv; dst = Wt + (size_t)4608 * HIDD;   N = 512;  bid -= 2304; }
  else                 { src = Wo; dst = Wot;                        N = 2048; bid -= 2560; }
  const int ktiles = HIDD / 64; // 32
  int n0 = (bid / ktiles) << 6;
  int k0 = (bid % ktiles) << 6;
#pragma unroll
  for (int i = 0; i < 16; i++) {
    int idx = i * 256 + t;
    int r = idx >> 6, c = idx & 63;
    lds[c * 65 + r] = src[(size_t)(k0 + r) * N + n0 + c];
  }
  __syncthreads();
#pragma unroll
  for (int i = 0; i < 2; i++) {
    int idx = i * 256 + t;
    int rr = idx >> 3, k8 = (idx & 7) * 8;
    s16x8 o;
#pragma unroll
    for (int e = 0; e < 8; e++) o[e] = (short)f2bf(lds[rr * 65 + k8 + e]);
    *(s16x8*)(dst + (size_t)(n0 + rr) * HIDD + k0 + k8) = o;
  }
}

// ---------------------------------------------------------------- 256xBN 8-phase bf16 GEMM
// C(M x n, CT; row-stride N) = A(MxK) @ Bt(nxK)^T.  BK=64 (2 K-halves of 32).
// BN in {256,128}. grid = (M/256)*(n/BN); M/256 must be 16.
__device__ __forceinline__ s16x8 ldsfrag(const char* half, int r, int g) {
  return *(const s16x8*)(half + r * 64 + ((g ^ ((r >> 1) & 3)) << 4));
}
template <int NL>
__device__ __forceinline__ void stage_half(char* ldsbase, const u16t* gbase,
                                           int K, int kcol, int tid) {
#pragma unroll
  for (int i = 0; i < NL; i++) {
    int o16 = i * 512 + tid;
    int r = o16 >> 2;
    int cs = (o16 & 3) ^ ((r >> 1) & 3);
    gload_lds16(gbase + (size_t)r * K + kcol + cs * 8, ldsbase + o16 * 16);
  }
}

template <int BN, typename CT>
__global__ __launch_bounds__(512, 2) void gemm8(const u16t* __restrict__ A,
                                                const u16t* __restrict__ Bt,
                                                CT* __restrict__ C,
                                                int M, int N, int K) {
  constexpr int NLB = BN / 128;            // B-half loads/thread
  constexpr int AHALF = 16384, ASLOT = 32768;
  constexpr int BHALF = BN * 64, BSLOT = 2 * BHALF;
  constexpr int PAIR = 2 + NLB;            // loads per (A,B) half-tile pair
  constexpr int NI = BN / 64;              // B frags per wave
  extern __shared__ __align__(16) char lds[];
  char* As = lds;
  char* Bs = lds + 2 * ASLOT;
  int tid = threadIdx.x, lane = tid & 63, w = tid >> 6;
  int wm = w >> 2, wn = w & 3;
  int cpx = gridDim.x >> 3;                       // grid % 8 == 0
  int wgid = (blockIdx.x & 7) * cpx + (blockIdx.x >> 3);
  int bm = wgid & 15, bn = wgid >> 4;             // M/256 == 16
  int m0 = bm << 8, n0 = bn * BN;
  const u16t* Ag = A + (size_t)m0 * K;
  const u16t* Bg = Bt + (size_t)n0 * K;
  const int NT = K >> 6;

  stage_half<2>(As, Ag, K, 0, tid);
  stage_half<NLB>(Bs, Bg, K, 0, tid);
  stage_half<2>(As + AHALF, Ag, K, 32, tid);
  stage_half<NLB>(Bs + BHALF, Bg, K, 32, tid);
  stage_half<2>(As + ASLOT, Ag, K, 64, tid);
  stage_half<NLB>(Bs + BSLOT, Bg, K, 64, tid);
  waitvm<2 * PAIR>();
  __builtin_amdgcn_s_barrier();

  const f32x4 fz = {0.f, 0.f, 0.f, 0.f};
  f32x4 acc[8][NI];
#pragma unroll
  for (int i = 0; i < 8; i++)
#pragma unroll
    for (int j = 0; j < NI; j++) acc[i][j] = fz;
  s16x8 afr[4], bfr[NI];
  int g = lane >> 4;
  int rA = (lane & 15) + wm * 128;
  int rB = (lane & 15) + wn * (BN / 4);

  for (int kt = 0; kt < NT; kt++) {
    int cur = kt & 1;
    char* Acur = As + cur * ASLOT;
    char* Bcur = Bs + cur * BSLOT;
    char* Anxt = As + (cur ^ 1) * ASLOT;
    char* Bnxt = Bs + (cur ^ 1) * BSLOT;
    // ---- phase 0: (kk0, mh0); stage Ah1(kt+1)
#pragma unroll
    for (int ni = 0; ni < NI; ni++) bfr[ni] = ldsfrag(Bcur, rB + ni * 16, g);
#pragma unroll
    for (int mi = 0; mi < 4; mi++) afr[mi] = ldsfrag(Acur, rA + mi * 16, g);
    if (kt + 1 < NT) stage_half<2>(Anxt + AHALF, Ag, K, (kt + 1) * 64 + 32, tid);
    __builtin_amdgcn_s_barrier();
    asm volatile("s_waitcnt lgkmcnt(0)" ::: "memory");
    __builtin_amdgcn_s_setprio(1);
#pragma unroll
    for (int mi = 0; mi < 4; mi++)
#pragma unroll
      for (int ni = 0; ni < NI; ni++)
        acc[mi][ni] = __builtin_amdgcn_mfma_f32_16x16x32_bf16(afr[mi], bfr[ni], acc[mi][ni], 0, 0, 0);
    __builtin_amdgcn_s_setprio(0);
    __builtin_amdgcn_s_barrier();
    // ---- phase 1: (kk0, mh1); stage Bh1(kt+1); counted wait
#pragma unroll
    for (int mi = 0; mi < 4; mi++) afr[mi] = ldsfrag(Acur, rA + 64 + mi * 16, g);
    if (kt + 1 < NT) stage_half<NLB>(Bnxt + BHALF, Bg, K, (kt + 1) * 64 + 32, tid);
    __builtin_amdgcn_s_barrier();
    asm volatile("s_waitcnt lgkmcnt(0)" ::: "memory");
    __builtin_amdgcn_s_setprio(1);
#pragma unroll
    for (int mi = 0; mi < 4; mi++)
#pragma unroll
      for (int ni = 0; ni < NI; ni++)
        acc[4 + mi][ni] = __builtin_amdgcn_mfma_f32_16x16x32_bf16(afr[mi], bfr[ni], acc[4 + mi][ni], 0, 0, 0);
    __builtin_amdgcn_s_setprio(0);
    if (kt + 1 < NT) waitvm<2 * PAIR>();
    else             waitvm<0>();
    __builtin_amdgcn_s_barrier();
    // ---- phase 2: (kk1, mh0); stage Ah0(kt+2)
#pragma unroll
    for (int ni = 0; ni < NI; ni++) bfr[ni] = ldsfrag(Bcur + BHALF, rB + ni * 16, g);
#pragma unroll
    for (int mi = 0; mi < 4; mi++) afr[mi] = ldsfrag(Acur + AHALF, rA + mi * 16, g);
    if (kt + 2 < NT) stage_half<2>(Acur, Ag, K, (kt + 2) * 64, tid);
    __builtin_amdgcn_s_barrier();
    asm volatile("s_waitcnt lgkmcnt(0)" ::: "memory");
    __builtin_amdgcn_s_setprio(1);
#pragma unroll
    for (int mi = 0; mi < 4; mi++)
#pragma unroll
      for (int ni = 0; ni < NI; ni++)
        acc[mi][ni] = __builtin_amdgcn_mfma_f32_16x16x32_bf16(afr[mi], bfr[ni], acc[mi][ni], 0, 0, 0);
    __builtin_amdgcn_s_setprio(0);
    __builtin_amdgcn_s_barrier();
    // ---- phase 3: (kk1, mh1); stage Bh0(kt+2); counted wait
#pragma unroll
    for (int mi = 0; mi < 4; mi++) afr[mi] = ldsfrag(Acur + AHALF, rA + 64 + mi * 16, g);
    if (kt + 2 < NT) stage_half<NLB>(Bcur, Bg, K, (kt + 2) * 64, tid);
    __builtin_amdgcn_s_barrier();
    asm volatile("s_waitcnt lgkmcnt(0)" ::: "memory");
    __builtin_amdgcn_s_setprio(1);
#pragma unroll
    for (int mi = 0; mi < 4; mi++)
#pragma unroll
      for (int ni = 0; ni < NI; ni++)
        acc[4 + mi][ni] = __builtin_amdgcn_mfma_f32_16x16x32_bf16(afr[mi], bfr[ni], acc[4 + mi][ni], 0, 0, 0);
    __builtin_amdgcn_s_setprio(0);
    if (kt < NT - 1) {
      if (kt + 2 < NT) waitvm<2 * PAIR>();
      else             waitvm<PAIR>();
    }
    __builtin_amdgcn_s_barrier();
  }
#pragma unroll
  for (int mi = 0; mi < 8; mi++)
#pragma unroll
    for (int ni = 0; ni < NI; ni++) {
      int row0 = m0 + wm * 128 + mi * 16 + ((lane >> 4) << 2);
      int col = n0 + wn * (BN / 4) + ni * 16 + (lane & 15);
#pragma unroll
      for (int j = 0; j < 4; j++) {
        if constexpr (sizeof(CT) == 2)
          C[(size_t)(row0 + j) * N + col] = f2bf(acc[mi][ni][j]);
        else
          C[(size_t)(row0 + j) * N + col] = acc[mi][ni][j];
      }
    }
}

// ---------------------------------------------------------------- 128x128 bf16 GEMM (m97 structure)
template <typename CT>
__global__ __launch_bounds__(256) void gemm_bt(const u16t* __restrict__ A,
                                               const u16t* __restrict__ Bt,
                                               CT* __restrict__ C,
                                               int M, int N, int K) {
  __shared__ __align__(16) char As[128 * 64];
  __shared__ __align__(16) char Bs[128 * 64];
  int tid = threadIdx.x;
  int lane = tid & 63;
  int w = tid >> 6;
  int cpx = gridDim.x >> 3;
  int wgid = ((int)blockIdx.x & 7) * cpx + ((int)blockIdx.x >> 3);
  int mtiles = M >> 7;
  int bm = wgid % mtiles;
  int bn = wgid / mtiles;
  int m0 = bm << 7, n0 = bn << 7;
  int wr = (w >> 1) * 64, wc = (w & 1) * 64;

  const f32x4 fz = {0.f, 0.f, 0.f, 0.f};
  f32x4 acc[4][4];
#pragma unroll
  for (int i = 0; i < 4; i++)
#pragma unroll
    for (int j = 0; j < 4; j++) acc[i][j] = fz;

  for (int k0 = 0; k0 < K; k0 += 32) {
    __syncthreads();
#pragma unroll
    for (int i = 0; i < 2; i++) {
      int idx = i * 256 + tid;
      int r = idx >> 2, c = idx & 3;
      int csrc = c ^ ((r >> 1) & 3);
      gload_lds16(A + (size_t)(m0 + r) * K + k0 + csrc * 8, As + idx * 16);
      gload_lds16(Bt + (size_t)(n0 + r) * K + k0 + csrc * 8, Bs + idx * 16);
    }
    __syncthreads();
    s16x8 af[4], bf[4];
    int g = lane >> 4;
#pragma unroll
    for (int mi = 0; mi < 4; mi++) {
      int r = wr + mi * 16 + (lane & 15);
      af[mi] = *(const s16x8*)(As + r * 64 + ((g ^ ((r >> 1) & 3)) << 4));
    }
#pragma unroll
    for (int ni = 0; ni < 4; ni++) {
      int r = wc + ni * 16 + (lane & 15);
      bf[ni] = *(const s16x8*)(Bs + r * 64 + ((g ^ ((r >> 1) & 3)) << 4));
    }
#pragma unroll
    for (int mi = 0; mi < 4; mi++)
#pragma unroll
      for (int ni = 0; ni < 4; ni++)
        acc[mi][ni] = __builtin_amdgcn_mfma_f32_16x16x32_bf16(af[mi], bf[ni], acc[mi][ni], 0, 0, 0);
  }
#pragma unroll
  for (int mi = 0; mi < 4; mi++)
#pragma unroll
    for (int ni = 0; ni < 4; ni++) {
      int row0 = m0 + wr + mi * 16 + ((lane >> 4) << 2);
      int col = n0 + wc + ni * 16 + (lane & 15);
#pragma unroll
      for (int j = 0; j < 4; j++) {
        if constexpr (sizeof(CT) == 2)
          C[(size_t)(row0 + j) * N + col] = f2bf(acc[mi][ni][j]);
        else
          C[(size_t)(row0 + j) * N + col] = acc[mi][ni][j];
      }
    }
}

// ------------------------------------------------- fused RMSNorm + RoPE for Q and K
__global__ __launch_bounds__(256) void qk_norm_rope(const u16t* __restrict__ Cqkv,
                                                    const float* __restrict__ rope,
                                                    const float* __restrict__ qw,
                                                    const float* __restrict__ kw,
                                                    u16t* __restrict__ Qb,   // (B,H,S,D)
                                                    u16t* __restrict__ Kb,   // (B,KV,S,D)
                                                    u16t* __restrict__ Gs,   // (B,S,H*D)
                                                    float* __restrict__ present) {
  int wid = blockIdx.x * 4 + (threadIdx.x >> 6);
  int lane = threadIdx.x & 63;
  const int NQ = BB * SS * HH; // 65536
  if (wid < NQ) {
    int b = wid >> 15;          // S*H = 32768
    int rem = wid & 32767;
    int s = rem >> 4, h = rem & 15;
    const u16t* base = Cqkv + (size_t)(b * SS + s) * NQKV + h * 256;
    float xlo = bf2f(base[lane]), xhi = bf2f(base[64 + lane]);
    float ss = xlo * xlo + xhi * xhi;
    ss += __shfl_xor(ss, 1);  ss += __shfl_xor(ss, 2);  ss += __shfl_xor(ss, 4);
    ss += __shfl_xor(ss, 8);  ss += __shfl_xor(ss, 16); ss += __shfl_xor(ss, 32);
    float r = rsqrtf(ss * (1.f / 128.f) + 1e-6f);
    float qlo = xlo * r * (1.f + qw[lane]);
    float qhi = xhi * r * (1.f + qw[64 + lane]);
    const float* cs = rope + (size_t)s * 256;
    float clo = cs[lane], chi = cs[64 + lane];
    float slo = cs[128 + lane], shi = cs[192 + lane];
    // 1/sqrt(128) * log2(e): scores land in log2 units -> exp2 in attention
    const float SC = 0.08838834764831845f * 1.4426950408889634f;
    float olo = (qlo * clo - qhi * slo) * SC;
    float ohi = (qhi * chi + qlo * shi) * SC;
    size_t qoff = (((size_t)b * HH + h) * SS + s) * DD;
    Qb[qoff + lane] = f2bf(olo);
    Qb[qoff + 64 + lane] = f2bf(ohi);
    float glo = bf2f(base[128 + lane]), ghi = bf2f(base[192 + lane]);
    size_t goff = ((size_t)(b * SS + s)) * (HH * DD) + h * DD;
    Gs[goff + lane] = f2bf(1.f / (1.f + __expf(-glo)));
    Gs[goff + 64 + lane] = f2bf(1.f / (1.f + __expf(-ghi)));
  } else {
    int wid2 = wid - NQ;        // (b, s, kv): per b = S*KV = 8192
    int b = wid2 >> 13;
    int rem = wid2 & 8191;
    int s = rem >> 2, kv = rem & 3;
    const u16t* base = Cqkv + (size_t)(b * SS + s) * NQKV + 4096 + kv * 128;
    float xlo = bf2f(base[lane]), xhi = bf2f(base[64 + lane]);
    float ss = xlo * xlo + xhi * xhi;
    ss += __shfl_xor(ss, 1);  ss += __shfl_xor(ss, 2);  ss += __shfl_xor(ss, 4);
    ss += __shfl_xor(ss, 8);  ss += __shfl_xor(ss, 16); ss += __shfl_xor(ss, 32);
    float r = rsqrtf(ss * (1.f / 128.f) + 1e-6f);
    float klo = xlo * r * (1.f + kw[lane]);
    float khi = xhi * r * (1.f + kw[64 + lane]);
    const float* cs = rope + (size_t)s * 256;
    float clo = cs[lane], chi = cs[64 + lane];
    float slo = cs[128 + lane], shi = cs[192 + lane];
    float olo = klo * clo - khi * slo;
    float ohi = khi * chi + klo * shi;
    size_t koff = (((size_t)b * KVH + kv) * SS + s) * DD;
    Kb[koff + lane] = f2bf(olo);
    Kb[koff + 64 + lane] = f2bf(ohi);
    size_t poff = (((size_t)(b * 2 * KVH + kv)) * SS + s) * DD;
    present[poff + lane] = olo;
    present[poff + 64 + lane] = ohi;
  }
}

// ------------------------------------------------- V: present write + V^T bf16 (B,KV,D,S)
__global__ __launch_bounds__(256) void v_write(const u16t* __restrict__ Cqkv,
                                               float* __restrict__ present,
                                               u16t* __restrict__ Vtb) {
  __shared__ float lds[128 * 65];
  int t = threadIdx.x;
  int b = blockIdx.x >> 7;
  int kv = (blockIdx.x >> 5) & 3;
  int s0 = (blockIdx.x & 31) << 6;
#pragma unroll
  for (int i = 0; i < 32; i++) {
    int idx = i * 256 + t;
    int sp = idx >> 7, d = idx & 127;
    float v = bf2f(Cqkv[(size_t)(b * SS + s0 + sp) * NQKV + 4608 + kv * 128 + d]);
    present[(((size_t)(b * 2 * KVH + KVH + kv)) * SS + s0 + sp) * DD + d] = v;
    lds[d * 65 + sp] = v;
  }
  __syncthreads();
#pragma unroll
  for (int i = 0; i < 8; i++) {
    int d = i * 16 + (t >> 4);
    int sp = (t & 15) * 4;
    s16x4 pk;
    pk[0] = (short)f2bf(lds[d * 65 + sp + 0]);
    pk[1] = (short)f2bf(lds[d * 65 + sp + 1]);
    pk[2] = (short)f2bf(lds[d * 65 + sp + 2]);
    pk[3] = (short)f2bf(lds[d * 65 + sp + 3]);
    *(s16x4*)(Vtb + ((size_t)(b * KVH + kv) * DD + d) * SS + s0 + sp) = pk;
  }
}

// ---------------------------------------------------------------- flash attention v5.1
// Round-12 verbatim (passed @266us): 4-wave, paired q-tiles, K/V dbuf,
// 2 blocks/CU (cross-block overlap covers the drain), swapped-QK^T in-register
// softmax, hoisted LDS offsets. NO defer-max (correctness-banned, r11/r14).
__global__ __launch_bounds__(256, 2) void attn_kernel(const u16t* __restrict__ Qb,   // (B,H,S,D) pre-scaled
                                                      const u16t* __restrict__ Kb,   // (B,KV,S,D)
                                                      const u16t* __restrict__ Vtb,  // (B,KV,D,S)
                                                      const u16t* __restrict__ Gs,   // (B,S,H*D)
                                                      u16t* __restrict__ AttG) {     // (B,S,H*D)
  __shared__ __align__(16) char Ks[2 * 16384];  // 64 rows x 256B, chunk xor (r&7)
  __shared__ __align__(16) char Vs[2 * 16384];  // V^T: 128 rows x 128B, chunk xor (d&7)
  __shared__ __align__(16) char Ps[4 * 2048];   // per-wave P: [q:16][k-granule xor (q&7)]

  int tid = threadIdx.x, lane = tid & 63, w = tid >> 6;
  int x = blockIdx.x & 7;          // XCD grouping: each XCD owns one (b,kv)
  int b = x >> 2, kv = x & 3;
  int rr = blockIdx.x >> 3;        // 0..63
  int h = kv * 4 + (rr & 3);
  int p = rr >> 2;                 // 0..15: pair {31-p, p}

  const u16t* Kbase = Kb + (((size_t)(b * KVH + kv)) * SS) * DD;
  const u16t* Vbase = Vtb + (((size_t)(b * KVH + kv)) * DD) * SS;

  auto stageK = [&](int kt, int buf) {
#pragma unroll
    for (int i = 0; i < 4; i++) {
      int idx = i * 256 + tid;
      int r_ = idx >> 4, c_ = idx & 15;
      gload_lds16(Kbase + (size_t)(kt * 64 + r_) * DD + (c_ ^ (r_ & 7)) * 8,
                  Ks + buf * 16384 + idx * 16);
    }
  };
  auto stageV = [&](int kt, int buf) {
#pragma unroll
    for (int i = 0; i < 4; i++) {
      int idx = i * 256 + tid;
      int r_ = idx >> 3, c_ = idx & 7;
      gload_lds16(Vbase + (size_t)r_ * SS + kt * 64 + (c_ ^ (r_ & 7)) * 8,
                  Vs + buf * 16384 + idx * 16);
    }
  };

  const f32x4 fz = {0.f, 0.f, 0.f, 0.f};
  int g = lane >> 4;
  int q15 = lane & 15;
  int q7 = q15 & 7;
  char* pq = Ps + w * 2048 + q15 * 128;   // this lane's q-row in P
  int cur = 0;

  // ---- hoisted LDS offsets (loop-invariant; live in VGPRs)
  int ka[4][4];     // K-read: row ni*16+q15, chunk (ks*4+g)^q7
#pragma unroll
  for (int ni = 0; ni < 4; ni++)
#pragma unroll
    for (int ks = 0; ks < 4; ks++)
      ka[ni][ks] = (ni * 16 + q15) * 256 + (((ks * 4 + g) ^ q7) << 4);
  int va[2][8];     // V-read: row f*16+q15, chunk (ks2*4+g)^q7
#pragma unroll
  for (int ks2 = 0; ks2 < 2; ks2++)
#pragma unroll
    for (int f = 0; f < 8; f++)
      va[ks2][f] = (f * 16 + q15) * 128 + (((ks2 * 4 + g) ^ q7) << 4);
  int pr_[2];       // P-read offsets within pq
#pragma unroll
  for (int ks2 = 0; ks2 < 2; ks2++) pr_[ks2] = ((ks2 * 4 + g) ^ q7) << 4;
  int pw_[4];       // P-write offsets within pq
#pragma unroll
  for (int ni = 0; ni < 4; ni++)
    pw_[ni] = (((ni * 2 + (g >> 1)) ^ q7) << 4) + ((g & 1) << 3);

  // prologue: stage tile 0 of segment 0 into buffer 0
  stageK(0, 0);
  stageV(0, 0);

  for (int seg = 0; seg < 2; seg++) {
    int qt = (seg == 0) ? (31 - p) : p;
    const u16t* Qbase = Qb + (((size_t)(b * HH + h)) * SS + qt * 64) * DD;
    s16x8 qf[4];
    {
      const u16t* qrow = Qbase + (size_t)(w * 16 + q15) * DD + g * 8;
#pragma unroll
      for (int ks = 0; ks < 4; ks++) qf[ks] = *(const s16x8*)(qrow + ks * 32);
    }
    f32x4 acco[8];
#pragma unroll
    for (int f = 0; f < 8; f++) acco[f] = fz;
    float mrun = -INFINITY, lrun = 0.f;

    if (seg == 0) {
      asm volatile("s_waitcnt vmcnt(0)" ::: "memory");
      __builtin_amdgcn_s_barrier();
    }

    for (int kt = 0; kt <= qt; kt++) {
      bool havenext = (kt < qt) || (seg == 0);
      if (havenext) {
        int nk = (kt < qt) ? (kt + 1) : 0;   // next tile, or seg1's tile 0
        stageK(nk, cur ^ 1);
        stageV(nk, cur ^ 1);
      }
      const char* kc = Ks + (cur << 14);
      const char* vc = Vs + (cur << 14);
      // ---- swapped QK^T: accs[ni][j] = S[q = lane&15][k = ni*16+g*4+j]
      f32x4 accs[4];
#pragma unroll
      for (int ni = 0; ni < 4; ni++) accs[ni] = fz;
#pragma unroll
      for (int ni = 0; ni < 4; ni++)
#pragma unroll
        for (int ks = 0; ks < 4; ks++) {
          s16x8 bfk = *(const s16x8*)(kc + ka[ni][ks]);
          accs[ni] = __builtin_amdgcn_mfma_f32_16x16x32_bf16(bfk, qf[ks], accs[ni], 0, 0, 0);
        }
      if (kt == qt) {
        int ql = w * 16 + q15;
#pragma unroll
        for (int ni = 0; ni < 4; ni++)
#pragma unroll
          for (int j = 0; j < 4; j++) {
            int kl = ni * 16 + (g << 2) + j;
            if (kl > ql) accs[ni][j] = -1e30f;
          }
      }
      // ---- per-lane softmax (q = lane&15; 4 lanes/q combine via 2 shuffles)
      f32x4 m4 = fmax4(fmax4(accs[0], accs[1]), fmax4(accs[2], accs[3]));
      float mt = fmaxf(fmaxf(m4[0], m4[1]), fmaxf(m4[2], m4[3]));
      mt = fmaxf(mt, __shfl_xor(mt, 16));
      mt = fmaxf(mt, __shfl_xor(mt, 32));
      float mnew = fmaxf(mrun, mt);
      float alpha = __builtin_amdgcn_exp2f(mrun - mnew);
      mrun = mnew;
#pragma unroll
      for (int ni = 0; ni < 4; ni++)
#pragma unroll
        for (int j = 0; j < 4; j++)
          accs[ni][j] = __builtin_amdgcn_exp2f(accs[ni][j] - mnew);
      f32x4 s4 = (accs[0] + accs[1]) + (accs[2] + accs[3]);
      float rs = (s4[0] + s4[1]) + (s4[2] + s4[3]);
      rs += __shfl_xor(rs, 16);
      rs += __shfl_xor(rs, 32);
      lrun = lrun * alpha + rs;
      // broadcast alpha to acco's q layout (rows q = g*4+j)
      float ar[4];
#pragma unroll
      for (int j = 0; j < 4; j++) ar[j] = __shfl(alpha, (g << 2) + j);
#pragma unroll
      for (int f = 0; f < 8; f++)
#pragma unroll
        for (int j = 0; j < 4; j++) acco[f][j] *= ar[j];

      // ---- P pack (bf16 pairs along k) -> b64 LDS stores
#pragma unroll
      for (int ni = 0; ni < 4; ni++) {
        uint2 pk;
        pk.x = cvtpk_bf16(accs[ni][0], accs[ni][1]);
        pk.y = cvtpk_bf16(accs[ni][2], accs[ni][3]);
        *(uint2*)(pq + pw_[ni]) = pk;
      }
      // ---- PV
#pragma unroll
      for (int ks2 = 0; ks2 < 2; ks2++) {
        s16x8 pa = *(const s16x8*)(pq + pr_[ks2]);
#pragma unroll
        for (int f = 0; f < 8; f++) {
          s16x8 vf = *(const s16x8*)(vc + va[ks2][f]);
          acco[f] = __builtin_amdgcn_mfma_f32_16x16x32_bf16(pa, vf, acco[f], 0, 0, 0);
        }
      }
      // ---- tile boundary: next tile staged, current reads done
      if (havenext) {
        asm volatile("s_waitcnt vmcnt(0)" ::: "memory");
        __builtin_amdgcn_s_barrier();
        cur ^= 1;
      }
    }
    // ---- segment epilogue: gate + store (lrun broadcast to acco layout)
    float lr[4];
#pragma unroll
    for (int j = 0; j < 4; j++) lr[j] = __shfl(lrun, (g << 2) + j);
#pragma unroll
    for (int f = 0; f < 8; f++) {
      int d = f * 16 + q15;
#pragma unroll
      for (int j = 0; j < 4; j++) {
        int srow = qt * 64 + w * 16 + (g << 2) + j;
        float o = acco[f][j] / lr[j];
        size_t off = ((size_t)b * SS + srow) * (HH * DD) + h * DD + d;
        float gt = bf2f(Gs[off]);
        AttG[off] = f2bf(o * gt);
      }
    }
  }
}

// ---------------------------------------------------------------- launcher
extern "C" void kernel_launch(void* const* d_in, const int* in_sizes, int n_in,
                              void* d_out, int out_size, void* d_ws, size_t ws_size,
                              hipStream_t stream) {
  const float* hidden = (const float*)d_in[0];
  const float* rope   = (const float*)d_in[2];
  const float* Wq     = (const float*)d_in[5];
  const float* Wk     = (const float*)d_in[6];
  const float* Wv     = (const float*)d_in[7];
  const float* Wo     = (const float*)d_in[8];
  const float* qw     = (const float*)d_in[9];
  const float* kw     = (const float*)d_in[10];
  float* out = (float*)d_out;
  float* present = out + (size_t)BB * SS * HIDD; // 8,388,608

  char* ws = (char*)d_ws;
  u16t* Xb    = (u16t*)(ws);                              // 4096x2048 bf16   16.78MB
  u16t* Wt    = (u16t*)(ws + 16777216);                   // 5120x2048 bf16   20.97MB
  u16t* Wot   = (u16t*)(ws + 37748736);                   // 2048x2048 bf16    8.39MB
  u16t* Cqkv  = (u16t*)(ws + 46137344);                   // 4096x5120 bf16   41.94MB
  u16t* Qb    = (u16t*)(ws + 88080384);                   // (B,H,S,D) bf16   16.78MB
  u16t* Kb    = (u16t*)(ws + 104857600);                  // (B,KV,S,D) bf16   4.19MB
  u16t* Vtb   = (u16t*)(ws + 109051904);                  // (B,KV,D,S) bf16   4.19MB
  u16t* Gs    = (u16t*)(ws + 113246208);                  // (B,S,H*D) bf16   16.78MB
  u16t* AttG  = Xb;  // alias: Xb dead after QKV GEMM; AttG written by attention

  (void)hipFuncSetAttribute(reinterpret_cast<const void*>(gemm8<256, u16t>),
                            hipFuncAttributeMaxDynamicSharedMemorySize, 131072);
  (void)hipFuncSetAttribute(reinterpret_cast<const void*>(gemm8<128, float>),
                            hipFuncAttributeMaxDynamicSharedMemorySize, 98304);

  // 1+2. fused prep: cast hidden (8 elem/thr) + weight transposes (s16x8 stores)
  prep_all<<<4096 + 3584, 256, 0, stream>>>(hidden, Wq, Wk, Wv, Wo, Xb, Wt, Wot);
  // 3a. Q projection (N=4096): 256^2 8-phase, grid 16x16 = 256 = exactly 1 block/CU
  gemm8<256, u16t><<<(MM / 256) * (4096 / 256), 512, 131072, stream>>>(Xb, Wt, Cqkv, MM, NQKV, HIDD);
  // 3b. K+V projection (N=1024): 128^2 m97, grid 32x8 = 256 = exactly 1 block/CU
  gemm_bt<u16t><<<(MM / 128) * (1024 / 128), 256, 0, stream>>>(
      Xb, Wt + (size_t)4096 * HIDD, Cqkv + 4096, MM, NQKV, HIDD);
  // 4. Q/K norm+rope (+present K, +sigmoid gate); V writer (+present V, +V^T)
  qk_norm_rope<<<(BB * SS * (HH + KVH)) / 4, 256, 0, stream>>>(Cqkv, rope, qw, kw, Qb, Kb, Gs, present);
  v_write<<<BB * KVH * (SS / 64), 256, 0, stream>>>(Cqkv, present, Vtb);
  // 5. flash attention v5.1 (round-12 verbatim, no defer-max)
  attn_kernel<<<BB * HH * (SS / 128), 256, 0, stream>>>(Qb, Kb, Vtb, Gs, AttG);
  // 6. output projection -> d_out: 256x128 8-phase, grid 16x16 = 256 = 1 block/CU
  gemm8<128, float><<<(MM / 256) * (HIDD / 128), 512, 98304, stream>>>(AttG, Wot, out, MM, HIDD, HIDD);
}

// Round 16
// 265.462 us; speedup vs baseline: 1.0434x; 1.0008x over previous
//
#include <hip/hip_runtime.h>
#include <hip/hip_bf16.h>
#include <cstdint>
#include <cstddef>

// Problem constants
#define BB   2
#define SS   2048
#define HIDD 2048
#define HH   16
#define KVH  4
#define DD   128
#define NQKV 5120   // H*2*D + KV*D + KV*D = 4096 + 512 + 512
#define MM   4096   // B*S

typedef unsigned short u16t;
typedef __attribute__((ext_vector_type(8))) short s16x8;
typedef __attribute__((ext_vector_type(4))) short s16x4;
typedef __attribute__((ext_vector_type(4))) float f32x4;

__device__ __forceinline__ u16t f2bf(float f) {
  unsigned u = __float_as_uint(f);
  u += 0x7fffu + ((u >> 16) & 1u);
  return (u16t)(u >> 16);
}
__device__ __forceinline__ float bf2f(u16t h) {
  return __uint_as_float(((unsigned)h) << 16);
}
__device__ __forceinline__ void gload_lds16(const void* g, void* l) {
  __builtin_amdgcn_global_load_lds(
      (const __attribute__((address_space(1))) unsigned int*)g,
      (__attribute__((address_space(3))) unsigned int*)l, 16, 0, 0);
}
__device__ __forceinline__ unsigned cvtpk_bf16(float lo, float hi) {
  unsigned r;
  asm("v_cvt_pk_bf16_f32 %0, %1, %2" : "=v"(r) : "v"(lo), "v"(hi));
  return r;
}
__device__ __forceinline__ f32x4 fmax4(f32x4 a, f32x4 b) {
  f32x4 r;
  r[0] = fmaxf(a[0], b[0]); r[1] = fmaxf(a[1], b[1]);
  r[2] = fmaxf(a[2], b[2]); r[3] = fmaxf(a[3], b[3]);
  return r;
}
// counted vmcnt via literal asm (compiler-ordering fence through "memory" clobber).
// Round-11/14 lessons: __builtin_amdgcn_s_waitcnt is NOT a memory fence; and
// defer-max (T13) breaks correctness on this pipelined structure -- banned.
template <int N>
__device__ __forceinline__ void waitvm() {
  static_assert(N == 0 || N == 3 || N == 4 || N == 6 || N == 8, "add literal");
  if constexpr (N == 0)      asm volatile("s_waitcnt vmcnt(0)" ::: "memory");
  else if constexpr (N == 3) asm volatile("s_waitcnt vmcnt(3)" ::: "memory");
  else if constexpr (N == 4) asm volatile("s_waitcnt vmcnt(4)" ::: "memory");
  else if constexpr (N == 6) asm volatile("s_waitcnt vmcnt(6)" ::: "memory");
  else if constexpr (N == 8) asm volatile("s_waitcnt vmcnt(8)" ::: "memory");
}

// ----------------------------------------- fused prep: cast hidden + transpose-cast all weights
__global__ __launch_bounds__(256) void prep_all(const float* __restrict__ hidden,
                                                const float* __restrict__ Wq,
                                                const float* __restrict__ Wk,
                                                const float* __restrict__ Wv,
                                                const float* __restrict__ Wo,
                                                u16t* __restrict__ Xb,
                                                u16t* __restrict__ Wt,
                                                u16t* __restrict__ Wot) {
  __shared__ float lds[64 * 65];
  int bid = blockIdx.x;
  int t = threadIdx.x;
  if (bid < 4096) {
    size_t i = ((size_t)bid * 256 + t) * 8;
    f32x4 v0 = *(const f32x4*)(hidden + i);
    f32x4 v1 = *(const f32x4*)(hidden + i + 4);
    s16x8 o;
    o[0] = (short)f2bf(v0[0]); o[1] = (short)f2bf(v0[1]);
    o[2] = (short)f2bf(v0[2]); o[3] = (short)f2bf(v0[3]);
    o[4] = (short)f2bf(v1[0]); o[5] = (short)f2bf(v1[1]);
    o[6] = (short)f2bf(v1[2]); o[7] = (short)f2bf(v1[3]);
    *(s16x8*)(Xb + i) = o;
    return;
  }
  bid -= 4096;
  const float* src; u16t* dst; int N;
  if (bid < 2048)      { src = Wq; dst = Wt;                         N = 4096; }
  else if (bid < 2304) { src = Wk; dst = Wt + (size_t)4096 * HIDD;   N = 512;  bid -= 2048; }
  else if (bid < 2560) { src = Wv; dst = Wt + (size_t)4608 * HIDD;   N = 512;  bid -= 2304; }
  else                 { src = Wo; dst = Wot;                        N = 2048; bid -= 2560; }
  const int ktiles = HIDD / 64; // 32
  int n0 = (bid / ktiles) << 6;
  int k0 = (bid % ktiles) << 6;
#pragma unroll
  for (int i = 0; i < 16; i++) {
    int idx = i * 256 + t;
    int r = idx >> 6, c = idx & 63;
    lds[c * 65 + r] = src[(size_t)(k0 + r) * N + n0 + c];
  }
  __syncthreads();
#pragma unroll
  for (int i = 0; i < 2; i++) {
    int idx = i * 256 + t;
    int rr = idx >> 3, k8 = (idx & 7) * 8;
    s16x8 o;
#pragma unroll
    for (int e = 0; e < 8; e++) o[e] = (short)f2bf(lds[rr * 65 + k8 + e]);
    *(s16x8*)(dst + (size_t)(n0 + rr) * HIDD + k0 + k8) = o;
  }
}

// ---------------------------------------------------------------- 256xBN 8-phase bf16 GEMM
// C(M x n, CT; row-stride N) = A(MxK) @ Bt(nxK)^T.  BK=64 (2 K-halves of 32).
// BN in {256,128}. grid = (M/256)*(n/BN); M/256 must be 16.
__device__ __forceinline__ s16x8 ldsfrag(const char* half, int r, int g) {
  return *(const s16x8*)(half + r * 64 + ((g ^ ((r >> 1) & 3)) << 4));
}
template <int NL>
__device__ __forceinline__ void stage_half(char* ldsbase, const u16t* gbase,
                                           int K, int kcol, int tid) {
#pragma unroll
  for (int i = 0; i < NL; i++) {
    int o16 = i * 512 + tid;
    int r = o16 >> 2;
    int cs = (o16 & 3) ^ ((r >> 1) & 3);
    gload_lds16(gbase + (size_t)r * K + kcol + cs * 8, ldsbase + o16 * 16);
  }
}

template <int BN, typename CT>
__global__ __launch_bounds__(512, 2) void gemm8(const u16t* __restrict__ A,
                                                const u16t* __restrict__ Bt,
                                                CT* __restrict__ C,
                                                int M, int N, int K) {
  constexpr int NLB = BN / 128;            // B-half loads/thread
  constexpr int AHALF = 16384, ASLOT = 32768;
  constexpr int BHALF = BN * 64, BSLOT = 2 * BHALF;
  constexpr int PAIR = 2 + NLB;            // loads per (A,B) half-tile pair
  constexpr int NI = BN / 64;              // B frags per wave
  extern __shared__ __align__(16) char lds[];
  char* As = lds;
  char* Bs = lds + 2 * ASLOT;
  int tid = threadIdx.x, lane = tid & 63, w = tid >> 6;
  int wm = w >> 2, wn = w & 3;
  int cpx = gridDim.x >> 3;                       // grid % 8 == 0
  int wgid = (blockIdx.x & 7) * cpx + (blockIdx.x >> 3);
  int bm = wgid & 15, bn = wgid >> 4;             // M/256 == 16
  int m0 = bm << 8, n0 = bn * BN;
  const u16t* Ag = A + (size_t)m0 * K;
  const u16t* Bg = Bt + (size_t)n0 * K;
  const int NT = K >> 6;

  stage_half<2>(As, Ag, K, 0, tid);
  stage_half<NLB>(Bs, Bg, K, 0, tid);
  stage_half<2>(As + AHALF, Ag, K, 32, tid);
  stage_half<NLB>(Bs + BHALF, Bg, K, 32, tid);
  stage_half<2>(As + ASLOT, Ag, K, 64, tid);
  stage_half<NLB>(Bs + BSLOT, Bg, K, 64, tid);
  waitvm<2 * PAIR>();
  __builtin_amdgcn_s_barrier();

  const f32x4 fz = {0.f, 0.f, 0.f, 0.f};
  f32x4 acc[8][NI];
#pragma unroll
  for (int i = 0; i < 8; i++)
#pragma unroll
    for (int j = 0; j < NI; j++) acc[i][j] = fz;
  s16x8 afr[4], bfr[NI];
  int g = lane >> 4;
  int rA = (lane & 15) + wm * 128;
  int rB = (lane & 15) + wn * (BN / 4);

  for (int kt = 0; kt < NT; kt++) {
    int cur = kt & 1;
    char* Acur = As + cur * ASLOT;
    char* Bcur = Bs + cur * BSLOT;
    char* Anxt = As + (cur ^ 1) * ASLOT;
    char* Bnxt = Bs + (cur ^ 1) * BSLOT;
    // ---- phase 0: (kk0, mh0); stage Ah1(kt+1)
#pragma unroll
    for (int ni = 0; ni < NI; ni++) bfr[ni] = ldsfrag(Bcur, rB + ni * 16, g);
#pragma unroll
    for (int mi = 0; mi < 4; mi++) afr[mi] = ldsfrag(Acur, rA + mi * 16, g);
    if (kt + 1 < NT) stage_half<2>(Anxt + AHALF, Ag, K, (kt + 1) * 64 + 32, tid);
    __builtin_amdgcn_s_barrier();
    asm volatile("s_waitcnt lgkmcnt(0)" ::: "memory");
    __builtin_amdgcn_s_setprio(1);
#pragma unroll
    for (int mi = 0; mi < 4; mi++)
#pragma unroll
      for (int ni = 0; ni < NI; ni++)
        acc[mi][ni] = __builtin_amdgcn_mfma_f32_16x16x32_bf16(afr[mi], bfr[ni], acc[mi][ni], 0, 0, 0);
    __builtin_amdgcn_s_setprio(0);
    __builtin_amdgcn_s_barrier();
    // ---- phase 1: (kk0, mh1); stage Bh1(kt+1); counted wait
#pragma unroll
    for (int mi = 0; mi < 4; mi++) afr[mi] = ldsfrag(Acur, rA + 64 + mi * 16, g);
    if (kt + 1 < NT) stage_half<NLB>(Bnxt + BHALF, Bg, K, (kt + 1) * 64 + 32, tid);
    __builtin_amdgcn_s_barrier();
    asm volatile("s_waitcnt lgkmcnt(0)" ::: "memory");
    __builtin_amdgcn_s_setprio(1);
#pragma unroll
    for (int mi = 0; mi < 4; mi++)
#pragma unroll
      for (int ni = 0; ni < NI; ni++)
        acc[4 + mi][ni] = __builtin_amdgcn_mfma_f32_16x16x32_bf16(afr[mi], bfr[ni], acc[4 + mi][ni], 0, 0, 0);
    __builtin_amdgcn_s_setprio(0);
    if (kt + 1 < NT) waitvm<2 * PAIR>();
    else             waitvm<0>();
    __builtin_amdgcn_s_barrier();
    // ---- phase 2: (kk1, mh0); stage Ah0(kt+2)
#pragma unroll
    for (int ni = 0; ni < NI; ni++) bfr[ni] = ldsfrag(Bcur + BHALF, rB + ni * 16, g);
#pragma unroll
    for (int mi = 0; mi < 4; mi++) afr[mi] = ldsfrag(Acur + AHALF, rA + mi * 16, g);
    if (kt + 2 < NT) stage_half<2>(Acur, Ag, K, (kt + 2) * 64, tid);
    __builtin_amdgcn_s_barrier();
    asm volatile("s_waitcnt lgkmcnt(0)" ::: "memory");
    __builtin_amdgcn_s_setprio(1);
#pragma unroll
    for (int mi = 0; mi < 4; mi++)
#pragma unroll
      for (int ni = 0; ni < NI; ni++)
        acc[mi][ni] = __builtin_amdgcn_mfma_f32_16x16x32_bf16(afr[mi], bfr[ni], acc[mi][ni], 0, 0, 0);
    __builtin_amdgcn_s_setprio(0);
    __builtin_amdgcn_s_barrier();
    // ---- phase 3: (kk1, mh1); stage Bh0(kt+2); counted wait
#pragma unroll
    for (int mi = 0; mi < 4; mi++) afr[mi] = ldsfrag(Acur + AHALF, rA + 64 + mi * 16, g);
    if (kt + 2 < NT) stage_half<NLB>(Bcur, Bg, K, (kt + 2) * 64, tid);
    __builtin_amdgcn_s_barrier();
    asm volatile("s_waitcnt lgkmcnt(0)" ::: "memory");
    __builtin_amdgcn_s_setprio(1);
#pragma unroll
    for (int mi = 0; mi < 4; mi++)
#pragma unroll
      for (int ni = 0; ni < NI; ni++)
        acc[4 + mi][ni] = __builtin_amdgcn_mfma_f32_16x16x32_bf16(afr[mi], bfr[ni], acc[4 + mi][ni], 0, 0, 0);
    __builtin_amdgcn_s_setprio(0);
    if (kt < NT - 1) {
      if (kt + 2 < NT) waitvm<2 * PAIR>();
      else             waitvm<PAIR>();
    }
    __builtin_amdgcn_s_barrier();
  }
#pragma unroll
  for (int mi = 0; mi < 8; mi++)
#pragma unroll
    for (int ni = 0; ni < NI; ni++) {
      int row0 = m0 + wm * 128 + mi * 16 + ((lane >> 4) << 2);
      int col = n0 + wn * (BN / 4) + ni * 16 + (lane & 15);
#pragma unroll
      for (int j = 0; j < 4; j++) {
        if constexpr (sizeof(CT) == 2)
          C[(size_t)(row0 + j) * N + col] = f2bf(acc[mi][ni][j]);
        else
          C[(size_t)(row0 + j) * N + col] = acc[mi][ni][j];
      }
    }
}

// ---------------------------------------------------------------- KV projection GEMM (m97 structure)
// A(MM x K) @ WtKV(1024 x K)^T. n-tile of 128 cols: bn 0..3 = K-heads -> Cqkv;
// bn 4..7 = V-heads -> present (f32) + Vtb (bf16, (B,KV,D,S)) directly.
// Replaces gemm_bt<u16t> + v_write (fused epilogue; V never touches Cqkv).
__global__ __launch_bounds__(256) void gemm_kv(const u16t* __restrict__ A,
                                               const u16t* __restrict__ Bt,
                                               u16t* __restrict__ Cqkv,
                                               float* __restrict__ present,
                                               u16t* __restrict__ Vtb,
                                               int K) {
  __shared__ __align__(16) char As[128 * 64];
  __shared__ __align__(16) char Bs[128 * 64];
  int tid = threadIdx.x;
  int lane = tid & 63;
  int w = tid >> 6;
  int cpx = gridDim.x >> 3;
  int wgid = ((int)blockIdx.x & 7) * cpx + ((int)blockIdx.x >> 3);
  const int mtiles = MM >> 7;                 // 32
  int bm = wgid % mtiles;
  int bn = wgid / mtiles;                     // 0..7
  int m0 = bm << 7, n0 = bn << 7;
  int wr = (w >> 1) * 64, wc = (w & 1) * 64;

  const f32x4 fz = {0.f, 0.f, 0.f, 0.f};
  f32x4 acc[4][4];
#pragma unroll
  for (int i = 0; i < 4; i++)
#pragma unroll
    for (int j = 0; j < 4; j++) acc[i][j] = fz;

  for (int k0 = 0; k0 < K; k0 += 32) {
    __syncthreads();
#pragma unroll
    for (int i = 0; i < 2; i++) {
      int idx = i * 256 + tid;
      int r = idx >> 2, c = idx & 3;
      int csrc = c ^ ((r >> 1) & 3);
      gload_lds16(A + (size_t)(m0 + r) * K + k0 + csrc * 8, As + idx * 16);
      gload_lds16(Bt + (size_t)(n0 + r) * K + k0 + csrc * 8, Bs + idx * 16);
    }
    __syncthreads();
    s16x8 af[4], bf[4];
    int g = lane >> 4;
#pragma unroll
    for (int mi = 0; mi < 4; mi++) {
      int r = wr + mi * 16 + (lane & 15);
      af[mi] = *(const s16x8*)(As + r * 64 + ((g ^ ((r >> 1) & 3)) << 4));
    }
#pragma unroll
    for (int ni = 0; ni < 4; ni++) {
      int r = wc + ni * 16 + (lane & 15);
      bf[ni] = *(const s16x8*)(Bs + r * 64 + ((g ^ ((r >> 1) & 3)) << 4));
    }
#pragma unroll
    for (int mi = 0; mi < 4; mi++)
#pragma unroll
      for (int ni = 0; ni < 4; ni++)
        acc[mi][ni] = __builtin_amdgcn_mfma_f32_16x16x32_bf16(af[mi], bf[ni], acc[mi][ni], 0, 0, 0);
  }
  if (bn < 4) {
    // K columns -> Cqkv[row][4096 + n0 + col]
#pragma unroll
    for (int mi = 0; mi < 4; mi++)
#pragma unroll
      for (int ni = 0; ni < 4; ni++) {
        int row0 = m0 + wr + mi * 16 + ((lane >> 4) << 2);
        int col = n0 + wc + ni * 16 + (lane & 15);
#pragma unroll
        for (int j = 0; j < 4; j++)
          Cqkv[(size_t)(row0 + j) * NQKV + 4096 + col] = f2bf(acc[mi][ni][j]);
      }
  } else {
    // V columns: vcol = n0-512 + wc + ni*16 + lane&15; kv = vcol>>7, d = vcol&127
#pragma unroll
    for (int mi = 0; mi < 4; mi++)
#pragma unroll
      for (int ni = 0; ni < 4; ni++) {
        int row0 = m0 + wr + mi * 16 + ((lane >> 4) << 2);
        int vcol = (n0 - 512) + wc + ni * 16 + (lane & 15);
        int kv = vcol >> 7, d = vcol & 127;
        int bb = row0 >> 11, sp = row0 & 2047;
        // present[bb][1][kv][sp+j][d]  (f32)
        size_t pbase = (((size_t)(bb * 2 * KVH + KVH + kv)) * SS + sp) * DD + d;
#pragma unroll
        for (int j = 0; j < 4; j++)
          present[pbase + (size_t)j * DD] = acc[mi][ni][j];
        // Vtb[bb][kv][d][sp..sp+3]  (bf16 x4 vector)
        s16x4 pk;
        pk[0] = (short)f2bf(acc[mi][ni][0]);
        pk[1] = (short)f2bf(acc[mi][ni][1]);
        pk[2] = (short)f2bf(acc[mi][ni][2]);
        pk[3] = (short)f2bf(acc[mi][ni][3]);
        *(s16x4*)(Vtb + ((size_t)(bb * KVH + kv) * DD + d) * SS + sp) = pk;
      }
  }
}

// ------------------------------------------------- fused RMSNorm + RoPE for Q and K
__global__ __launch_bounds__(256) void qk_norm_rope(const u16t* __restrict__ Cqkv,
                                                    const float* __restrict__ rope,
                                                    const float* __restrict__ qw,
                                                    const float* __restrict__ kw,
                                                    u16t* __restrict__ Qb,   // (B,H,S,D)
                                                    u16t* __restrict__ Kb,   // (B,KV,S,D)
                                                    u16t* __restrict__ Gs,   // (B,S,H*D)
                                                    float* __restrict__ present) {
  int wid = blockIdx.x * 4 + (threadIdx.x >> 6);
  int lane = threadIdx.x & 63;
  const int NQ = BB * SS * HH; // 65536
  if (wid < NQ) {
    int b = wid >> 15;          // S*H = 32768
    int rem = wid & 32767;
    int s = rem >> 4, h = rem & 15;
    const u16t* base = Cqkv + (size_t)(b * SS + s) * NQKV + h * 256;
    float xlo = bf2f(base[lane]), xhi = bf2f(base[64 + lane]);
    float ss = xlo * xlo + xhi * xhi;
    ss += __shfl_xor(ss, 1);  ss += __shfl_xor(ss, 2);  ss += __shfl_xor(ss, 4);
    ss += __shfl_xor(ss, 8);  ss += __shfl_xor(ss, 16); ss += __shfl_xor(ss, 32);
    float r = rsqrtf(ss * (1.f / 128.f) + 1e-6f);
    float qlo = xlo * r * (1.f + qw[lane]);
    float qhi = xhi * r * (1.f + qw[64 + lane]);
    const float* cs = rope + (size_t)s * 256;
    float clo = cs[lane], chi = cs[64 + lane];
    float slo = cs[128 + lane], shi = cs[192 + lane];
    // 1/sqrt(128) * log2(e): scores land in log2 units -> exp2 in attention
    const float SC = 0.08838834764831845f * 1.4426950408889634f;
    float olo = (qlo * clo - qhi * slo) * SC;
    float ohi = (qhi * chi + qlo * shi) * SC;
    size_t qoff = (((size_t)b * HH + h) * SS + s) * DD;
    Qb[qoff + lane] = f2bf(olo);
    Qb[qoff + 64 + lane] = f2bf(ohi);
    float glo = bf2f(base[128 + lane]), ghi = bf2f(base[192 + lane]);
    size_t goff = ((size_t)(b * SS + s)) * (HH * DD) + h * DD;
    Gs[goff + lane] = f2bf(1.f / (1.f + __expf(-glo)));
    Gs[goff + 64 + lane] = f2bf(1.f / (1.f + __expf(-ghi)));
  } else {
    int wid2 = wid - NQ;        // (b, s, kv): per b = S*KV = 8192
    int b = wid2 >> 13;
    int rem = wid2 & 8191;
    int s = rem >> 2, kv = rem & 3;
    const u16t* base = Cqkv + (size_t)(b * SS + s) * NQKV + 4096 + kv * 128;
    float xlo = bf2f(base[lane]), xhi = bf2f(base[64 + lane]);
    float ss = xlo * xlo + xhi * xhi;
    ss += __shfl_xor(ss, 1);  ss += __shfl_xor(ss, 2);  ss += __shfl_xor(ss, 4);
    ss += __shfl_xor(ss, 8);  ss += __shfl_xor(ss, 16); ss += __shfl_xor(ss, 32);
    float r = rsqrtf(ss * (1.f / 128.f) + 1e-6f);
    float klo = xlo * r * (1.f + kw[lane]);
    float khi = xhi * r * (1.f + kw[64 + lane]);
    const float* cs = rope + (size_t)s * 256;
    float clo = cs[lane], chi = cs[64 + lane];
    float slo = cs[128 + lane], shi = cs[192 + lane];
    float olo = klo * clo - khi * slo;
    float ohi = khi * chi + klo * shi;
    size_t koff = (((size_t)b * KVH + kv) * SS + s) * DD;
    Kb[koff + lane] = f2bf(olo);
    Kb[koff + 64 + lane] = f2bf(ohi);
    size_t poff = (((size_t)(b * 2 * KVH + kv)) * SS + s) * DD;
    present[poff + lane] = olo;
    present[poff + 64 + lane] = ohi;
  }
}

// ---------------------------------------------------------------- flash attention v5.1
// Round-12 verbatim (passed @266us): 4-wave, paired q-tiles, K/V dbuf,
// 2 blocks/CU (cross-block overlap covers the drain), swapped-QK^T in-register
// softmax, hoisted LDS offsets. NO defer-max (correctness-banned, r11/r14).
__global__ __launch_bounds__(256, 2) void attn_kernel(const u16t* __restrict__ Qb,   // (B,H,S,D) pre-scaled
                                                      const u16t* __restrict__ Kb,   // (B,KV,S,D)
                                                      const u16t* __restrict__ Vtb,  // (B,KV,D,S)
                                                      const u16t* __restrict__ Gs,   // (B,S,H*D)
                                                      u16t* __restrict__ AttG) {     // (B,S,H*D)
  __shared__ __align__(16) char Ks[2 * 16384];  // 64 rows x 256B, chunk xor (r&7)
  __shared__ __align__(16) char Vs[2 * 16384];  // V^T: 128 rows x 128B, chunk xor (d&7)
  __shared__ __align__(16) char Ps[4 * 2048];   // per-wave P: [q:16][k-granule xor (q&7)]

  int tid = threadIdx.x, lane = tid & 63, w = tid >> 6;
  int x = blockIdx.x & 7;          // XCD grouping: each XCD owns one (b,kv)
  int b = x >> 2, kv = x & 3;
  int rr = blockIdx.x >> 3;        // 0..63
  int h = kv * 4 + (rr & 3);
  int p = rr >> 2;                 // 0..15: pair {31-p, p}

  const u16t* Kbase = Kb + (((size_t)(b * KVH + kv)) * SS) * DD;
  const u16t* Vbase = Vtb + (((size_t)(b * KVH + kv)) * DD) * SS;

  auto stageK = [&](int kt, int buf) {
#pragma unroll
    for (int i = 0; i < 4; i++) {
      int idx = i * 256 + tid;
      int r_ = idx >> 4, c_ = idx & 15;
      gload_lds16(Kbase + (size_t)(kt * 64 + r_) * DD + (c_ ^ (r_ & 7)) * 8,
                  Ks + buf * 16384 + idx * 16);
    }
  };
  auto stageV = [&](int kt, int buf) {
#pragma unroll
    for (int i = 0; i < 4; i++) {
      int idx = i * 256 + tid;
      int r_ = idx >> 3, c_ = idx & 7;
      gload_lds16(Vbase + (size_t)r_ * SS + kt * 64 + (c_ ^ (r_ & 7)) * 8,
                  Vs + buf * 16384 + idx * 16);
    }
  };

  const f32x4 fz = {0.f, 0.f, 0.f, 0.f};
  int g = lane >> 4;
  int q15 = lane & 15;
  int q7 = q15 & 7;
  char* pq = Ps + w * 2048 + q15 * 128;   // this lane's q-row in P
  int cur = 0;

  // ---- hoisted LDS offsets (loop-invariant; live in VGPRs)
  int ka[4][4];     // K-read: row ni*16+q15, chunk (ks*4+g)^q7
#pragma unroll
  for (int ni = 0; ni < 4; ni++)
#pragma unroll
    for (int ks = 0; ks < 4; ks++)
      ka[ni][ks] = (ni * 16 + q15) * 256 + (((ks * 4 + g) ^ q7) << 4);
  int va[2][8];     // V-read: row f*16+q15, chunk (ks2*4+g)^q7
#pragma unroll
  for (int ks2 = 0; ks2 < 2; ks2++)
#pragma unroll
    for (int f = 0; f < 8; f++)
      va[ks2][f] = (f * 16 + q15) * 128 + (((ks2 * 4 + g) ^ q7) << 4);
  int pr_[2];       // P-read offsets within pq
#pragma unroll
  for (int ks2 = 0; ks2 < 2; ks2++) pr_[ks2] = ((ks2 * 4 + g) ^ q7) << 4;
  int pw_[4];       // P-write offsets within pq
#pragma unroll
  for (int ni = 0; ni < 4; ni++)
    pw_[ni] = (((ni * 2 + (g >> 1)) ^ q7) << 4) + ((g & 1) << 3);

  // prologue: stage tile 0 of segment 0 into buffer 0
  stageK(0, 0);
  stageV(0, 0);

  for (int seg = 0; seg < 2; seg++) {
    int qt = (seg == 0) ? (31 - p) : p;
    const u16t* Qbase = Qb + (((size_t)(b * HH + h)) * SS + qt * 64) * DD;
    s16x8 qf[4];
    {
      const u16t* qrow = Qbase + (size_t)(w * 16 + q15) * DD + g * 8;
#pragma unroll
      for (int ks = 0; ks < 4; ks++) qf[ks] = *(const s16x8*)(qrow + ks * 32);
    }
    f32x4 acco[8];
#pragma unroll
    for (int f = 0; f < 8; f++) acco[f] = fz;
    float mrun = -INFINITY, lrun = 0.f;

    if (seg == 0) {
      asm volatile("s_waitcnt vmcnt(0)" ::: "memory");
      __builtin_amdgcn_s_barrier();
    }

    for (int kt = 0; kt <= qt; kt++) {
      bool havenext = (kt < qt) || (seg == 0);
      if (havenext) {
        int nk = (kt < qt) ? (kt + 1) : 0;   // next tile, or seg1's tile 0
        stageK(nk, cur ^ 1);
        stageV(nk, cur ^ 1);
      }
      const char* kc = Ks + (cur << 14);
      const char* vc = Vs + (cur << 14);
      // ---- swapped QK^T: accs[ni][j] = S[q = lane&15][k = ni*16+g*4+j]
      f32x4 accs[4];
#pragma unroll
      for (int ni = 0; ni < 4; ni++) accs[ni] = fz;
#pragma unroll
      for (int ni = 0; ni < 4; ni++)
#pragma unroll
        for (int ks = 0; ks < 4; ks++) {
          s16x8 bfk = *(const s16x8*)(kc + ka[ni][ks]);
          accs[ni] = __builtin_amdgcn_mfma_f32_16x16x32_bf16(bfk, qf[ks], accs[ni], 0, 0, 0);
        }
      if (kt == qt) {
        int ql = w * 16 + q15;
#pragma unroll
        for (int ni = 0; ni < 4; ni++)
#pragma unroll
          for (int j = 0; j < 4; j++) {
            int kl = ni * 16 + (g << 2) + j;
            if (kl > ql) accs[ni][j] = -1e30f;
          }
      }
      // ---- per-lane softmax (q = lane&15; 4 lanes/q combine via 2 shuffles)
      f32x4 m4 = fmax4(fmax4(accs[0], accs[1]), fmax4(accs[2], accs[3]));
      float mt = fmaxf(fmaxf(m4[0], m4[1]), fmaxf(m4[2], m4[3]));
      mt = fmaxf(mt, __shfl_xor(mt, 16));
      mt = fmaxf(mt, __shfl_xor(mt, 32));
      float mnew = fmaxf(mrun, mt);
      float alpha = __builtin_amdgcn_exp2f(mrun - mnew);
      mrun = mnew;
#pragma unroll
      for (int ni = 0; ni < 4; ni++)
#pragma unroll
        for (int j = 0; j < 4; j++)
          accs[ni][j] = __builtin_amdgcn_exp2f(accs[ni][j] - mnew);
      f32x4 s4 = (accs[0] + accs[1]) + (accs[2] + accs[3]);
      float rs = (s4[0] + s4[1]) + (s4[2] + s4[3]);
      rs += __shfl_xor(rs, 16);
      rs += __shfl_xor(rs, 32);
      lrun = lrun * alpha + rs;
      // broadcast alpha to acco's q layout (rows q = g*4+j)
      float ar[4];
#pragma unroll
      for (int j = 0; j < 4; j++) ar[j] = __shfl(alpha, (g << 2) + j);
#pragma unroll
      for (int f = 0; f < 8; f++)
#pragma unroll
        for (int j = 0; j < 4; j++) acco[f][j] *= ar[j];

      // ---- P pack (bf16 pairs along k) -> b64 LDS stores
#pragma unroll
      for (int ni = 0; ni < 4; ni++) {
        uint2 pk;
        pk.x = cvtpk_bf16(accs[ni][0], accs[ni][1]);
        pk.y = cvtpk_bf16(accs[ni][2], accs[ni][3]);
        *(uint2*)(pq + pw_[ni]) = pk;
      }
      // ---- PV
#pragma unroll
      for (int ks2 = 0; ks2 < 2; ks2++) {
        s16x8 pa = *(const s16x8*)(pq + pr_[ks2]);
#pragma unroll
        for (int f = 0; f < 8; f++) {
          s16x8 vf = *(const s16x8*)(vc + va[ks2][f]);
          acco[f] = __builtin_amdgcn_mfma_f32_16x16x32_bf16(pa, vf, acco[f], 0, 0, 0);
        }
      }
      // ---- tile boundary: next tile staged, current reads done
      if (havenext) {
        asm volatile("s_waitcnt vmcnt(0)" ::: "memory");
        __builtin_amdgcn_s_barrier();
        cur ^= 1;
      }
    }
    // ---- segment epilogue: gate + store (lrun broadcast to acco layout)
    float lr[4];
#pragma unroll
    for (int j = 0; j < 4; j++) lr[j] = __shfl(lrun, (g << 2) + j);
#pragma unroll
    for (int f = 0; f < 8; f++) {
      int d = f * 16 + q15;
#pragma unroll
      for (int j = 0; j < 4; j++) {
        int srow = qt * 64 + w * 16 + (g << 2) + j;
        float o = acco[f][j] / lr[j];
        size_t off = ((size_t)b * SS + srow) * (HH * DD) + h * DD + d;
        float gt = bf2f(Gs[off]);
        AttG[off] = f2bf(o * gt);
      }
    }
  }
}

// ---------------------------------------------------------------- launcher
extern "C" void kernel_launch(void* const* d_in, const int* in_sizes, int n_in,
                              void* d_out, int out_size, void* d_ws, size_t ws_size,
                              hipStream_t stream) {
  const float* hidden = (const float*)d_in[0];
  const float* rope   = (const float*)d_in[2];
  const float* Wq     = (const float*)d_in[5];
  const float* Wk     = (const float*)d_in[6];
  const float* Wv     = (const float*)d_in[7];
  const float* Wo     = (const float*)d_in[8];
  const float* qw     = (const float*)d_in[9];
  const float* kw     = (const float*)d_in[10];
  float* out = (float*)d_out;
  float* present = out + (size_t)BB * SS * HIDD; // 8,388,608

  char* ws = (char*)d_ws;
  u16t* Xb    = (u16t*)(ws);                              // 4096x2048 bf16   16.78MB
  u16t* Wt    = (u16t*)(ws + 16777216);                   // 5120x2048 bf16   20.97MB
  u16t* Wot   = (u16t*)(ws + 37748736);                   // 2048x2048 bf16    8.39MB
  u16t* Cqkv  = (u16t*)(ws + 46137344);                   // 4096x5120 bf16   41.94MB
  u16t* Qb    = (u16t*)(ws + 88080384);                   // (B,H,S,D) bf16   16.78MB
  u16t* Kb    = (u16t*)(ws + 104857600);                  // (B,KV,S,D) bf16   4.19MB
  u16t* Vtb   = (u16t*)(ws + 109051904);                  // (B,KV,D,S) bf16   4.19MB
  u16t* Gs    = (u16t*)(ws + 113246208);                  // (B,S,H*D) bf16   16.78MB
  u16t* AttG  = Xb;  // alias: Xb dead after QKV GEMM; AttG written by attention

  (void)hipFuncSetAttribute(reinterpret_cast<const void*>(gemm8<256, u16t>),
                            hipFuncAttributeMaxDynamicSharedMemorySize, 131072);
  (void)hipFuncSetAttribute(reinterpret_cast<const void*>(gemm8<128, float>),
                            hipFuncAttributeMaxDynamicSharedMemorySize, 98304);

  // 1+2. fused prep: cast hidden (8 elem/thr) + weight transposes (s16x8 stores)
  prep_all<<<4096 + 3584, 256, 0, stream>>>(hidden, Wq, Wk, Wv, Wo, Xb, Wt, Wot);
  // 3a. Q projection (N=4096): 256^2 8-phase, grid 16x16 = 256 = exactly 1 block/CU
  gemm8<256, u16t><<<(MM / 256) * (4096 / 256), 512, 131072, stream>>>(Xb, Wt, Cqkv, MM, NQKV, HIDD);
  // 3b. K+V projection with fused V epilogue (present f32 + Vtb bf16); grid 256
  gemm_kv<<<(MM / 128) * (1024 / 128), 256, 0, stream>>>(
      Xb, Wt + (size_t)4096 * HIDD, Cqkv, present, Vtb, HIDD);
  // 4. Q/K norm+rope (+present K, +sigmoid gate)
  qk_norm_rope<<<(BB * SS * (HH + KVH)) / 4, 256, 0, stream>>>(Cqkv, rope, qw, kw, Qb, Kb, Gs, present);
  // 5. flash attention v5.1 (round-12 verbatim)
  attn_kernel<<<BB * HH * (SS / 128), 256, 0, stream>>>(Qb, Kb, Vtb, Gs, AttG);
  // 6. output projection -> d_out: 256x128 8-phase, grid 16x16 = 256 = 1 block/CU
  gemm8<128, float><<<(MM / 256) * (HIDD / 128), 512, 98304, stream>>>(AttG, Wot, out, MM, HIDD, HIDD);
}

// Round 17
// 262.593 us; speedup vs baseline: 1.0548x; 1.0109x over previous
//
#include <hip/hip_runtime.h>
#include <hip/hip_bf16.h>
#include <cstdint>
#include <cstddef>

// Problem constants
#define BB   2
#define SS   2048
#define HIDD 2048
#define HH   16
#define KVH  4
#define DD   128
#define NQKV 5120   // H*2*D + KV*D + KV*D = 4096 + 512 + 512
#define MM   4096   // B*S

typedef unsigned short u16t;
typedef __attribute__((ext_vector_type(8))) short s16x8;
typedef __attribute__((ext_vector_type(4))) short s16x4;
typedef __attribute__((ext_vector_type(4))) float f32x4;

__device__ __forceinline__ u16t f2bf(float f) {
  unsigned u = __float_as_uint(f);
  u += 0x7fffu + ((u >> 16) & 1u);
  return (u16t)(u >> 16);
}
__device__ __forceinline__ float bf2f(u16t h) {
  return __uint_as_float(((unsigned)h) << 16);
}
__device__ __forceinline__ void gload_lds16(const void* g, void* l) {
  __builtin_amdgcn_global_load_lds(
      (const __attribute__((address_space(1))) unsigned int*)g,
      (__attribute__((address_space(3))) unsigned int*)l, 16, 0, 0);
}
__device__ __forceinline__ unsigned cvtpk_bf16(float lo, float hi) {
  unsigned r;
  asm("v_cvt_pk_bf16_f32 %0, %1, %2" : "=v"(r) : "v"(lo), "v"(hi));
  return r;
}
__device__ __forceinline__ f32x4 fmax4(f32x4 a, f32x4 b) {
  f32x4 r;
  r[0] = fmaxf(a[0], b[0]); r[1] = fmaxf(a[1], b[1]);
  r[2] = fmaxf(a[2], b[2]); r[3] = fmaxf(a[3], b[3]);
  return r;
}
// counted vmcnt via literal asm (compiler-ordering fence through "memory" clobber).
// Round-11/14 lessons: __builtin_amdgcn_s_waitcnt is NOT a memory fence; and
// defer-max (T13) breaks correctness on this pipelined structure -- banned.
template <int N>
__device__ __forceinline__ void waitvm() {
  static_assert(N == 0 || N == 3 || N == 4 || N == 6 || N == 8, "add literal");
  if constexpr (N == 0)      asm volatile("s_waitcnt vmcnt(0)" ::: "memory");
  else if constexpr (N == 3) asm volatile("s_waitcnt vmcnt(3)" ::: "memory");
  else if constexpr (N == 4) asm volatile("s_waitcnt vmcnt(4)" ::: "memory");
  else if constexpr (N == 6) asm volatile("s_waitcnt vmcnt(6)" ::: "memory");
  else if constexpr (N == 8) asm volatile("s_waitcnt vmcnt(8)" ::: "memory");
}

// ----------------------------------------- fused prep: cast hidden + transpose-cast all weights
__global__ __launch_bounds__(256) void prep_all(const float* __restrict__ hidden,
                                                const float* __restrict__ Wq,
                                                const float* __restrict__ Wk,
                                                const float* __restrict__ Wv,
                                                const float* __restrict__ Wo,
                                                u16t* __restrict__ Xb,
                                                u16t* __restrict__ Wt,
                                                u16t* __restrict__ Wot) {
  __shared__ float lds[64 * 65];
  int bid = blockIdx.x;
  int t = threadIdx.x;
  if (bid < 4096) {
    size_t i = ((size_t)bid * 256 + t) * 8;
    f32x4 v0 = *(const f32x4*)(hidden + i);
    f32x4 v1 = *(const f32x4*)(hidden + i + 4);
    s16x8 o;
    o[0] = (short)f2bf(v0[0]); o[1] = (short)f2bf(v0[1]);
    o[2] = (short)f2bf(v0[2]); o[3] = (short)f2bf(v0[3]);
    o[4] = (short)f2bf(v1[0]); o[5] = (short)f2bf(v1[1]);
    o[6] = (short)f2bf(v1[2]); o[7] = (short)f2bf(v1[3]);
    *(s16x8*)(Xb + i) = o;
    return;
  }
  bid -= 4096;
  const float* src; u16t* dst; int N;
  if (bid < 2048)      { src = Wq; dst = Wt;                         N = 4096; }
  else if (bid < 2304) { src = Wk; dst = Wt + (size_t)4096 * HIDD;   N = 512;  bid -= 2048; }
  else if (bid < 2560) { src = Wv; dst = Wt + (size_t)4608 * HIDD;   N = 512;  bid -= 2304; }
  else                 { src = Wo; dst = Wot;                        N = 2048; bid -= 2560; }
  const int ktiles = HIDD / 64; // 32
  int n0 = (bid / ktiles) << 6;
  int k0 = (bid % ktiles) << 6;
#pragma unroll
  for (int i = 0; i < 16; i++) {
    int idx = i * 256 + t;
    int r = idx >> 6, c = idx & 63;
    lds[c * 65 + r] = src[(size_t)(k0 + r) * N + n0 + c];
  }
  __syncthreads();
#pragma unroll
  for (int i = 0; i < 2; i++) {
    int idx = i * 256 + t;
    int rr = idx >> 3, k8 = (idx & 7) * 8;
    s16x8 o;
#pragma unroll
    for (int e = 0; e < 8; e++) o[e] = (short)f2bf(lds[rr * 65 + k8 + e]);
    *(s16x8*)(dst + (size_t)(n0 + rr) * HIDD + k0 + k8) = o;
  }
}

// ---------------------------------------------------------------- shared GEMM pieces
__device__ __forceinline__ s16x8 ldsfrag(const char* half, int r, int g) {
  return *(const s16x8*)(half + r * 64 + ((g ^ ((r >> 1) & 3)) << 4));
}
template <int NL>
__device__ __forceinline__ void stage_half(char* ldsbase, const u16t* gbase,
                                           int K, int kcol, int tid) {
#pragma unroll
  for (int i = 0; i < NL; i++) {
    int o16 = i * 512 + tid;
    int r = o16 >> 2;
    int cs = (o16 & 3) ^ ((r >> 1) & 3);
    gload_lds16(gbase + (size_t)r * K + kcol + cs * 8, ldsbase + o16 * 16);
  }
}

// ---------------------------------------------------------------- 256xBN 8-phase bf16 GEMM
// (used for O-proj with BN=128). grid = (M/256)*(n/BN); M/256 must be 16.
template <int BN, typename CT>
__global__ __launch_bounds__(512, 2) void gemm8(const u16t* __restrict__ A,
                                                const u16t* __restrict__ Bt,
                                                CT* __restrict__ C,
                                                int M, int N, int K) {
  constexpr int NLB = BN / 128;            // B-half loads/thread
  constexpr int AHALF = 16384, ASLOT = 32768;
  constexpr int BHALF = BN * 64, BSLOT = 2 * BHALF;
  constexpr int PAIR = 2 + NLB;            // loads per (A,B) half-tile pair
  constexpr int NI = BN / 64;              // B frags per wave
  extern __shared__ __align__(16) char lds[];
  char* As = lds;
  char* Bs = lds + 2 * ASLOT;
  int tid = threadIdx.x, lane = tid & 63, w = tid >> 6;
  int wm = w >> 2, wn = w & 3;
  int cpx = gridDim.x >> 3;                       // grid % 8 == 0
  int wgid = (blockIdx.x & 7) * cpx + (blockIdx.x >> 3);
  int bm = wgid & 15, bn = wgid >> 4;             // M/256 == 16
  int m0 = bm << 8, n0 = bn * BN;
  const u16t* Ag = A + (size_t)m0 * K;
  const u16t* Bg = Bt + (size_t)n0 * K;
  const int NT = K >> 6;

  stage_half<2>(As, Ag, K, 0, tid);
  stage_half<NLB>(Bs, Bg, K, 0, tid);
  stage_half<2>(As + AHALF, Ag, K, 32, tid);
  stage_half<NLB>(Bs + BHALF, Bg, K, 32, tid);
  stage_half<2>(As + ASLOT, Ag, K, 64, tid);
  stage_half<NLB>(Bs + BSLOT, Bg, K, 64, tid);
  waitvm<2 * PAIR>();
  __builtin_amdgcn_s_barrier();

  const f32x4 fz = {0.f, 0.f, 0.f, 0.f};
  f32x4 acc[8][NI];
#pragma unroll
  for (int i = 0; i < 8; i++)
#pragma unroll
    for (int j = 0; j < NI; j++) acc[i][j] = fz;
  s16x8 afr[4], bfr[NI];
  int g = lane >> 4;
  int rA = (lane & 15) + wm * 128;
  int rB = (lane & 15) + wn * (BN / 4);

  for (int kt = 0; kt < NT; kt++) {
    int cur = kt & 1;
    char* Acur = As + cur * ASLOT;
    char* Bcur = Bs + cur * BSLOT;
    char* Anxt = As + (cur ^ 1) * ASLOT;
    char* Bnxt = Bs + (cur ^ 1) * BSLOT;
#pragma unroll
    for (int ni = 0; ni < NI; ni++) bfr[ni] = ldsfrag(Bcur, rB + ni * 16, g);
#pragma unroll
    for (int mi = 0; mi < 4; mi++) afr[mi] = ldsfrag(Acur, rA + mi * 16, g);
    if (kt + 1 < NT) stage_half<2>(Anxt + AHALF, Ag, K, (kt + 1) * 64 + 32, tid);
    __builtin_amdgcn_s_barrier();
    asm volatile("s_waitcnt lgkmcnt(0)" ::: "memory");
    __builtin_amdgcn_s_setprio(1);
#pragma unroll
    for (int mi = 0; mi < 4; mi++)
#pragma unroll
      for (int ni = 0; ni < NI; ni++)
        acc[mi][ni] = __builtin_amdgcn_mfma_f32_16x16x32_bf16(afr[mi], bfr[ni], acc[mi][ni], 0, 0, 0);
    __builtin_amdgcn_s_setprio(0);
    __builtin_amdgcn_s_barrier();
#pragma unroll
    for (int mi = 0; mi < 4; mi++) afr[mi] = ldsfrag(Acur, rA + 64 + mi * 16, g);
    if (kt + 1 < NT) stage_half<NLB>(Bnxt + BHALF, Bg, K, (kt + 1) * 64 + 32, tid);
    __builtin_amdgcn_s_barrier();
    asm volatile("s_waitcnt lgkmcnt(0)" ::: "memory");
    __builtin_amdgcn_s_setprio(1);
#pragma unroll
    for (int mi = 0; mi < 4; mi++)
#pragma unroll
      for (int ni = 0; ni < NI; ni++)
        acc[4 + mi][ni] = __builtin_amdgcn_mfma_f32_16x16x32_bf16(afr[mi], bfr[ni], acc[4 + mi][ni], 0, 0, 0);
    __builtin_amdgcn_s_setprio(0);
    if (kt + 1 < NT) waitvm<2 * PAIR>();
    else             waitvm<0>();
    __builtin_amdgcn_s_barrier();
#pragma unroll
    for (int ni = 0; ni < NI; ni++) bfr[ni] = ldsfrag(Bcur + BHALF, rB + ni * 16, g);
#pragma unroll
    for (int mi = 0; mi < 4; mi++) afr[mi] = ldsfrag(Acur + AHALF, rA + mi * 16, g);
    if (kt + 2 < NT) stage_half<2>(Acur, Ag, K, (kt + 2) * 64, tid);
    __builtin_amdgcn_s_barrier();
    asm volatile("s_waitcnt lgkmcnt(0)" ::: "memory");
    __builtin_amdgcn_s_setprio(1);
#pragma unroll
    for (int mi = 0; mi < 4; mi++)
#pragma unroll
      for (int ni = 0; ni < NI; ni++)
        acc[mi][ni] = __builtin_amdgcn_mfma_f32_16x16x32_bf16(afr[mi], bfr[ni], acc[mi][ni], 0, 0, 0);
    __builtin_amdgcn_s_setprio(0);
    __builtin_amdgcn_s_barrier();
#pragma unroll
    for (int mi = 0; mi < 4; mi++) afr[mi] = ldsfrag(Acur + AHALF, rA + 64 + mi * 16, g);
    if (kt + 2 < NT) stage_half<NLB>(Bcur, Bg, K, (kt + 2) * 64, tid);
    __builtin_amdgcn_s_barrier();
    asm volatile("s_waitcnt lgkmcnt(0)" ::: "memory");
    __builtin_amdgcn_s_setprio(1);
#pragma unroll
    for (int mi = 0; mi < 4; mi++)
#pragma unroll
      for (int ni = 0; ni < NI; ni++)
        acc[4 + mi][ni] = __builtin_amdgcn_mfma_f32_16x16x32_bf16(afr[mi], bfr[ni], acc[4 + mi][ni], 0, 0, 0);
    __builtin_amdgcn_s_setprio(0);
    if (kt < NT - 1) {
      if (kt + 2 < NT) waitvm<2 * PAIR>();
      else             waitvm<PAIR>();
    }
    __builtin_amdgcn_s_barrier();
  }
#pragma unroll
  for (int mi = 0; mi < 8; mi++)
#pragma unroll
    for (int ni = 0; ni < NI; ni++) {
      int row0 = m0 + wm * 128 + mi * 16 + ((lane >> 4) << 2);
      int col = n0 + wn * (BN / 4) + ni * 16 + (lane & 15);
#pragma unroll
      for (int j = 0; j < 4; j++) {
        if constexpr (sizeof(CT) == 2)
          C[(size_t)(row0 + j) * N + col] = f2bf(acc[mi][ni][j]);
        else
          C[(size_t)(row0 + j) * N + col] = acc[mi][ni][j];
      }
    }
}

// ---------------------------------------------------------------- Q projection GEMM + fused norm/rope/gate
// BN=256: each block's 256-col tile = one head's [query(0..127) | gate(128..255)].
// Main loop identical to gemm8<256>. Epilogue: gate -> sigmoid -> Gs directly;
// query -> f32 LDS buffer (row-keyed granule swizzle) -> barrier -> per-row
// RMSNorm+RoPE (verbatim qk_norm_rope math) -> Qb (pre-scaled by log2(e)/sqrt(D)).
__global__ __launch_bounds__(512, 2) void gemm8q(const u16t* __restrict__ A,
                                                 const u16t* __restrict__ Bt,
                                                 const float* __restrict__ rope,
                                                 const float* __restrict__ qw,
                                                 u16t* __restrict__ Qb,   // (B,H,S,D)
                                                 u16t* __restrict__ Gs,   // (B,S,H*D)
                                                 int K) {
  constexpr int NLB = 2, AHALF = 16384, ASLOT = 32768;
  constexpr int BHALF = 16384, BSLOT = 32768;
  constexpr int PAIR = 4, NI = 4;
  extern __shared__ __align__(16) char lds[];
  char* As = lds;
  char* Bs = lds + 2 * ASLOT;
  int tid = threadIdx.x, lane = tid & 63, w = tid >> 6;
  int wm = w >> 2, wn = w & 3;
  int cpx = gridDim.x >> 3;
  int wgid = (blockIdx.x & 7) * cpx + (blockIdx.x >> 3);
  int bm = wgid & 15, bn = wgid >> 4;             // bn = head h
  int m0 = bm << 8, n0 = bn << 8;
  const u16t* Ag = A + (size_t)m0 * K;
  const u16t* Bg = Bt + (size_t)n0 * K;
  const int NT = K >> 6;

  stage_half<2>(As, Ag, K, 0, tid);
  stage_half<NLB>(Bs, Bg, K, 0, tid);
  stage_half<2>(As + AHALF, Ag, K, 32, tid);
  stage_half<NLB>(Bs + BHALF, Bg, K, 32, tid);
  stage_half<2>(As + ASLOT, Ag, K, 64, tid);
  stage_half<NLB>(Bs + BSLOT, Bg, K, 64, tid);
  waitvm<2 * PAIR>();
  __builtin_amdgcn_s_barrier();

  const f32x4 fz = {0.f, 0.f, 0.f, 0.f};
  f32x4 acc[8][NI];
#pragma unroll
  for (int i = 0; i < 8; i++)
#pragma unroll
    for (int j = 0; j < NI; j++) acc[i][j] = fz;
  s16x8 afr[4], bfr[NI];
  int g = lane >> 4;
  int rA = (lane & 15) + wm * 128;
  int rB = (lane & 15) + wn * 64;

  for (int kt = 0; kt < NT; kt++) {
    int cur = kt & 1;
    char* Acur = As + cur * ASLOT;
    char* Bcur = Bs + cur * BSLOT;
    char* Anxt = As + (cur ^ 1) * ASLOT;
    char* Bnxt = Bs + (cur ^ 1) * BSLOT;
#pragma unroll
    for (int ni = 0; ni < NI; ni++) bfr[ni] = ldsfrag(Bcur, rB + ni * 16, g);
#pragma unroll
    for (int mi = 0; mi < 4; mi++) afr[mi] = ldsfrag(Acur, rA + mi * 16, g);
    if (kt + 1 < NT) stage_half<2>(Anxt + AHALF, Ag, K, (kt + 1) * 64 + 32, tid);
    __builtin_amdgcn_s_barrier();
    asm volatile("s_waitcnt lgkmcnt(0)" ::: "memory");
    __builtin_amdgcn_s_setprio(1);
#pragma unroll
    for (int mi = 0; mi < 4; mi++)
#pragma unroll
      for (int ni = 0; ni < NI; ni++)
        acc[mi][ni] = __builtin_amdgcn_mfma_f32_16x16x32_bf16(afr[mi], bfr[ni], acc[mi][ni], 0, 0, 0);
    __builtin_amdgcn_s_setprio(0);
    __builtin_amdgcn_s_barrier();
#pragma unroll
    for (int mi = 0; mi < 4; mi++) afr[mi] = ldsfrag(Acur, rA + 64 + mi * 16, g);
    if (kt + 1 < NT) stage_half<NLB>(Bnxt + BHALF, Bg, K, (kt + 1) * 64 + 32, tid);
    __builtin_amdgcn_s_barrier();
    asm volatile("s_waitcnt lgkmcnt(0)" ::: "memory");
    __builtin_amdgcn_s_setprio(1);
#pragma unroll
    for (int mi = 0; mi < 4; mi++)
#pragma unroll
      for (int ni = 0; ni < NI; ni++)
        acc[4 + mi][ni] = __builtin_amdgcn_mfma_f32_16x16x32_bf16(afr[mi], bfr[ni], acc[4 + mi][ni], 0, 0, 0);
    __builtin_amdgcn_s_setprio(0);
    if (kt + 1 < NT) waitvm<2 * PAIR>();
    else             waitvm<0>();
    __builtin_amdgcn_s_barrier();
#pragma unroll
    for (int ni = 0; ni < NI; ni++) bfr[ni] = ldsfrag(Bcur + BHALF, rB + ni * 16, g);
#pragma unroll
    for (int mi = 0; mi < 4; mi++) afr[mi] = ldsfrag(Acur + AHALF, rA + mi * 16, g);
    if (kt + 2 < NT) stage_half<2>(Acur, Ag, K, (kt + 2) * 64, tid);
    __builtin_amdgcn_s_barrier();
    asm volatile("s_waitcnt lgkmcnt(0)" ::: "memory");
    __builtin_amdgcn_s_setprio(1);
#pragma unroll
    for (int mi = 0; mi < 4; mi++)
#pragma unroll
      for (int ni = 0; ni < NI; ni++)
        acc[mi][ni] = __builtin_amdgcn_mfma_f32_16x16x32_bf16(afr[mi], bfr[ni], acc[mi][ni], 0, 0, 0);
    __builtin_amdgcn_s_setprio(0);
    __builtin_amdgcn_s_barrier();
#pragma unroll
    for (int mi = 0; mi < 4; mi++) afr[mi] = ldsfrag(Acur + AHALF, rA + 64 + mi * 16, g);
    if (kt + 2 < NT) stage_half<NLB>(Bcur, Bg, K, (kt + 2) * 64, tid);
    __builtin_amdgcn_s_barrier();
    asm volatile("s_waitcnt lgkmcnt(0)" ::: "memory");
    __builtin_amdgcn_s_setprio(1);
#pragma unroll
    for (int mi = 0; mi < 4; mi++)
#pragma unroll
      for (int ni = 0; ni < NI; ni++)
        acc[4 + mi][ni] = __builtin_amdgcn_mfma_f32_16x16x32_bf16(afr[mi], bfr[ni], acc[4 + mi][ni], 0, 0, 0);
    __builtin_amdgcn_s_setprio(0);
    if (kt < NT - 1) {
      if (kt + 2 < NT) waitvm<2 * PAIR>();
      else             waitvm<PAIR>();
    }
    __builtin_amdgcn_s_barrier();
  }

  // ---- fused epilogue --------------------------------------------------
  int h = bn;
  float* qbuf = (float*)lds;   // 256 rows x 128 f32 (128KB), granule-swizzled
  if (wn < 2) {
    // query columns -> LDS (word = row*128 + ((gr ^ ((row>>2)&7))<<4 | (c&15)))
#pragma unroll
    for (int mi = 0; mi < 8; mi++)
#pragma unroll
      for (int ni = 0; ni < NI; ni++) {
        int rl0 = wm * 128 + mi * 16 + ((lane >> 4) << 2);
        int c = wn * 64 + ni * 16 + (lane & 15);
        int gr = c >> 4;
#pragma unroll
        for (int j = 0; j < 4; j++) {
          int rl = rl0 + j;
          qbuf[rl * 128 + (((gr ^ ((rl >> 2) & 7)) << 4) | (c & 15))] = acc[mi][ni][j];
        }
      }
  } else {
    // gate columns -> sigmoid -> Gs
#pragma unroll
    for (int mi = 0; mi < 8; mi++)
#pragma unroll
      for (int ni = 0; ni < NI; ni++) {
        int row0 = m0 + wm * 128 + mi * 16 + ((lane >> 4) << 2);
        int d = (wn - 2) * 64 + ni * 16 + (lane & 15);
#pragma unroll
        for (int j = 0; j < 4; j++) {
          int bb = (row0 + j) >> 11, s = (row0 + j) & 2047;
          float gv = acc[mi][ni][j];
          Gs[((size_t)(bb * SS + s)) * (HH * DD) + h * DD + d] =
              f2bf(1.f / (1.f + __expf(-gv)));
        }
      }
  }
  __syncthreads();
  // per-row RMSNorm + RoPE (verbatim qk_norm_rope Q math); wave w: rows w*32..+31
  float qwl = qw[lane], qwh = qw[64 + lane];
  const float SC = 0.08838834764831845f * 1.4426950408889634f;
  for (int r2 = 0; r2 < 32; r2++) {
    int rl = w * 32 + r2;
    int row0 = m0 + rl;
    int bb = row0 >> 11, s = row0 & 2047;
    int swz = ((rl >> 2) & 7) << 4;
    int cl = lane, ch = 64 + lane;
    float xlo = qbuf[rl * 128 + ((((cl >> 4) << 4) ^ swz) | (cl & 15))];
    float xhi = qbuf[rl * 128 + ((((ch >> 4) << 4) ^ swz) | (ch & 15))];
    float ss2 = xlo * xlo + xhi * xhi;
    ss2 += __shfl_xor(ss2, 1);  ss2 += __shfl_xor(ss2, 2);  ss2 += __shfl_xor(ss2, 4);
    ss2 += __shfl_xor(ss2, 8);  ss2 += __shfl_xor(ss2, 16); ss2 += __shfl_xor(ss2, 32);
    float r = rsqrtf(ss2 * (1.f / 128.f) + 1e-6f);
    float qlo = xlo * r * (1.f + qwl);
    float qhi = xhi * r * (1.f + qwh);
    const float* cs = rope + (size_t)s * 256;
    float clo = cs[lane], chi = cs[64 + lane];
    float slo = cs[128 + lane], shi = cs[192 + lane];
    float olo = (qlo * clo - qhi * slo) * SC;
    float ohi = (qhi * chi + qlo * shi) * SC;
    size_t qoff = (((size_t)bb * HH + h) * SS + s) * DD;
    Qb[qoff + lane] = f2bf(olo);
    Qb[qoff + 64 + lane] = f2bf(ohi);
  }
}

// ---------------------------------------------------------------- KV projection GEMM (m97 structure)
// bn 0..3 = K-heads -> Cqkv; bn 4..7 = V-heads -> present (f32) + Vtb (bf16).
__global__ __launch_bounds__(256) void gemm_kv(const u16t* __restrict__ A,
                                               const u16t* __restrict__ Bt,
                                               u16t* __restrict__ Cqkv,
                                               float* __restrict__ present,
                                               u16t* __restrict__ Vtb,
                                               int K) {
  __shared__ __align__(16) char As[128 * 64];
  __shared__ __align__(16) char Bs[128 * 64];
  int tid = threadIdx.x;
  int lane = tid & 63;
  int w = tid >> 6;
  int cpx = gridDim.x >> 3;
  int wgid = ((int)blockIdx.x & 7) * cpx + ((int)blockIdx.x >> 3);
  const int mtiles = MM >> 7;                 // 32
  int bm = wgid % mtiles;
  int bn = wgid / mtiles;                     // 0..7
  int m0 = bm << 7, n0 = bn << 7;
  int wr = (w >> 1) * 64, wc = (w & 1) * 64;

  const f32x4 fz = {0.f, 0.f, 0.f, 0.f};
  f32x4 acc[4][4];
#pragma unroll
  for (int i = 0; i < 4; i++)
#pragma unroll
    for (int j = 0; j < 4; j++) acc[i][j] = fz;

  for (int k0 = 0; k0 < K; k0 += 32) {
    __syncthreads();
#pragma unroll
    for (int i = 0; i < 2; i++) {
      int idx = i * 256 + tid;
      int r = idx >> 2, c = idx & 3;
      int csrc = c ^ ((r >> 1) & 3);
      gload_lds16(A + (size_t)(m0 + r) * K + k0 + csrc * 8, As + idx * 16);
      gload_lds16(Bt + (size_t)(n0 + r) * K + k0 + csrc * 8, Bs + idx * 16);
    }
    __syncthreads();
    s16x8 af[4], bf[4];
    int g = lane >> 4;
#pragma unroll
    for (int mi = 0; mi < 4; mi++) {
      int r = wr + mi * 16 + (lane & 15);
      af[mi] = *(const s16x8*)(As + r * 64 + ((g ^ ((r >> 1) & 3)) << 4));
    }
#pragma unroll
    for (int ni = 0; ni < 4; ni++) {
      int r = wc + ni * 16 + (lane & 15);
      bf[ni] = *(const s16x8*)(Bs + r * 64 + ((g ^ ((r >> 1) & 3)) << 4));
    }
#pragma unroll
    for (int mi = 0; mi < 4; mi++)
#pragma unroll
      for (int ni = 0; ni < 4; ni++)
        acc[mi][ni] = __builtin_amdgcn_mfma_f32_16x16x32_bf16(af[mi], bf[ni], acc[mi][ni], 0, 0, 0);
  }
  if (bn < 4) {
#pragma unroll
    for (int mi = 0; mi < 4; mi++)
#pragma unroll
      for (int ni = 0; ni < 4; ni++) {
        int row0 = m0 + wr + mi * 16 + ((lane >> 4) << 2);
        int col = n0 + wc + ni * 16 + (lane & 15);
#pragma unroll
        for (int j = 0; j < 4; j++)
          Cqkv[(size_t)(row0 + j) * NQKV + 4096 + col] = f2bf(acc[mi][ni][j]);
      }
  } else {
#pragma unroll
    for (int mi = 0; mi < 4; mi++)
#pragma unroll
      for (int ni = 0; ni < 4; ni++) {
        int row0 = m0 + wr + mi * 16 + ((lane >> 4) << 2);
        int vcol = (n0 - 512) + wc + ni * 16 + (lane & 15);
        int kv = vcol >> 7, d = vcol & 127;
        int bb = row0 >> 11, sp = row0 & 2047;
        size_t pbase = (((size_t)(bb * 2 * KVH + KVH + kv)) * SS + sp) * DD + d;
#pragma unroll
        for (int j = 0; j < 4; j++)
          present[pbase + (size_t)j * DD] = acc[mi][ni][j];
        s16x4 pk;
        pk[0] = (short)f2bf(acc[mi][ni][0]);
        pk[1] = (short)f2bf(acc[mi][ni][1]);
        pk[2] = (short)f2bf(acc[mi][ni][2]);
        pk[3] = (short)f2bf(acc[mi][ni][3]);
        *(s16x4*)(Vtb + ((size_t)(bb * KVH + kv) * DD + d) * SS + sp) = pk;
      }
  }
}

// ------------------------------------------------- K-only RMSNorm + RoPE (Q handled in gemm8q)
__global__ __launch_bounds__(256) void k_norm_rope(const u16t* __restrict__ Cqkv,
                                                   const float* __restrict__ rope,
                                                   const float* __restrict__ kw,
                                                   u16t* __restrict__ Kb,   // (B,KV,S,D)
                                                   float* __restrict__ present) {
  int wid = blockIdx.x * 4 + (threadIdx.x >> 6);  // 0 .. B*S*KV-1 (16384)
  int lane = threadIdx.x & 63;
  int b = wid >> 13;
  int rem = wid & 8191;
  int s = rem >> 2, kv = rem & 3;
  const u16t* base = Cqkv + (size_t)(b * SS + s) * NQKV + 4096 + kv * 128;
  float xlo = bf2f(base[lane]), xhi = bf2f(base[64 + lane]);
  float ss = xlo * xlo + xhi * xhi;
  ss += __shfl_xor(ss, 1);  ss += __shfl_xor(ss, 2);  ss += __shfl_xor(ss, 4);
  ss += __shfl_xor(ss, 8);  ss += __shfl_xor(ss, 16); ss += __shfl_xor(ss, 32);
  float r = rsqrtf(ss * (1.f / 128.f) + 1e-6f);
  float klo = xlo * r * (1.f + kw[lane]);
  float khi = xhi * r * (1.f + kw[64 + lane]);
  const float* cs = rope + (size_t)s * 256;
  float clo = cs[lane], chi = cs[64 + lane];
  float slo = cs[128 + lane], shi = cs[192 + lane];
  float olo = klo * clo - khi * slo;
  float ohi = khi * chi + klo * shi;
  size_t koff = (((size_t)b * KVH + kv) * SS + s) * DD;
  Kb[koff + lane] = f2bf(olo);
  Kb[koff + 64 + lane] = f2bf(ohi);
  size_t poff = (((size_t)(b * 2 * KVH + kv)) * SS + s) * DD;
  present[poff + lane] = olo;
  present[poff + 64 + lane] = ohi;
}

// ---------------------------------------------------------------- flash attention v5.1 (round-12 verbatim)
__global__ __launch_bounds__(256, 2) void attn_kernel(const u16t* __restrict__ Qb,   // (B,H,S,D) pre-scaled
                                                      const u16t* __restrict__ Kb,   // (B,KV,S,D)
                                                      const u16t* __restrict__ Vtb,  // (B,KV,D,S)
                                                      const u16t* __restrict__ Gs,   // (B,S,H*D)
                                                      u16t* __restrict__ AttG) {     // (B,S,H*D)
  __shared__ __align__(16) char Ks[2 * 16384];  // 64 rows x 256B, chunk xor (r&7)
  __shared__ __align__(16) char Vs[2 * 16384];  // V^T: 128 rows x 128B, chunk xor (d&7)
  __shared__ __align__(16) char Ps[4 * 2048];   // per-wave P: [q:16][k-granule xor (q&7)]

  int tid = threadIdx.x, lane = tid & 63, w = tid >> 6;
  int x = blockIdx.x & 7;          // XCD grouping: each XCD owns one (b,kv)
  int b = x >> 2, kv = x & 3;
  int rr = blockIdx.x >> 3;        // 0..63
  int h = kv * 4 + (rr & 3);
  int p = rr >> 2;                 // 0..15: pair {31-p, p}

  const u16t* Kbase = Kb + (((size_t)(b * KVH + kv)) * SS) * DD;
  const u16t* Vbase = Vtb + (((size_t)(b * KVH + kv)) * DD) * SS;

  auto stageK = [&](int kt, int buf) {
#pragma unroll
    for (int i = 0; i < 4; i++) {
      int idx = i * 256 + tid;
      int r_ = idx >> 4, c_ = idx & 15;
      gload_lds16(Kbase + (size_t)(kt * 64 + r_) * DD + (c_ ^ (r_ & 7)) * 8,
                  Ks + buf * 16384 + idx * 16);
    }
  };
  auto stageV = [&](int kt, int buf) {
#pragma unroll
    for (int i = 0; i < 4; i++) {
      int idx = i * 256 + tid;
      int r_ = idx >> 3, c_ = idx & 7;
      gload_lds16(Vbase + (size_t)r_ * SS + kt * 64 + (c_ ^ (r_ & 7)) * 8,
                  Vs + buf * 16384 + idx * 16);
    }
  };

  const f32x4 fz = {0.f, 0.f, 0.f, 0.f};
  int g = lane >> 4;
  int q15 = lane & 15;
  int q7 = q15 & 7;
  char* pq = Ps + w * 2048 + q15 * 128;   // this lane's q-row in P
  int cur = 0;

  // ---- hoisted LDS offsets (loop-invariant; live in VGPRs)
  int ka[4][4];
#pragma unroll
  for (int ni = 0; ni < 4; ni++)
#pragma unroll
    for (int ks = 0; ks < 4; ks++)
      ka[ni][ks] = (ni * 16 + q15) * 256 + (((ks * 4 + g) ^ q7) << 4);
  int va[2][8];
#pragma unroll
  for (int ks2 = 0; ks2 < 2; ks2++)
#pragma unroll
    for (int f = 0; f < 8; f++)
      va[ks2][f] = (f * 16 + q15) * 128 + (((ks2 * 4 + g) ^ q7) << 4);
  int pr_[2];
#pragma unroll
  for (int ks2 = 0; ks2 < 2; ks2++) pr_[ks2] = ((ks2 * 4 + g) ^ q7) << 4;
  int pw_[4];
#pragma unroll
  for (int ni = 0; ni < 4; ni++)
    pw_[ni] = (((ni * 2 + (g >> 1)) ^ q7) << 4) + ((g & 1) << 3);

  stageK(0, 0);
  stageV(0, 0);

  for (int seg = 0; seg < 2; seg++) {
    int qt = (seg == 0) ? (31 - p) : p;
    const u16t* Qbase = Qb + (((size_t)(b * HH + h)) * SS + qt * 64) * DD;
    s16x8 qf[4];
    {
      const u16t* qrow = Qbase + (size_t)(w * 16 + q15) * DD + g * 8;
#pragma unroll
      for (int ks = 0; ks < 4; ks++) qf[ks] = *(const s16x8*)(qrow + ks * 32);
    }
    f32x4 acco[8];
#pragma unroll
    for (int f = 0; f < 8; f++) acco[f] = fz;
    float mrun = -INFINITY, lrun = 0.f;

    if (seg == 0) {
      asm volatile("s_waitcnt vmcnt(0)" ::: "memory");
      __builtin_amdgcn_s_barrier();
    }

    for (int kt = 0; kt <= qt; kt++) {
      bool havenext = (kt < qt) || (seg == 0);
      if (havenext) {
        int nk = (kt < qt) ? (kt + 1) : 0;
        stageK(nk, cur ^ 1);
        stageV(nk, cur ^ 1);
      }
      const char* kc = Ks + (cur << 14);
      const char* vc = Vs + (cur << 14);
      f32x4 accs[4];
#pragma unroll
      for (int ni = 0; ni < 4; ni++) accs[ni] = fz;
#pragma unroll
      for (int ni = 0; ni < 4; ni++)
#pragma unroll
        for (int ks = 0; ks < 4; ks++) {
          s16x8 bfk = *(const s16x8*)(kc + ka[ni][ks]);
          accs[ni] = __builtin_amdgcn_mfma_f32_16x16x32_bf16(bfk, qf[ks], accs[ni], 0, 0, 0);
        }
      if (kt == qt) {
        int ql = w * 16 + q15;
#pragma unroll
        for (int ni = 0; ni < 4; ni++)
#pragma unroll
          for (int j = 0; j < 4; j++) {
            int kl = ni * 16 + (g << 2) + j;
            if (kl > ql) accs[ni][j] = -1e30f;
          }
      }
      f32x4 m4 = fmax4(fmax4(accs[0], accs[1]), fmax4(accs[2], accs[3]));
      float mt = fmaxf(fmaxf(m4[0], m4[1]), fmaxf(m4[2], m4[3]));
      mt = fmaxf(mt, __shfl_xor(mt, 16));
      mt = fmaxf(mt, __shfl_xor(mt, 32));
      float mnew = fmaxf(mrun, mt);
      float alpha = __builtin_amdgcn_exp2f(mrun - mnew);
      mrun = mnew;
#pragma unroll
      for (int ni = 0; ni < 4; ni++)
#pragma unroll
        for (int j = 0; j < 4; j++)
          accs[ni][j] = __builtin_amdgcn_exp2f(accs[ni][j] - mnew);
      f32x4 s4 = (accs[0] + accs[1]) + (accs[2] + accs[3]);
      float rs = (s4[0] + s4[1]) + (s4[2] + s4[3]);
      rs += __shfl_xor(rs, 16);
      rs += __shfl_xor(rs, 32);
      lrun = lrun * alpha + rs;
      float ar[4];
#pragma unroll
      for (int j = 0; j < 4; j++) ar[j] = __shfl(alpha, (g << 2) + j);
#pragma unroll
      for (int f = 0; f < 8; f++)
#pragma unroll
        for (int j = 0; j < 4; j++) acco[f][j] *= ar[j];

#pragma unroll
      for (int ni = 0; ni < 4; ni++) {
        uint2 pk;
        pk.x = cvtpk_bf16(accs[ni][0], accs[ni][1]);
        pk.y = cvtpk_bf16(accs[ni][2], accs[ni][3]);
        *(uint2*)(pq + pw_[ni]) = pk;
      }
#pragma unroll
      for (int ks2 = 0; ks2 < 2; ks2++) {
        s16x8 pa = *(const s16x8*)(pq + pr_[ks2]);
#pragma unroll
        for (int f = 0; f < 8; f++) {
          s16x8 vf = *(const s16x8*)(vc + va[ks2][f]);
          acco[f] = __builtin_amdgcn_mfma_f32_16x16x32_bf16(pa, vf, acco[f], 0, 0, 0);
        }
      }
      if (havenext) {
        asm volatile("s_waitcnt vmcnt(0)" ::: "memory");
        __builtin_amdgcn_s_barrier();
        cur ^= 1;
      }
    }
    float lr[4];
#pragma unroll
    for (int j = 0; j < 4; j++) lr[j] = __shfl(lrun, (g << 2) + j);
#pragma unroll
    for (int f = 0; f < 8; f++) {
      int d = f * 16 + q15;
#pragma unroll
      for (int j = 0; j < 4; j++) {
        int srow = qt * 64 + w * 16 + (g << 2) + j;
        float o = acco[f][j] / lr[j];
        size_t off = ((size_t)b * SS + srow) * (HH * DD) + h * DD + d;
        float gt = bf2f(Gs[off]);
        AttG[off] = f2bf(o * gt);
      }
    }
  }
}

// ---------------------------------------------------------------- launcher
extern "C" void kernel_launch(void* const* d_in, const int* in_sizes, int n_in,
                              void* d_out, int out_size, void* d_ws, size_t ws_size,
                              hipStream_t stream) {
  const float* hidden = (const float*)d_in[0];
  const float* rope   = (const float*)d_in[2];
  const float* Wq     = (const float*)d_in[5];
  const float* Wk     = (const float*)d_in[6];
  const float* Wv     = (const float*)d_in[7];
  const float* Wo     = (const float*)d_in[8];
  const float* qw     = (const float*)d_in[9];
  const float* kw     = (const float*)d_in[10];
  float* out = (float*)d_out;
  float* present = out + (size_t)BB * SS * HIDD; // 8,388,608

  char* ws = (char*)d_ws;
  u16t* Xb    = (u16t*)(ws);                              // 4096x2048 bf16   16.78MB
  u16t* Wt    = (u16t*)(ws + 16777216);                   // 5120x2048 bf16   20.97MB
  u16t* Wot   = (u16t*)(ws + 37748736);                   // 2048x2048 bf16    8.39MB
  u16t* Cqkv  = (u16t*)(ws + 46137344);                   // K cols only      41.94MB region
  u16t* Qb    = (u16t*)(ws + 88080384);                   // (B,H,S,D) bf16   16.78MB
  u16t* Kb    = (u16t*)(ws + 104857600);                  // (B,KV,S,D) bf16   4.19MB
  u16t* Vtb   = (u16t*)(ws + 109051904);                  // (B,KV,D,S) bf16   4.19MB
  u16t* Gs    = (u16t*)(ws + 113246208);                  // (B,S,H*D) bf16   16.78MB
  u16t* AttG  = Xb;  // alias: Xb dead after projections; AttG written by attention

  (void)hipFuncSetAttribute(reinterpret_cast<const void*>(gemm8q),
                            hipFuncAttributeMaxDynamicSharedMemorySize, 131072);
  (void)hipFuncSetAttribute(reinterpret_cast<const void*>(gemm8<128, float>),
                            hipFuncAttributeMaxDynamicSharedMemorySize, 98304);

  // 1+2. fused prep: cast hidden + weight transposes
  prep_all<<<4096 + 3584, 256, 0, stream>>>(hidden, Wq, Wk, Wv, Wo, Xb, Wt, Wot);
  // 3a. Q projection + fused RMSNorm/RoPE/gate: grid 16x16 = 256 = 1 block/CU
  gemm8q<<<(MM / 256) * (4096 / 256), 512, 131072, stream>>>(Xb, Wt, rope, qw, Qb, Gs, HIDD);
  // 3b. K+V projection with fused V epilogue; grid 256
  gemm_kv<<<(MM / 128) * (1024 / 128), 256, 0, stream>>>(
      Xb, Wt + (size_t)4096 * HIDD, Cqkv, present, Vtb, HIDD);
  // 4. K-only norm+rope (+present K)
  k_norm_rope<<<(BB * SS * KVH) / 4, 256, 0, stream>>>(Cqkv, rope, kw, Kb, present);
  // 5. flash attention v5.1 (round-12 verbatim)
  attn_kernel<<<BB * HH * (SS / 128), 256, 0, stream>>>(Qb, Kb, Vtb, Gs, AttG);
  // 6. output projection -> d_out: 256x128 8-phase, grid 16x16 = 256 = 1 block/CU
  gemm8<128, float><<<(MM / 256) * (HIDD / 128), 512, 98304, stream>>>(AttG, Wot, out, MM, HIDD, HIDD);
}

// Round 18
// 261.062 us; speedup vs baseline: 1.0610x; 1.0059x over previous
//
#include <hip/hip_runtime.h>
#include <hip/hip_bf16.h>
#include <cstdint>
#include <cstddef>

// Problem constants
#define BB   2
#define SS   2048
#define HIDD 2048
#define HH   16
#define KVH  4
#define DD   128
#define NQKV 5120   // H*2*D + KV*D + KV*D = 4096 + 512 + 512
#define MM   4096   // B*S

typedef unsigned short u16t;
typedef __attribute__((ext_vector_type(8))) short s16x8;
typedef __attribute__((ext_vector_type(4))) short s16x4;
typedef __attribute__((ext_vector_type(4))) float f32x4;

__device__ __forceinline__ u16t f2bf(float f) {
  unsigned u = __float_as_uint(f);
  u += 0x7fffu + ((u >> 16) & 1u);
  return (u16t)(u >> 16);
}
__device__ __forceinline__ float bf2f(u16t h) {
  return __uint_as_float(((unsigned)h) << 16);
}
__device__ __forceinline__ void gload_lds16(const void* g, void* l) {
  __builtin_amdgcn_global_load_lds(
      (const __attribute__((address_space(1))) unsigned int*)g,
      (__attribute__((address_space(3))) unsigned int*)l, 16, 0, 0);
}
__device__ __forceinline__ unsigned cvtpk_bf16(float lo, float hi) {
  unsigned r;
  asm("v_cvt_pk_bf16_f32 %0, %1, %2" : "=v"(r) : "v"(lo), "v"(hi));
  return r;
}
__device__ __forceinline__ f32x4 fmax4(f32x4 a, f32x4 b) {
  f32x4 r;
  r[0] = fmaxf(a[0], b[0]); r[1] = fmaxf(a[1], b[1]);
  r[2] = fmaxf(a[2], b[2]); r[3] = fmaxf(a[3], b[3]);
  return r;
}
// counted vmcnt via literal asm (compiler-ordering fence through "memory" clobber).
// Round-11/14 lessons: __builtin_amdgcn_s_waitcnt is NOT a memory fence; and
// defer-max (T13) breaks correctness on this pipelined structure -- banned.
template <int N>
__device__ __forceinline__ void waitvm() {
  static_assert(N == 0 || N == 3 || N == 4 || N == 6 || N == 8, "add literal");
  if constexpr (N == 0)      asm volatile("s_waitcnt vmcnt(0)" ::: "memory");
  else if constexpr (N == 3) asm volatile("s_waitcnt vmcnt(3)" ::: "memory");
  else if constexpr (N == 4) asm volatile("s_waitcnt vmcnt(4)" ::: "memory");
  else if constexpr (N == 6) asm volatile("s_waitcnt vmcnt(6)" ::: "memory");
  else if constexpr (N == 8) asm volatile("s_waitcnt vmcnt(8)" ::: "memory");
}

// ----------------------------------------- fused prep: cast hidden + transpose-cast all weights
__global__ __launch_bounds__(256) void prep_all(const float* __restrict__ hidden,
                                                const float* __restrict__ Wq,
                                                const float* __restrict__ Wk,
                                                const float* __restrict__ Wv,
                                                const float* __restrict__ Wo,
                                                u16t* __restrict__ Xb,
                                                u16t* __restrict__ Wt,
                                                u16t* __restrict__ Wot) {
  __shared__ float lds[64 * 65];
  int bid = blockIdx.x;
  int t = threadIdx.x;
  if (bid < 4096) {
    size_t i = ((size_t)bid * 256 + t) * 8;
    f32x4 v0 = *(const f32x4*)(hidden + i);
    f32x4 v1 = *(const f32x4*)(hidden + i + 4);
    s16x8 o;
    o[0] = (short)f2bf(v0[0]); o[1] = (short)f2bf(v0[1]);
    o[2] = (short)f2bf(v0[2]); o[3] = (short)f2bf(v0[3]);
    o[4] = (short)f2bf(v1[0]); o[5] = (short)f2bf(v1[1]);
    o[6] = (short)f2bf(v1[2]); o[7] = (short)f2bf(v1[3]);
    *(s16x8*)(Xb + i) = o;
    return;
  }
  bid -= 4096;
  const float* src; u16t* dst; int N;
  if (bid < 2048)      { src = Wq; dst = Wt;                         N = 4096; }
  else if (bid < 2304) { src = Wk; dst = Wt + (size_t)4096 * HIDD;   N = 512;  bid -= 2048; }
  else if (bid < 2560) { src = Wv; dst = Wt + (size_t)4608 * HIDD;   N = 512;  bid -= 2304; }
  else                 { src = Wo; dst = Wot;                        N = 2048; bid -= 2560; }
  const int ktiles = HIDD / 64; // 32
  int n0 = (bid / ktiles) << 6;
  int k0 = (bid % ktiles) << 6;
#pragma unroll
  for (int i = 0; i < 16; i++) {
    int idx = i * 256 + t;
    int r = idx >> 6, c = idx & 63;
    lds[c * 65 + r] = src[(size_t)(k0 + r) * N + n0 + c];
  }
  __syncthreads();
#pragma unroll
  for (int i = 0; i < 2; i++) {
    int idx = i * 256 + t;
    int rr = idx >> 3, k8 = (idx & 7) * 8;
    s16x8 o;
#pragma unroll
    for (int e = 0; e < 8; e++) o[e] = (short)f2bf(lds[rr * 65 + k8 + e]);
    *(s16x8*)(dst + (size_t)(n0 + rr) * HIDD + k0 + k8) = o;
  }
}

// ---------------------------------------------------------------- shared GEMM pieces
__device__ __forceinline__ s16x8 ldsfrag(const char* half, int r, int g) {
  return *(const s16x8*)(half + r * 64 + ((g ^ ((r >> 1) & 3)) << 4));
}
template <int NL>
__device__ __forceinline__ void stage_half(char* ldsbase, const u16t* gbase,
                                           int K, int kcol, int tid) {
#pragma unroll
  for (int i = 0; i < NL; i++) {
    int o16 = i * 512 + tid;
    int r = o16 >> 2;
    int cs = (o16 & 3) ^ ((r >> 1) & 3);
    gload_lds16(gbase + (size_t)r * K + kcol + cs * 8, ldsbase + o16 * 16);
  }
}

// ---------------------------------------------------------------- 256xBN 8-phase bf16 GEMM
// (used for O-proj with BN=128). grid = (M/256)*(n/BN); M/256 must be 16.
template <int BN, typename CT>
__global__ __launch_bounds__(512, 2) void gemm8(const u16t* __restrict__ A,
                                                const u16t* __restrict__ Bt,
                                                CT* __restrict__ C,
                                                int M, int N, int K) {
  constexpr int NLB = BN / 128;            // B-half loads/thread
  constexpr int AHALF = 16384, ASLOT = 32768;
  constexpr int BHALF = BN * 64, BSLOT = 2 * BHALF;
  constexpr int PAIR = 2 + NLB;            // loads per (A,B) half-tile pair
  constexpr int NI = BN / 64;              // B frags per wave
  extern __shared__ __align__(16) char lds[];
  char* As = lds;
  char* Bs = lds + 2 * ASLOT;
  int tid = threadIdx.x, lane = tid & 63, w = tid >> 6;
  int wm = w >> 2, wn = w & 3;
  int cpx = gridDim.x >> 3;                       // grid % 8 == 0
  int wgid = (blockIdx.x & 7) * cpx + (blockIdx.x >> 3);
  int bm = wgid & 15, bn = wgid >> 4;             // M/256 == 16
  int m0 = bm << 8, n0 = bn * BN;
  const u16t* Ag = A + (size_t)m0 * K;
  const u16t* Bg = Bt + (size_t)n0 * K;
  const int NT = K >> 6;

  stage_half<2>(As, Ag, K, 0, tid);
  stage_half<NLB>(Bs, Bg, K, 0, tid);
  stage_half<2>(As + AHALF, Ag, K, 32, tid);
  stage_half<NLB>(Bs + BHALF, Bg, K, 32, tid);
  stage_half<2>(As + ASLOT, Ag, K, 64, tid);
  stage_half<NLB>(Bs + BSLOT, Bg, K, 64, tid);
  waitvm<2 * PAIR>();
  __builtin_amdgcn_s_barrier();

  const f32x4 fz = {0.f, 0.f, 0.f, 0.f};
  f32x4 acc[8][NI];
#pragma unroll
  for (int i = 0; i < 8; i++)
#pragma unroll
    for (int j = 0; j < NI; j++) acc[i][j] = fz;
  s16x8 afr[4], bfr[NI];
  int g = lane >> 4;
  int rA = (lane & 15) + wm * 128;
  int rB = (lane & 15) + wn * (BN / 4);

  for (int kt = 0; kt < NT; kt++) {
    int cur = kt & 1;
    char* Acur = As + cur * ASLOT;
    char* Bcur = Bs + cur * BSLOT;
    char* Anxt = As + (cur ^ 1) * ASLOT;
    char* Bnxt = Bs + (cur ^ 1) * BSLOT;
#pragma unroll
    for (int ni = 0; ni < NI; ni++) bfr[ni] = ldsfrag(Bcur, rB + ni * 16, g);
#pragma unroll
    for (int mi = 0; mi < 4; mi++) afr[mi] = ldsfrag(Acur, rA + mi * 16, g);
    if (kt + 1 < NT) stage_half<2>(Anxt + AHALF, Ag, K, (kt + 1) * 64 + 32, tid);
    __builtin_amdgcn_s_barrier();
    asm volatile("s_waitcnt lgkmcnt(0)" ::: "memory");
    __builtin_amdgcn_s_setprio(1);
#pragma unroll
    for (int mi = 0; mi < 4; mi++)
#pragma unroll
      for (int ni = 0; ni < NI; ni++)
        acc[mi][ni] = __builtin_amdgcn_mfma_f32_16x16x32_bf16(afr[mi], bfr[ni], acc[mi][ni], 0, 0, 0);
    __builtin_amdgcn_s_setprio(0);
    __builtin_amdgcn_s_barrier();
#pragma unroll
    for (int mi = 0; mi < 4; mi++) afr[mi] = ldsfrag(Acur, rA + 64 + mi * 16, g);
    if (kt + 1 < NT) stage_half<NLB>(Bnxt + BHALF, Bg, K, (kt + 1) * 64 + 32, tid);
    __builtin_amdgcn_s_barrier();
    asm volatile("s_waitcnt lgkmcnt(0)" ::: "memory");
    __builtin_amdgcn_s_setprio(1);
#pragma unroll
    for (int mi = 0; mi < 4; mi++)
#pragma unroll
      for (int ni = 0; ni < NI; ni++)
        acc[4 + mi][ni] = __builtin_amdgcn_mfma_f32_16x16x32_bf16(afr[mi], bfr[ni], acc[4 + mi][ni], 0, 0, 0);
    __builtin_amdgcn_s_setprio(0);
    if (kt + 1 < NT) waitvm<2 * PAIR>();
    else             waitvm<0>();
    __builtin_amdgcn_s_barrier();
#pragma unroll
    for (int ni = 0; ni < NI; ni++) bfr[ni] = ldsfrag(Bcur + BHALF, rB + ni * 16, g);
#pragma unroll
    for (int mi = 0; mi < 4; mi++) afr[mi] = ldsfrag(Acur + AHALF, rA + mi * 16, g);
    if (kt + 2 < NT) stage_half<2>(Acur, Ag, K, (kt + 2) * 64, tid);
    __builtin_amdgcn_s_barrier();
    asm volatile("s_waitcnt lgkmcnt(0)" ::: "memory");
    __builtin_amdgcn_s_setprio(1);
#pragma unroll
    for (int mi = 0; mi < 4; mi++)
#pragma unroll
      for (int ni = 0; ni < NI; ni++)
        acc[mi][ni] = __builtin_amdgcn_mfma_f32_16x16x32_bf16(afr[mi], bfr[ni], acc[mi][ni], 0, 0, 0);
    __builtin_amdgcn_s_setprio(0);
    __builtin_amdgcn_s_barrier();
#pragma unroll
    for (int mi = 0; mi < 4; mi++) afr[mi] = ldsfrag(Acur + AHALF, rA + 64 + mi * 16, g);
    if (kt + 2 < NT) stage_half<NLB>(Bcur, Bg, K, (kt + 2) * 64, tid);
    __builtin_amdgcn_s_barrier();
    asm volatile("s_waitcnt lgkmcnt(0)" ::: "memory");
    __builtin_amdgcn_s_setprio(1);
#pragma unroll
    for (int mi = 0; mi < 4; mi++)
#pragma unroll
      for (int ni = 0; ni < NI; ni++)
        acc[4 + mi][ni] = __builtin_amdgcn_mfma_f32_16x16x32_bf16(afr[mi], bfr[ni], acc[4 + mi][ni], 0, 0, 0);
    __builtin_amdgcn_s_setprio(0);
    if (kt < NT - 1) {
      if (kt + 2 < NT) waitvm<2 * PAIR>();
      else             waitvm<PAIR>();
    }
    __builtin_amdgcn_s_barrier();
  }
#pragma unroll
  for (int mi = 0; mi < 8; mi++)
#pragma unroll
    for (int ni = 0; ni < NI; ni++) {
      int row0 = m0 + wm * 128 + mi * 16 + ((lane >> 4) << 2);
      int col = n0 + wn * (BN / 4) + ni * 16 + (lane & 15);
#pragma unroll
      for (int j = 0; j < 4; j++) {
        if constexpr (sizeof(CT) == 2)
          C[(size_t)(row0 + j) * N + col] = f2bf(acc[mi][ni][j]);
        else
          C[(size_t)(row0 + j) * N + col] = acc[mi][ni][j];
      }
    }
}

// ---------------------------------------------------------------- Q projection GEMM + fused norm/rope/gate
// BN=256: each block's 256-col tile = one head's [query(0..127) | gate(128..255)].
// Main loop identical to gemm8<256>. Epilogue v2 (round-18): sum-of-squares
// computed IN REGISTERS (bulk 4-shuffle q15 butterflies, 32 independent chains)
// and parked in a 2KB LDS array; the per-row norm loop then has NO shuffles and
// fully independent iterations (pipelinable rope loads).
__global__ __launch_bounds__(512, 2) void gemm8q(const u16t* __restrict__ A,
                                                 const u16t* __restrict__ Bt,
                                                 const float* __restrict__ rope,
                                                 const float* __restrict__ qw,
                                                 u16t* __restrict__ Qb,   // (B,H,S,D)
                                                 u16t* __restrict__ Gs,   // (B,S,H*D)
                                                 int K) {
  constexpr int NLB = 2, AHALF = 16384, ASLOT = 32768;
  constexpr int BHALF = 16384, BSLOT = 32768;
  constexpr int PAIR = 4, NI = 4;
  extern __shared__ __align__(16) char lds[];
  char* As = lds;
  char* Bs = lds + 2 * ASLOT;
  int tid = threadIdx.x, lane = tid & 63, w = tid >> 6;
  int wm = w >> 2, wn = w & 3;
  int cpx = gridDim.x >> 3;
  int wgid = (blockIdx.x & 7) * cpx + (blockIdx.x >> 3);
  int bm = wgid & 15, bn = wgid >> 4;             // bn = head h
  int m0 = bm << 8, n0 = bn << 8;
  const u16t* Ag = A + (size_t)m0 * K;
  const u16t* Bg = Bt + (size_t)n0 * K;
  const int NT = K >> 6;

  stage_half<2>(As, Ag, K, 0, tid);
  stage_half<NLB>(Bs, Bg, K, 0, tid);
  stage_half<2>(As + AHALF, Ag, K, 32, tid);
  stage_half<NLB>(Bs + BHALF, Bg, K, 32, tid);
  stage_half<2>(As + ASLOT, Ag, K, 64, tid);
  stage_half<NLB>(Bs + BSLOT, Bg, K, 64, tid);
  waitvm<2 * PAIR>();
  __builtin_amdgcn_s_barrier();

  const f32x4 fz = {0.f, 0.f, 0.f, 0.f};
  f32x4 acc[8][NI];
#pragma unroll
  for (int i = 0; i < 8; i++)
#pragma unroll
    for (int j = 0; j < NI; j++) acc[i][j] = fz;
  s16x8 afr[4], bfr[NI];
  int g = lane >> 4;
  int rA = (lane & 15) + wm * 128;
  int rB = (lane & 15) + wn * 64;

  for (int kt = 0; kt < NT; kt++) {
    int cur = kt & 1;
    char* Acur = As + cur * ASLOT;
    char* Bcur = Bs + cur * BSLOT;
    char* Anxt = As + (cur ^ 1) * ASLOT;
    char* Bnxt = Bs + (cur ^ 1) * BSLOT;
#pragma unroll
    for (int ni = 0; ni < NI; ni++) bfr[ni] = ldsfrag(Bcur, rB + ni * 16, g);
#pragma unroll
    for (int mi = 0; mi < 4; mi++) afr[mi] = ldsfrag(Acur, rA + mi * 16, g);
    if (kt + 1 < NT) stage_half<2>(Anxt + AHALF, Ag, K, (kt + 1) * 64 + 32, tid);
    __builtin_amdgcn_s_barrier();
    asm volatile("s_waitcnt lgkmcnt(0)" ::: "memory");
    __builtin_amdgcn_s_setprio(1);
#pragma unroll
    for (int mi = 0; mi < 4; mi++)
#pragma unroll
      for (int ni = 0; ni < NI; ni++)
        acc[mi][ni] = __builtin_amdgcn_mfma_f32_16x16x32_bf16(afr[mi], bfr[ni], acc[mi][ni], 0, 0, 0);
    __builtin_amdgcn_s_setprio(0);
    __builtin_amdgcn_s_barrier();
#pragma unroll
    for (int mi = 0; mi < 4; mi++) afr[mi] = ldsfrag(Acur, rA + 64 + mi * 16, g);
    if (kt + 1 < NT) stage_half<NLB>(Bnxt + BHALF, Bg, K, (kt + 1) * 64 + 32, tid);
    __builtin_amdgcn_s_barrier();
    asm volatile("s_waitcnt lgkmcnt(0)" ::: "memory");
    __builtin_amdgcn_s_setprio(1);
#pragma unroll
    for (int mi = 0; mi < 4; mi++)
#pragma unroll
      for (int ni = 0; ni < NI; ni++)
        acc[4 + mi][ni] = __builtin_amdgcn_mfma_f32_16x16x32_bf16(afr[mi], bfr[ni], acc[4 + mi][ni], 0, 0, 0);
    __builtin_amdgcn_s_setprio(0);
    if (kt + 1 < NT) waitvm<2 * PAIR>();
    else             waitvm<0>();
    __builtin_amdgcn_s_barrier();
#pragma unroll
    for (int ni = 0; ni < NI; ni++) bfr[ni] = ldsfrag(Bcur + BHALF, rB + ni * 16, g);
#pragma unroll
    for (int mi = 0; mi < 4; mi++) afr[mi] = ldsfrag(Acur + AHALF, rA + mi * 16, g);
    if (kt + 2 < NT) stage_half<2>(Acur, Ag, K, (kt + 2) * 64, tid);
    __builtin_amdgcn_s_barrier();
    asm volatile("s_waitcnt lgkmcnt(0)" ::: "memory");
    __builtin_amdgcn_s_setprio(1);
#pragma unroll
    for (int mi = 0; mi < 4; mi++)
#pragma unroll
      for (int ni = 0; ni < NI; ni++)
        acc[mi][ni] = __builtin_amdgcn_mfma_f32_16x16x32_bf16(afr[mi], bfr[ni], acc[mi][ni], 0, 0, 0);
    __builtin_amdgcn_s_setprio(0);
    __builtin_amdgcn_s_barrier();
#pragma unroll
    for (int mi = 0; mi < 4; mi++) afr[mi] = ldsfrag(Acur + AHALF, rA + 64 + mi * 16, g);
    if (kt + 2 < NT) stage_half<NLB>(Bcur, Bg, K, (kt + 2) * 64, tid);
    __builtin_amdgcn_s_barrier();
    asm volatile("s_waitcnt lgkmcnt(0)" ::: "memory");
    __builtin_amdgcn_s_setprio(1);
#pragma unroll
    for (int mi = 0; mi < 4; mi++)
#pragma unroll
      for (int ni = 0; ni < NI; ni++)
        acc[4 + mi][ni] = __builtin_amdgcn_mfma_f32_16x16x32_bf16(afr[mi], bfr[ni], acc[4 + mi][ni], 0, 0, 0);
    __builtin_amdgcn_s_setprio(0);
    if (kt < NT - 1) {
      if (kt + 2 < NT) waitvm<2 * PAIR>();
      else             waitvm<PAIR>();
    }
    __builtin_amdgcn_s_barrier();
  }

  // ---- fused epilogue v2 ------------------------------------------------
  int h = bn;
  float* qbuf = (float*)lds;                    // 256 rows x 128 f32, granule-swizzled
  float* ssqb = (float*)(lds + 131072);         // [2][256] partial sum-of-squares
  int q15 = lane & 15;
  if (wn < 2) {
    // per-(mi8,j) partial ssq over this wave's 4 ni values, then bulk q15 butterflies
    float ps[8][4];
#pragma unroll
    for (int mi = 0; mi < 8; mi++)
#pragma unroll
      for (int j = 0; j < 4; j++) {
        float s = 0.f;
#pragma unroll
        for (int ni = 0; ni < NI; ni++) { float v = acc[mi][ni][j]; s += v * v; }
        ps[mi][j] = s;
      }
#pragma unroll
    for (int d = 1; d < 16; d <<= 1)
#pragma unroll
      for (int mi = 0; mi < 8; mi++)
#pragma unroll
        for (int j = 0; j < 4; j++) ps[mi][j] += __shfl_xor(ps[mi][j], d);
    // query values -> qbuf (row-keyed granule swizzle)
#pragma unroll
    for (int mi = 0; mi < 8; mi++)
#pragma unroll
      for (int ni = 0; ni < NI; ni++) {
        int rl0 = wm * 128 + ((mi >> 2) << 6) + (mi & 3) * 16 + ((lane >> 4) << 2);
        int c = wn * 64 + ni * 16 + q15;
        int gr = c >> 4;
#pragma unroll
        for (int j = 0; j < 4; j++) {
          int rl = rl0 + j;
          qbuf[rl * 128 + (((gr ^ ((rl >> 2) & 7)) << 4) | (c & 15))] = acc[mi][ni][j];
        }
      }
    // one lane per row-group writes the partial ssq
    if (q15 == 0) {
#pragma unroll
      for (int mi = 0; mi < 8; mi++)
#pragma unroll
        for (int j = 0; j < 4; j++) {
          int rl = wm * 128 + ((mi >> 2) << 6) + (mi & 3) * 16 + (g << 2) + j;
          ssqb[wn * 256 + rl] = ps[mi][j];
        }
    }
  } else {
    // gate columns -> sigmoid -> Gs
#pragma unroll
    for (int mi = 0; mi < 8; mi++)
#pragma unroll
      for (int ni = 0; ni < NI; ni++) {
        int row0 = m0 + wm * 128 + ((mi >> 2) << 6) + (mi & 3) * 16 + ((lane >> 4) << 2);
        int d = (wn - 2) * 64 + ni * 16 + q15;
#pragma unroll
        for (int j = 0; j < 4; j++) {
          int bb = (row0 + j) >> 11, s = (row0 + j) & 2047;
          float gv = acc[mi][ni][j];
          Gs[((size_t)(bb * SS + s)) * (HH * DD) + h * DD + d] =
              f2bf(1.f / (1.f + __expf(-gv)));
        }
      }
  }
  __syncthreads();
  // per-row RMSNorm + RoPE (no shuffles; iterations independent)
  float qwl = qw[lane], qwh = qw[64 + lane];
  const float SC = 0.08838834764831845f * 1.4426950408889634f;
#pragma unroll 4
  for (int r2 = 0; r2 < 32; r2++) {
    int rl = w * 32 + r2;
    int row0 = m0 + rl;
    int bb = row0 >> 11, s = row0 & 2047;
    int swz = ((rl >> 2) & 7) << 4;
    int cl = lane, ch = 64 + lane;
    float xlo = qbuf[rl * 128 + ((((cl >> 4) << 4) ^ swz) | (cl & 15))];
    float xhi = qbuf[rl * 128 + ((((ch >> 4) << 4) ^ swz) | (ch & 15))];
    float ss2 = ssqb[rl] + ssqb[256 + rl];
    float r = rsqrtf(ss2 * (1.f / 128.f) + 1e-6f);
    float qlo = xlo * r * (1.f + qwl);
    float qhi = xhi * r * (1.f + qwh);
    const float* cs = rope + (size_t)s * 256;
    float clo = cs[lane], chi = cs[64 + lane];
    float slo = cs[128 + lane], shi = cs[192 + lane];
    float olo = (qlo * clo - qhi * slo) * SC;
    float ohi = (qhi * chi + qlo * shi) * SC;
    size_t qoff = (((size_t)bb * HH + h) * SS + s) * DD;
    Qb[qoff + lane] = f2bf(olo);
    Qb[qoff + 64 + lane] = f2bf(ohi);
  }
}

// ---------------------------------------------------------------- KV projection GEMM (m97 structure)
// bn 0..3 = K-heads -> Cqkv; bn 4..7 = V-heads -> present (f32) + Vtb (bf16).
__global__ __launch_bounds__(256) void gemm_kv(const u16t* __restrict__ A,
                                               const u16t* __restrict__ Bt,
                                               u16t* __restrict__ Cqkv,
                                               float* __restrict__ present,
                                               u16t* __restrict__ Vtb,
                                               int K) {
  __shared__ __align__(16) char As[128 * 64];
  __shared__ __align__(16) char Bs[128 * 64];
  int tid = threadIdx.x;
  int lane = tid & 63;
  int w = tid >> 6;
  int cpx = gridDim.x >> 3;
  int wgid = ((int)blockIdx.x & 7) * cpx + ((int)blockIdx.x >> 3);
  const int mtiles = MM >> 7;                 // 32
  int bm = wgid % mtiles;
  int bn = wgid / mtiles;                     // 0..7
  int m0 = bm << 7, n0 = bn << 7;
  int wr = (w >> 1) * 64, wc = (w & 1) * 64;

  const f32x4 fz = {0.f, 0.f, 0.f, 0.f};
  f32x4 acc[4][4];
#pragma unroll
  for (int i = 0; i < 4; i++)
#pragma unroll
    for (int j = 0; j < 4; j++) acc[i][j] = fz;

  for (int k0 = 0; k0 < K; k0 += 32) {
    __syncthreads();
#pragma unroll
    for (int i = 0; i < 2; i++) {
      int idx = i * 256 + tid;
      int r = idx >> 2, c = idx & 3;
      int csrc = c ^ ((r >> 1) & 3);
      gload_lds16(A + (size_t)(m0 + r) * K + k0 + csrc * 8, As + idx * 16);
      gload_lds16(Bt + (size_t)(n0 + r) * K + k0 + csrc * 8, Bs + idx * 16);
    }
    __syncthreads();
    s16x8 af[4], bf[4];
    int g = lane >> 4;
#pragma unroll
    for (int mi = 0; mi < 4; mi++) {
      int r = wr + mi * 16 + (lane & 15);
      af[mi] = *(const s16x8*)(As + r * 64 + ((g ^ ((r >> 1) & 3)) << 4));
    }
#pragma unroll
    for (int ni = 0; ni < 4; ni++) {
      int r = wc + ni * 16 + (lane & 15);
      bf[ni] = *(const s16x8*)(Bs + r * 64 + ((g ^ ((r >> 1) & 3)) << 4));
    }
#pragma unroll
    for (int mi = 0; mi < 4; mi++)
#pragma unroll
      for (int ni = 0; ni < 4; ni++)
        acc[mi][ni] = __builtin_amdgcn_mfma_f32_16x16x32_bf16(af[mi], bf[ni], acc[mi][ni], 0, 0, 0);
  }
  if (bn < 4) {
#pragma unroll
    for (int mi = 0; mi < 4; mi++)
#pragma unroll
      for (int ni = 0; ni < 4; ni++) {
        int row0 = m0 + wr + mi * 16 + ((lane >> 4) << 2);
        int col = n0 + wc + ni * 16 + (lane & 15);
#pragma unroll
        for (int j = 0; j < 4; j++)
          Cqkv[(size_t)(row0 + j) * NQKV + 4096 + col] = f2bf(acc[mi][ni][j]);
      }
  } else {
#pragma unroll
    for (int mi = 0; mi < 4; mi++)
#pragma unroll
      for (int ni = 0; ni < 4; ni++) {
        int row0 = m0 + wr + mi * 16 + ((lane >> 4) << 2);
        int vcol = (n0 - 512) + wc + ni * 16 + (lane & 15);
        int kv = vcol >> 7, d = vcol & 127;
        int bb = row0 >> 11, sp = row0 & 2047;
        size_t pbase = (((size_t)(bb * 2 * KVH + KVH + kv)) * SS + sp) * DD + d;
#pragma unroll
        for (int j = 0; j < 4; j++)
          present[pbase + (size_t)j * DD] = acc[mi][ni][j];
        s16x4 pk;
        pk[0] = (short)f2bf(acc[mi][ni][0]);
        pk[1] = (short)f2bf(acc[mi][ni][1]);
        pk[2] = (short)f2bf(acc[mi][ni][2]);
        pk[3] = (short)f2bf(acc[mi][ni][3]);
        *(s16x4*)(Vtb + ((size_t)(bb * KVH + kv) * DD + d) * SS + sp) = pk;
      }
  }
}

// ------------------------------------------------- K-only RMSNorm + RoPE (Q handled in gemm8q)
__global__ __launch_bounds__(256) void k_norm_rope(const u16t* __restrict__ Cqkv,
                                                   const float* __restrict__ rope,
                                                   const float* __restrict__ kw,
                                                   u16t* __restrict__ Kb,   // (B,KV,S,D)
                                                   float* __restrict__ present) {
  int wid = blockIdx.x * 4 + (threadIdx.x >> 6);  // 0 .. B*S*KV-1 (16384)
  int lane = threadIdx.x & 63;
  int b = wid >> 13;
  int rem = wid & 8191;
  int s = rem >> 2, kv = rem & 3;
  const u16t* base = Cqkv + (size_t)(b * SS + s) * NQKV + 4096 + kv * 128;
  float xlo = bf2f(base[lane]), xhi = bf2f(base[64 + lane]);
  float ss = xlo * xlo + xhi * xhi;
  ss += __shfl_xor(ss, 1);  ss += __shfl_xor(ss, 2);  ss += __shfl_xor(ss, 4);
  ss += __shfl_xor(ss, 8);  ss += __shfl_xor(ss, 16); ss += __shfl_xor(ss, 32);
  float r = rsqrtf(ss * (1.f / 128.f) + 1e-6f);
  float klo = xlo * r * (1.f + kw[lane]);
  float khi = xhi * r * (1.f + kw[64 + lane]);
  const float* cs = rope + (size_t)s * 256;
  float clo = cs[lane], chi = cs[64 + lane];
  float slo = cs[128 + lane], shi = cs[192 + lane];
  float olo = klo * clo - khi * slo;
  float ohi = khi * chi + klo * shi;
  size_t koff = (((size_t)b * KVH + kv) * SS + s) * DD;
  Kb[koff + lane] = f2bf(olo);
  Kb[koff + 64 + lane] = f2bf(ohi);
  size_t poff = (((size_t)(b * 2 * KVH + kv)) * SS + s) * DD;
  present[poff + lane] = olo;
  present[poff + 64 + lane] = ohi;
}

// ---------------------------------------------------------------- flash attention v5.1 (round-12 verbatim)
__global__ __launch_bounds__(256, 2) void attn_kernel(const u16t* __restrict__ Qb,   // (B,H,S,D) pre-scaled
                                                      const u16t* __restrict__ Kb,   // (B,KV,S,D)
                                                      const u16t* __restrict__ Vtb,  // (B,KV,D,S)
                                                      const u16t* __restrict__ Gs,   // (B,S,H*D)
                                                      u16t* __restrict__ AttG) {     // (B,S,H*D)
  __shared__ __align__(16) char Ks[2 * 16384];  // 64 rows x 256B, chunk xor (r&7)
  __shared__ __align__(16) char Vs[2 * 16384];  // V^T: 128 rows x 128B, chunk xor (d&7)
  __shared__ __align__(16) char Ps[4 * 2048];   // per-wave P: [q:16][k-granule xor (q&7)]

  int tid = threadIdx.x, lane = tid & 63, w = tid >> 6;
  int x = blockIdx.x & 7;          // XCD grouping: each XCD owns one (b,kv)
  int b = x >> 2, kv = x & 3;
  int rr = blockIdx.x >> 3;        // 0..63
  int h = kv * 4 + (rr & 3);
  int p = rr >> 2;                 // 0..15: pair {31-p, p}

  const u16t* Kbase = Kb + (((size_t)(b * KVH + kv)) * SS) * DD;
  const u16t* Vbase = Vtb + (((size_t)(b * KVH + kv)) * DD) * SS;

  auto stageK = [&](int kt, int buf) {
#pragma unroll
    for (int i = 0; i < 4; i++) {
      int idx = i * 256 + tid;
      int r_ = idx >> 4, c_ = idx & 15;
      gload_lds16(Kbase + (size_t)(kt * 64 + r_) * DD + (c_ ^ (r_ & 7)) * 8,
                  Ks + buf * 16384 + idx * 16);
    }
  };
  auto stageV = [&](int kt, int buf) {
#pragma unroll
    for (int i = 0; i < 4; i++) {
      int idx = i * 256 + tid;
      int r_ = idx >> 3, c_ = idx & 7;
      gload_lds16(Vbase + (size_t)r_ * SS + kt * 64 + (c_ ^ (r_ & 7)) * 8,
                  Vs + buf * 16384 + idx * 16);
    }
  };

  const f32x4 fz = {0.f, 0.f, 0.f, 0.f};
  int g = lane >> 4;
  int q15 = lane & 15;
  int q7 = q15 & 7;
  char* pq = Ps + w * 2048 + q15 * 128;   // this lane's q-row in P
  int cur = 0;

  int ka[4][4];
#pragma unroll
  for (int ni = 0; ni < 4; ni++)
#pragma unroll
    for (int ks = 0; ks < 4; ks++)
      ka[ni][ks] = (ni * 16 + q15) * 256 + (((ks * 4 + g) ^ q7) << 4);
  int va[2][8];
#pragma unroll
  for (int ks2 = 0; ks2 < 2; ks2++)
#pragma unroll
    for (int f = 0; f < 8; f++)
      va[ks2][f] = (f * 16 + q15) * 128 + (((ks2 * 4 + g) ^ q7) << 4);
  int pr_[2];
#pragma unroll
  for (int ks2 = 0; ks2 < 2; ks2++) pr_[ks2] = ((ks2 * 4 + g) ^ q7) << 4;
  int pw_[4];
#pragma unroll
  for (int ni = 0; ni < 4; ni++)
    pw_[ni] = (((ni * 2 + (g >> 1)) ^ q7) << 4) + ((g & 1) << 3);

  stageK(0, 0);
  stageV(0, 0);

  for (int seg = 0; seg < 2; seg++) {
    int qt = (seg == 0) ? (31 - p) : p;
    const u16t* Qbase = Qb + (((size_t)(b * HH + h)) * SS + qt * 64) * DD;
    s16x8 qf[4];
    {
      const u16t* qrow = Qbase + (size_t)(w * 16 + q15) * DD + g * 8;
#pragma unroll
      for (int ks = 0; ks < 4; ks++) qf[ks] = *(const s16x8*)(qrow + ks * 32);
    }
    f32x4 acco[8];
#pragma unroll
    for (int f = 0; f < 8; f++) acco[f] = fz;
    float mrun = -INFINITY, lrun = 0.f;

    if (seg == 0) {
      asm volatile("s_waitcnt vmcnt(0)" ::: "memory");
      __builtin_amdgcn_s_barrier();
    }

    for (int kt = 0; kt <= qt; kt++) {
      bool havenext = (kt < qt) || (seg == 0);
      if (havenext) {
        int nk = (kt < qt) ? (kt + 1) : 0;
        stageK(nk, cur ^ 1);
        stageV(nk, cur ^ 1);
      }
      const char* kc = Ks + (cur << 14);
      const char* vc = Vs + (cur << 14);
      f32x4 accs[4];
#pragma unroll
      for (int ni = 0; ni < 4; ni++) accs[ni] = fz;
#pragma unroll
      for (int ni = 0; ni < 4; ni++)
#pragma unroll
        for (int ks = 0; ks < 4; ks++) {
          s16x8 bfk = *(const s16x8*)(kc + ka[ni][ks]);
          accs[ni] = __builtin_amdgcn_mfma_f32_16x16x32_bf16(bfk, qf[ks], accs[ni], 0, 0, 0);
        }
      if (kt == qt) {
        int ql = w * 16 + q15;
#pragma unroll
        for (int ni = 0; ni < 4; ni++)
#pragma unroll
          for (int j = 0; j < 4; j++) {
            int kl = ni * 16 + (g << 2) + j;
            if (kl > ql) accs[ni][j] = -1e30f;
          }
      }
      f32x4 m4 = fmax4(fmax4(accs[0], accs[1]), fmax4(accs[2], accs[3]));
      float mt = fmaxf(fmaxf(m4[0], m4[1]), fmaxf(m4[2], m4[3]));
      mt = fmaxf(mt, __shfl_xor(mt, 16));
      mt = fmaxf(mt, __shfl_xor(mt, 32));
      float mnew = fmaxf(mrun, mt);
      float alpha = __builtin_amdgcn_exp2f(mrun - mnew);
      mrun = mnew;
#pragma unroll
      for (int ni = 0; ni < 4; ni++)
#pragma unroll
        for (int j = 0; j < 4; j++)
          accs[ni][j] = __builtin_amdgcn_exp2f(accs[ni][j] - mnew);
      f32x4 s4 = (accs[0] + accs[1]) + (accs[2] + accs[3]);
      float rs = (s4[0] + s4[1]) + (s4[2] + s4[3]);
      rs += __shfl_xor(rs, 16);
      rs += __shfl_xor(rs, 32);
      lrun = lrun * alpha + rs;
      float ar[4];
#pragma unroll
      for (int j = 0; j < 4; j++) ar[j] = __shfl(alpha, (g << 2) + j);
#pragma unroll
      for (int f = 0; f < 8; f++)
#pragma unroll
        for (int j = 0; j < 4; j++) acco[f][j] *= ar[j];

#pragma unroll
      for (int ni = 0; ni < 4; ni++) {
        uint2 pk;
        pk.x = cvtpk_bf16(accs[ni][0], accs[ni][1]);
        pk.y = cvtpk_bf16(accs[ni][2], accs[ni][3]);
        *(uint2*)(pq + pw_[ni]) = pk;
      }
#pragma unroll
      for (int ks2 = 0; ks2 < 2; ks2++) {
        s16x8 pa = *(const s16x8*)(pq + pr_[ks2]);
#pragma unroll
        for (int f = 0; f < 8; f++) {
          s16x8 vf = *(const s16x8*)(vc + va[ks2][f]);
          acco[f] = __builtin_amdgcn_mfma_f32_16x16x32_bf16(pa, vf, acco[f], 0, 0, 0);
        }
      }
      if (havenext) {
        asm volatile("s_waitcnt vmcnt(0)" ::: "memory");
        __builtin_amdgcn_s_barrier();
        cur ^= 1;
      }
    }
    float lr[4];
#pragma unroll
    for (int j = 0; j < 4; j++) lr[j] = __shfl(lrun, (g << 2) + j);
#pragma unroll
    for (int f = 0; f < 8; f++) {
      int d = f * 16 + q15;
#pragma unroll
      for (int j = 0; j < 4; j++) {
        int srow = qt * 64 + w * 16 + (g << 2) + j;
        float o = acco[f][j] / lr[j];
        size_t off = ((size_t)b * SS + srow) * (HH * DD) + h * DD + d;
        float gt = bf2f(Gs[off]);
        AttG[off] = f2bf(o * gt);
      }
    }
  }
}

// ---------------------------------------------------------------- launcher
extern "C" void kernel_launch(void* const* d_in, const int* in_sizes, int n_in,
                              void* d_out, int out_size, void* d_ws, size_t ws_size,
                              hipStream_t stream) {
  const float* hidden = (const float*)d_in[0];
  const float* rope   = (const float*)d_in[2];
  const float* Wq     = (const float*)d_in[5];
  const float* Wk     = (const float*)d_in[6];
  const float* Wv     = (const float*)d_in[7];
  const float* Wo     = (const float*)d_in[8];
  const float* qw     = (const float*)d_in[9];
  const float* kw     = (const float*)d_in[10];
  float* out = (float*)d_out;
  float* present = out + (size_t)BB * SS * HIDD; // 8,388,608

  char* ws = (char*)d_ws;
  u16t* Xb    = (u16t*)(ws);                              // 4096x2048 bf16   16.78MB
  u16t* Wt    = (u16t*)(ws + 16777216);                   // 5120x2048 bf16   20.97MB
  u16t* Wot   = (u16t*)(ws + 37748736);                   // 2048x2048 bf16    8.39MB
  u16t* Cqkv  = (u16t*)(ws + 46137344);                   // K cols only      41.94MB region
  u16t* Qb    = (u16t*)(ws + 88080384);                   // (B,H,S,D) bf16   16.78MB
  u16t* Kb    = (u16t*)(ws + 104857600);                  // (B,KV,S,D) bf16   4.19MB
  u16t* Vtb   = (u16t*)(ws + 109051904);                  // (B,KV,D,S) bf16   4.19MB
  u16t* Gs    = (u16t*)(ws + 113246208);                  // (B,S,H*D) bf16   16.78MB
  u16t* AttG  = Xb;  // alias: Xb dead after projections; AttG written by attention

  (void)hipFuncSetAttribute(reinterpret_cast<const void*>(gemm8q),
                            hipFuncAttributeMaxDynamicSharedMemorySize, 133120);
  (void)hipFuncSetAttribute(reinterpret_cast<const void*>(gemm8<128, float>),
                            hipFuncAttributeMaxDynamicSharedMemorySize, 98304);

  // 1+2. fused prep: cast hidden + weight transposes
  prep_all<<<4096 + 3584, 256, 0, stream>>>(hidden, Wq, Wk, Wv, Wo, Xb, Wt, Wot);
  // 3a. Q projection + fused RMSNorm/RoPE/gate (epilogue v2): grid 256 = 1 block/CU
  gemm8q<<<(MM / 256) * (4096 / 256), 512, 133120, stream>>>(Xb, Wt, rope, qw, Qb, Gs, HIDD);
  // 3b. K+V projection with fused V epilogue; grid 256
  gemm_kv<<<(MM / 128) * (1024 / 128), 256, 0, stream>>>(
      Xb, Wt + (size_t)4096 * HIDD, Cqkv, present, Vtb, HIDD);
  // 4. K-only norm+rope (+present K)
  k_norm_rope<<<(BB * SS * KVH) / 4, 256, 0, stream>>>(Cqkv, rope, kw, Kb, present);
  // 5. flash attention v5.1 (round-12 verbatim)
  attn_kernel<<<BB * HH * (SS / 128), 256, 0, stream>>>(Qb, Kb, Vtb, Gs, AttG);
  // 6. output projection -> d_out: 256x128 8-phase, grid 16x16 = 256 = 1 block/CU
  gemm8<128, float><<<(MM / 256) * (HIDD / 128), 512, 98304, stream>>>(AttG, Wot, out, MM, HIDD, HIDD);
}

// Round 19
// 257.809 us; speedup vs baseline: 1.0744x; 1.0126x over previous
//
#include <hip/hip_runtime.h>
#include <hip/hip_bf16.h>
#include <cstdint>
#include <cstddef>

// Problem constants
#define BB   2
#define SS   2048
#define HIDD 2048
#define HH   16
#define KVH  4
#define DD   128
#define NQKV 5120   // H*2*D + KV*D + KV*D = 4096 + 512 + 512
#define MM   4096   // B*S

typedef unsigned short u16t;
typedef __attribute__((ext_vector_type(8))) short s16x8;
typedef __attribute__((ext_vector_type(4))) short s16x4;
typedef __attribute__((ext_vector_type(4))) float f32x4;

__device__ __forceinline__ u16t f2bf(float f) {
  unsigned u = __float_as_uint(f);
  u += 0x7fffu + ((u >> 16) & 1u);
  return (u16t)(u >> 16);
}
__device__ __forceinline__ float bf2f(u16t h) {
  return __uint_as_float(((unsigned)h) << 16);
}
__device__ __forceinline__ void gload_lds16(const void* g, void* l) {
  __builtin_amdgcn_global_load_lds(
      (const __attribute__((address_space(1))) unsigned int*)g,
      (__attribute__((address_space(3))) unsigned int*)l, 16, 0, 0);
}
__device__ __forceinline__ unsigned cvtpk_bf16(float lo, float hi) {
  unsigned r;
  asm("v_cvt_pk_bf16_f32 %0, %1, %2" : "=v"(r) : "v"(lo), "v"(hi));
  return r;
}
__device__ __forceinline__ f32x4 fmax4(f32x4 a, f32x4 b) {
  f32x4 r;
  r[0] = fmaxf(a[0], b[0]); r[1] = fmaxf(a[1], b[1]);
  r[2] = fmaxf(a[2], b[2]); r[3] = fmaxf(a[3], b[3]);
  return r;
}
// counted vmcnt via literal asm (compiler-ordering fence through "memory" clobber).
// Round-11/14 lessons: __builtin_amdgcn_s_waitcnt is NOT a memory fence; and
// defer-max (T13) breaks correctness on this pipelined structure -- banned.
template <int N>
__device__ __forceinline__ void waitvm() {
  static_assert(N == 0 || N == 3 || N == 4 || N == 6 || N == 8, "add literal");
  if constexpr (N == 0)      asm volatile("s_waitcnt vmcnt(0)" ::: "memory");
  else if constexpr (N == 3) asm volatile("s_waitcnt vmcnt(3)" ::: "memory");
  else if constexpr (N == 4) asm volatile("s_waitcnt vmcnt(4)" ::: "memory");
  else if constexpr (N == 6) asm volatile("s_waitcnt vmcnt(6)" ::: "memory");
  else if constexpr (N == 8) asm volatile("s_waitcnt vmcnt(8)" ::: "memory");
}

// ----------------------------------------- fused prep: cast hidden + transpose-cast all weights
__global__ __launch_bounds__(256) void prep_all(const float* __restrict__ hidden,
                                                const float* __restrict__ Wq,
                                                const float* __restrict__ Wk,
                                                const float* __restrict__ Wv,
                                                const float* __restrict__ Wo,
                                                u16t* __restrict__ Xb,
                                                u16t* __restrict__ Wt,
                                                u16t* __restrict__ Wot) {
  __shared__ float lds[64 * 65];
  int bid = blockIdx.x;
  int t = threadIdx.x;
  if (bid < 4096) {
    size_t i = ((size_t)bid * 256 + t) * 8;
    f32x4 v0 = *(const f32x4*)(hidden + i);
    f32x4 v1 = *(const f32x4*)(hidden + i + 4);
    s16x8 o;
    o[0] = (short)f2bf(v0[0]); o[1] = (short)f2bf(v0[1]);
    o[2] = (short)f2bf(v0[2]); o[3] = (short)f2bf(v0[3]);
    o[4] = (short)f2bf(v1[0]); o[5] = (short)f2bf(v1[1]);
    o[6] = (short)f2bf(v1[2]); o[7] = (short)f2bf(v1[3]);
    *(s16x8*)(Xb + i) = o;
    return;
  }
  bid -= 4096;
  const float* src; u16t* dst; int N;
  if (bid < 2048)      { src = Wq; dst = Wt;                         N = 4096; }
  else if (bid < 2304) { src = Wk; dst = Wt + (size_t)4096 * HIDD;   N = 512;  bid -= 2048; }
  else if (bid < 2560) { src = Wv; dst = Wt + (size_t)4608 * HIDD;   N = 512;  bid -= 2304; }
  else                 { src = Wo; dst = Wot;                        N = 2048; bid -= 2560; }
  const int ktiles = HIDD / 64; // 32
  int n0 = (bid / ktiles) << 6;
  int k0 = (bid % ktiles) << 6;
#pragma unroll
  for (int i = 0; i < 16; i++) {
    int idx = i * 256 + t;
    int r = idx >> 6, c = idx & 63;
    lds[c * 65 + r] = src[(size_t)(k0 + r) * N + n0 + c];
  }
  __syncthreads();
#pragma unroll
  for (int i = 0; i < 2; i++) {
    int idx = i * 256 + t;
    int rr = idx >> 3, k8 = (idx & 7) * 8;
    s16x8 o;
#pragma unroll
    for (int e = 0; e < 8; e++) o[e] = (short)f2bf(lds[rr * 65 + k8 + e]);
    *(s16x8*)(dst + (size_t)(n0 + rr) * HIDD + k0 + k8) = o;
  }
}

// ---------------------------------------------------------------- shared GEMM pieces
__device__ __forceinline__ s16x8 ldsfrag(const char* half, int r, int g) {
  return *(const s16x8*)(half + r * 64 + ((g ^ ((r >> 1) & 3)) << 4));
}
template <int NL>
__device__ __forceinline__ void stage_half(char* ldsbase, const u16t* gbase,
                                           int K, int kcol, int tid) {
#pragma unroll
  for (int i = 0; i < NL; i++) {
    int o16 = i * 512 + tid;
    int r = o16 >> 2;
    int cs = (o16 & 3) ^ ((r >> 1) & 3);
    gload_lds16(gbase + (size_t)r * K + kcol + cs * 8, ldsbase + o16 * 16);
  }
}

// ---------------------------------------------------------------- 256xBN 8-phase bf16 GEMM
// (used for O-proj with BN=128). grid = (M/256)*(n/BN); M/256 must be 16.
template <int BN, typename CT>
__global__ __launch_bounds__(512, 2) void gemm8(const u16t* __restrict__ A,
                                                const u16t* __restrict__ Bt,
                                                CT* __restrict__ C,
                                                int M, int N, int K) {
  constexpr int NLB = BN / 128;            // B-half loads/thread
  constexpr int AHALF = 16384, ASLOT = 32768;
  constexpr int BHALF = BN * 64, BSLOT = 2 * BHALF;
  constexpr int PAIR = 2 + NLB;            // loads per (A,B) half-tile pair
  constexpr int NI = BN / 64;              // B frags per wave
  extern __shared__ __align__(16) char lds[];
  char* As = lds;
  char* Bs = lds + 2 * ASLOT;
  int tid = threadIdx.x, lane = tid & 63, w = tid >> 6;
  int wm = w >> 2, wn = w & 3;
  int cpx = gridDim.x >> 3;                       // grid % 8 == 0
  int wgid = (blockIdx.x & 7) * cpx + (blockIdx.x >> 3);
  int bm = wgid & 15, bn = wgid >> 4;             // M/256 == 16
  int m0 = bm << 8, n0 = bn * BN;
  const u16t* Ag = A + (size_t)m0 * K;
  const u16t* Bg = Bt + (size_t)n0 * K;
  const int NT = K >> 6;

  stage_half<2>(As, Ag, K, 0, tid);
  stage_half<NLB>(Bs, Bg, K, 0, tid);
  stage_half<2>(As + AHALF, Ag, K, 32, tid);
  stage_half<NLB>(Bs + BHALF, Bg, K, 32, tid);
  stage_half<2>(As + ASLOT, Ag, K, 64, tid);
  stage_half<NLB>(Bs + BSLOT, Bg, K, 64, tid);
  waitvm<2 * PAIR>();
  __builtin_amdgcn_s_barrier();

  const f32x4 fz = {0.f, 0.f, 0.f, 0.f};
  f32x4 acc[8][NI];
#pragma unroll
  for (int i = 0; i < 8; i++)
#pragma unroll
    for (int j = 0; j < NI; j++) acc[i][j] = fz;
  s16x8 afr[4], bfr[NI];
  int g = lane >> 4;
  int rA = (lane & 15) + wm * 128;
  int rB = (lane & 15) + wn * (BN / 4);

  for (int kt = 0; kt < NT; kt++) {
    int cur = kt & 1;
    char* Acur = As + cur * ASLOT;
    char* Bcur = Bs + cur * BSLOT;
    char* Anxt = As + (cur ^ 1) * ASLOT;
    char* Bnxt = Bs + (cur ^ 1) * BSLOT;
#pragma unroll
    for (int ni = 0; ni < NI; ni++) bfr[ni] = ldsfrag(Bcur, rB + ni * 16, g);
#pragma unroll
    for (int mi = 0; mi < 4; mi++) afr[mi] = ldsfrag(Acur, rA + mi * 16, g);
    if (kt + 1 < NT) stage_half<2>(Anxt + AHALF, Ag, K, (kt + 1) * 64 + 32, tid);
    __builtin_amdgcn_s_barrier();
    asm volatile("s_waitcnt lgkmcnt(0)" ::: "memory");
    __builtin_amdgcn_s_setprio(1);
#pragma unroll
    for (int mi = 0; mi < 4; mi++)
#pragma unroll
      for (int ni = 0; ni < NI; ni++)
        acc[mi][ni] = __builtin_amdgcn_mfma_f32_16x16x32_bf16(afr[mi], bfr[ni], acc[mi][ni], 0, 0, 0);
    __builtin_amdgcn_s_setprio(0);
    __builtin_amdgcn_s_barrier();
#pragma unroll
    for (int mi = 0; mi < 4; mi++) afr[mi] = ldsfrag(Acur, rA + 64 + mi * 16, g);
    if (kt + 1 < NT) stage_half<NLB>(Bnxt + BHALF, Bg, K, (kt + 1) * 64 + 32, tid);
    __builtin_amdgcn_s_barrier();
    asm volatile("s_waitcnt lgkmcnt(0)" ::: "memory");
    __builtin_amdgcn_s_setprio(1);
#pragma unroll
    for (int mi = 0; mi < 4; mi++)
#pragma unroll
      for (int ni = 0; ni < NI; ni++)
        acc[4 + mi][ni] = __builtin_amdgcn_mfma_f32_16x16x32_bf16(afr[mi], bfr[ni], acc[4 + mi][ni], 0, 0, 0);
    __builtin_amdgcn_s_setprio(0);
    if (kt + 1 < NT) waitvm<2 * PAIR>();
    else             waitvm<0>();
    __builtin_amdgcn_s_barrier();
#pragma unroll
    for (int ni = 0; ni < NI; ni++) bfr[ni] = ldsfrag(Bcur + BHALF, rB + ni * 16, g);
#pragma unroll
    for (int mi = 0; mi < 4; mi++) afr[mi] = ldsfrag(Acur + AHALF, rA + mi * 16, g);
    if (kt + 2 < NT) stage_half<2>(Acur, Ag, K, (kt + 2) * 64, tid);
    __builtin_amdgcn_s_barrier();
    asm volatile("s_waitcnt lgkmcnt(0)" ::: "memory");
    __builtin_amdgcn_s_setprio(1);
#pragma unroll
    for (int mi = 0; mi < 4; mi++)
#pragma unroll
      for (int ni = 0; ni < NI; ni++)
        acc[mi][ni] = __builtin_amdgcn_mfma_f32_16x16x32_bf16(afr[mi], bfr[ni], acc[mi][ni], 0, 0, 0);
    __builtin_amdgcn_s_setprio(0);
    __builtin_amdgcn_s_barrier();
#pragma unroll
    for (int mi = 0; mi < 4; mi++) afr[mi] = ldsfrag(Acur + AHALF, rA + 64 + mi * 16, g);
    if (kt + 2 < NT) stage_half<NLB>(Bcur, Bg, K, (kt + 2) * 64, tid);
    __builtin_amdgcn_s_barrier();
    asm volatile("s_waitcnt lgkmcnt(0)" ::: "memory");
    __builtin_amdgcn_s_setprio(1);
#pragma unroll
    for (int mi = 0; mi < 4; mi++)
#pragma unroll
      for (int ni = 0; ni < NI; ni++)
        acc[4 + mi][ni] = __builtin_amdgcn_mfma_f32_16x16x32_bf16(afr[mi], bfr[ni], acc[4 + mi][ni], 0, 0, 0);
    __builtin_amdgcn_s_setprio(0);
    if (kt < NT - 1) {
      if (kt + 2 < NT) waitvm<2 * PAIR>();
      else             waitvm<PAIR>();
    }
    __builtin_amdgcn_s_barrier();
  }
#pragma unroll
  for (int mi = 0; mi < 8; mi++)
#pragma unroll
    for (int ni = 0; ni < NI; ni++) {
      int row0 = m0 + wm * 128 + mi * 16 + ((lane >> 4) << 2);
      int col = n0 + wn * (BN / 4) + ni * 16 + (lane & 15);
#pragma unroll
      for (int j = 0; j < 4; j++) {
        if constexpr (sizeof(CT) == 2)
          C[(size_t)(row0 + j) * N + col] = f2bf(acc[mi][ni][j]);
        else
          C[(size_t)(row0 + j) * N + col] = acc[mi][ni][j];
      }
    }
}

// ---------------------------------------------------------------- Q projection GEMM + fused norm/rope/gate
// BN=256: each block's 256-col tile = one head's [query(0..127) | gate(128..255)].
// Epilogue v2: register ssq + q15 butterflies -> ssqb; qbuf LDS round-trip; per-row
// norm+rope with no shuffles.
__global__ __launch_bounds__(512, 2) void gemm8q(const u16t* __restrict__ A,
                                                 const u16t* __restrict__ Bt,
                                                 const float* __restrict__ rope,
                                                 const float* __restrict__ qw,
                                                 u16t* __restrict__ Qb,   // (B,H,S,D)
                                                 u16t* __restrict__ Gs,   // (B,S,H*D)
                                                 int K) {
  constexpr int NLB = 2, AHALF = 16384, ASLOT = 32768;
  constexpr int BHALF = 16384, BSLOT = 32768;
  constexpr int PAIR = 4, NI = 4;
  extern __shared__ __align__(16) char lds[];
  char* As = lds;
  char* Bs = lds + 2 * ASLOT;
  int tid = threadIdx.x, lane = tid & 63, w = tid >> 6;
  int wm = w >> 2, wn = w & 3;
  int cpx = gridDim.x >> 3;
  int wgid = (blockIdx.x & 7) * cpx + (blockIdx.x >> 3);
  int bm = wgid & 15, bn = wgid >> 4;             // bn = head h
  int m0 = bm << 8, n0 = bn << 8;
  const u16t* Ag = A + (size_t)m0 * K;
  const u16t* Bg = Bt + (size_t)n0 * K;
  const int NT = K >> 6;

  stage_half<2>(As, Ag, K, 0, tid);
  stage_half<NLB>(Bs, Bg, K, 0, tid);
  stage_half<2>(As + AHALF, Ag, K, 32, tid);
  stage_half<NLB>(Bs + BHALF, Bg, K, 32, tid);
  stage_half<2>(As + ASLOT, Ag, K, 64, tid);
  stage_half<NLB>(Bs + BSLOT, Bg, K, 64, tid);
  waitvm<2 * PAIR>();
  __builtin_amdgcn_s_barrier();

  const f32x4 fz = {0.f, 0.f, 0.f, 0.f};
  f32x4 acc[8][NI];
#pragma unroll
  for (int i = 0; i < 8; i++)
#pragma unroll
    for (int j = 0; j < NI; j++) acc[i][j] = fz;
  s16x8 afr[4], bfr[NI];
  int g = lane >> 4;
  int rA = (lane & 15) + wm * 128;
  int rB = (lane & 15) + wn * 64;

  for (int kt = 0; kt < NT; kt++) {
    int cur = kt & 1;
    char* Acur = As + cur * ASLOT;
    char* Bcur = Bs + cur * BSLOT;
    char* Anxt = As + (cur ^ 1) * ASLOT;
    char* Bnxt = Bs + (cur ^ 1) * BSLOT;
#pragma unroll
    for (int ni = 0; ni < NI; ni++) bfr[ni] = ldsfrag(Bcur, rB + ni * 16, g);
#pragma unroll
    for (int mi = 0; mi < 4; mi++) afr[mi] = ldsfrag(Acur, rA + mi * 16, g);
    if (kt + 1 < NT) stage_half<2>(Anxt + AHALF, Ag, K, (kt + 1) * 64 + 32, tid);
    __builtin_amdgcn_s_barrier();
    asm volatile("s_waitcnt lgkmcnt(0)" ::: "memory");
    __builtin_amdgcn_s_setprio(1);
#pragma unroll
    for (int mi = 0; mi < 4; mi++)
#pragma unroll
      for (int ni = 0; ni < NI; ni++)
        acc[mi][ni] = __builtin_amdgcn_mfma_f32_16x16x32_bf16(afr[mi], bfr[ni], acc[mi][ni], 0, 0, 0);
    __builtin_amdgcn_s_setprio(0);
    __builtin_amdgcn_s_barrier();
#pragma unroll
    for (int mi = 0; mi < 4; mi++) afr[mi] = ldsfrag(Acur, rA + 64 + mi * 16, g);
    if (kt + 1 < NT) stage_half<NLB>(Bnxt + BHALF, Bg, K, (kt + 1) * 64 + 32, tid);
    __builtin_amdgcn_s_barrier();
    asm volatile("s_waitcnt lgkmcnt(0)" ::: "memory");
    __builtin_amdgcn_s_setprio(1);
#pragma unroll
    for (int mi = 0; mi < 4; mi++)
#pragma unroll
      for (int ni = 0; ni < NI; ni++)
        acc[4 + mi][ni] = __builtin_amdgcn_mfma_f32_16x16x32_bf16(afr[mi], bfr[ni], acc[4 + mi][ni], 0, 0, 0);
    __builtin_amdgcn_s_setprio(0);
    if (kt + 1 < NT) waitvm<2 * PAIR>();
    else             waitvm<0>();
    __builtin_amdgcn_s_barrier();
#pragma unroll
    for (int ni = 0; ni < NI; ni++) bfr[ni] = ldsfrag(Bcur + BHALF, rB + ni * 16, g);
#pragma unroll
    for (int mi = 0; mi < 4; mi++) afr[mi] = ldsfrag(Acur + AHALF, rA + mi * 16, g);
    if (kt + 2 < NT) stage_half<2>(Acur, Ag, K, (kt + 2) * 64, tid);
    __builtin_amdgcn_s_barrier();
    asm volatile("s_waitcnt lgkmcnt(0)" ::: "memory");
    __builtin_amdgcn_s_setprio(1);
#pragma unroll
    for (int mi = 0; mi < 4; mi++)
#pragma unroll
      for (int ni = 0; ni < NI; ni++)
        acc[mi][ni] = __builtin_amdgcn_mfma_f32_16x16x32_bf16(afr[mi], bfr[ni], acc[mi][ni], 0, 0, 0);
    __builtin_amdgcn_s_setprio(0);
    __builtin_amdgcn_s_barrier();
#pragma unroll
    for (int mi = 0; mi < 4; mi++) afr[mi] = ldsfrag(Acur + AHALF, rA + 64 + mi * 16, g);
    if (kt + 2 < NT) stage_half<NLB>(Bcur, Bg, K, (kt + 2) * 64, tid);
    __builtin_amdgcn_s_barrier();
    asm volatile("s_waitcnt lgkmcnt(0)" ::: "memory");
    __builtin_amdgcn_s_setprio(1);
#pragma unroll
    for (int mi = 0; mi < 4; mi++)
#pragma unroll
      for (int ni = 0; ni < NI; ni++)
        acc[4 + mi][ni] = __builtin_amdgcn_mfma_f32_16x16x32_bf16(afr[mi], bfr[ni], acc[4 + mi][ni], 0, 0, 0);
    __builtin_amdgcn_s_setprio(0);
    if (kt < NT - 1) {
      if (kt + 2 < NT) waitvm<2 * PAIR>();
      else             waitvm<PAIR>();
    }
    __builtin_amdgcn_s_barrier();
  }

  // ---- fused epilogue v2 ------------------------------------------------
  int h = bn;
  float* qbuf = (float*)lds;                    // 256 rows x 128 f32, granule-swizzled
  float* ssqb = (float*)(lds + 131072);         // [2][256] partial sum-of-squares
  int q15 = lane & 15;
  if (wn < 2) {
    float ps[8][4];
#pragma unroll
    for (int mi = 0; mi < 8; mi++)
#pragma unroll
      for (int j = 0; j < 4; j++) {
        float s = 0.f;
#pragma unroll
        for (int ni = 0; ni < NI; ni++) { float v = acc[mi][ni][j]; s += v * v; }
        ps[mi][j] = s;
      }
#pragma unroll
    for (int d = 1; d < 16; d <<= 1)
#pragma unroll
      for (int mi = 0; mi < 8; mi++)
#pragma unroll
        for (int j = 0; j < 4; j++) ps[mi][j] += __shfl_xor(ps[mi][j], d);
#pragma unroll
    for (int mi = 0; mi < 8; mi++)
#pragma unroll
      for (int ni = 0; ni < NI; ni++) {
        int rl0 = wm * 128 + mi * 16 + ((lane >> 4) << 2);
        int c = wn * 64 + ni * 16 + q15;
        int gr = c >> 4;
#pragma unroll
        for (int j = 0; j < 4; j++) {
          int rl = rl0 + j;
          qbuf[rl * 128 + (((gr ^ ((rl >> 2) & 7)) << 4) | (c & 15))] = acc[mi][ni][j];
        }
      }
    if (q15 == 0) {
#pragma unroll
      for (int mi = 0; mi < 8; mi++)
#pragma unroll
        for (int j = 0; j < 4; j++) {
          int rl = wm * 128 + mi * 16 + (g << 2) + j;
          ssqb[wn * 256 + rl] = ps[mi][j];
        }
    }
  } else {
#pragma unroll
    for (int mi = 0; mi < 8; mi++)
#pragma unroll
      for (int ni = 0; ni < NI; ni++) {
        int row0 = m0 + wm * 128 + mi * 16 + ((lane >> 4) << 2);
        int d = (wn - 2) * 64 + ni * 16 + q15;
#pragma unroll
        for (int j = 0; j < 4; j++) {
          int bb = (row0 + j) >> 11, s = (row0 + j) & 2047;
          float gv = acc[mi][ni][j];
          Gs[((size_t)(bb * SS + s)) * (HH * DD) + h * DD + d] =
              f2bf(1.f / (1.f + __expf(-gv)));
        }
      }
  }
  __syncthreads();
  float qwl = qw[lane], qwh = qw[64 + lane];
  const float SC = 0.08838834764831845f * 1.4426950408889634f;
#pragma unroll 4
  for (int r2 = 0; r2 < 32; r2++) {
    int rl = w * 32 + r2;
    int row0 = m0 + rl;
    int bb = row0 >> 11, s = row0 & 2047;
    int swz = ((rl >> 2) & 7) << 4;
    int cl = lane, ch = 64 + lane;
    float xlo = qbuf[rl * 128 + ((((cl >> 4) << 4) ^ swz) | (cl & 15))];
    float xhi = qbuf[rl * 128 + ((((ch >> 4) << 4) ^ swz) | (ch & 15))];
    float ss2 = ssqb[rl] + ssqb[256 + rl];
    float r = rsqrtf(ss2 * (1.f / 128.f) + 1e-6f);
    float qlo = xlo * r * (1.f + qwl);
    float qhi = xhi * r * (1.f + qwh);
    const float* cs = rope + (size_t)s * 256;
    float clo = cs[lane], chi = cs[64 + lane];
    float slo = cs[128 + lane], shi = cs[192 + lane];
    float olo = (qlo * clo - qhi * slo) * SC;
    float ohi = (qhi * chi + qlo * shi) * SC;
    size_t qoff = (((size_t)bb * HH + h) * SS + s) * DD;
    Qb[qoff + lane] = f2bf(olo);
    Qb[qoff + 64 + lane] = f2bf(ohi);
  }
}

// ---------------------------------------------------------------- KV projection GEMM + fused K-norm/rope
// bn 0..3 = K head bn: 128-row x 128-col tile = one full KV head -> fused
// RMSNorm+RoPE (same epilogue pattern as gemm8q) -> Kb (bf16) + present-K (f32).
// bn 4..7 = V-heads -> present (f32) + Vtb (bf16) directly from registers.
__global__ __launch_bounds__(256) void gemm_kv(const u16t* __restrict__ A,
                                               const u16t* __restrict__ Bt,
                                               const float* __restrict__ rope,
                                               const float* __restrict__ kw,
                                               u16t* __restrict__ Kb,
                                               float* __restrict__ present,
                                               u16t* __restrict__ Vtb,
                                               int K) {
  extern __shared__ __align__(16) char lds[];
  char* As = lds;            // [128*64]
  char* Bs = lds + 8192;     // [128*64]
  int tid = threadIdx.x;
  int lane = tid & 63;
  int w = tid >> 6;
  int cpx = gridDim.x >> 3;
  int wgid = ((int)blockIdx.x & 7) * cpx + ((int)blockIdx.x >> 3);
  const int mtiles = MM >> 7;                 // 32
  int bm = wgid % mtiles;
  int bn = wgid / mtiles;                     // 0..7
  int m0 = bm << 7, n0 = bn << 7;
  int wr = (w >> 1) * 64, wc = (w & 1) * 64;

  const f32x4 fz = {0.f, 0.f, 0.f, 0.f};
  f32x4 acc[4][4];
#pragma unroll
  for (int i = 0; i < 4; i++)
#pragma unroll
    for (int j = 0; j < 4; j++) acc[i][j] = fz;

  for (int k0 = 0; k0 < K; k0 += 32) {
    __syncthreads();
#pragma unroll
    for (int i = 0; i < 2; i++) {
      int idx = i * 256 + tid;
      int r = idx >> 2, c = idx & 3;
      int csrc = c ^ ((r >> 1) & 3);
      gload_lds16(A + (size_t)(m0 + r) * K + k0 + csrc * 8, As + idx * 16);
      gload_lds16(Bt + (size_t)(n0 + r) * K + k0 + csrc * 8, Bs + idx * 16);
    }
    __syncthreads();
    s16x8 af[4], bf[4];
    int g = lane >> 4;
#pragma unroll
    for (int mi = 0; mi < 4; mi++) {
      int r = wr + mi * 16 + (lane & 15);
      af[mi] = *(const s16x8*)(As + r * 64 + ((g ^ ((r >> 1) & 3)) << 4));
    }
#pragma unroll
    for (int ni = 0; ni < 4; ni++) {
      int r = wc + ni * 16 + (lane & 15);
      bf[ni] = *(const s16x8*)(Bs + r * 64 + ((g ^ ((r >> 1) & 3)) << 4));
    }
#pragma unroll
    for (int mi = 0; mi < 4; mi++)
#pragma unroll
      for (int ni = 0; ni < 4; ni++)
        acc[mi][ni] = __builtin_amdgcn_mfma_f32_16x16x32_bf16(af[mi], bf[ni], acc[mi][ni], 0, 0, 0);
  }
  if (bn < 4) {
    // ---- fused K epilogue: RMSNorm + RoPE (head kv = bn) ----
    int kv = bn;
    int q15 = lane & 15, g = lane >> 4;
    __syncthreads();                        // protect As/Bs before reuse as kbuf
    float* kbuf = (float*)lds;              // 128 rows x 128 f32 (64KB), granule-swz
    float* ssqb = (float*)(lds + 65536);    // [2][128] partials
    float ps[4][4];
#pragma unroll
    for (int mi = 0; mi < 4; mi++)
#pragma unroll
      for (int j = 0; j < 4; j++) {
        float s = 0.f;
#pragma unroll
        for (int ni = 0; ni < 4; ni++) { float v = acc[mi][ni][j]; s += v * v; }
        ps[mi][j] = s;
      }
#pragma unroll
    for (int d = 1; d < 16; d <<= 1)
#pragma unroll
      for (int mi = 0; mi < 4; mi++)
#pragma unroll
        for (int j = 0; j < 4; j++) ps[mi][j] += __shfl_xor(ps[mi][j], d);
#pragma unroll
    for (int mi = 0; mi < 4; mi++)
#pragma unroll
      for (int ni = 0; ni < 4; ni++) {
        int rl0 = wr + mi * 16 + (g << 2);
        int c = wc + ni * 16 + q15;
        int gr = c >> 4;
#pragma unroll
        for (int j = 0; j < 4; j++) {
          int rl = rl0 + j;
          kbuf[rl * 128 + (((gr ^ ((rl >> 2) & 7)) << 4) | (c & 15))] = acc[mi][ni][j];
        }
      }
    if (q15 == 0) {
#pragma unroll
      for (int mi = 0; mi < 4; mi++)
#pragma unroll
        for (int j = 0; j < 4; j++) {
          int rl = wr + mi * 16 + (g << 2) + j;
          ssqb[(w & 1) * 128 + rl] = ps[mi][j];
        }
    }
    __syncthreads();
    float kwl = kw[lane], kwh = kw[64 + lane];
#pragma unroll 4
    for (int r2 = 0; r2 < 32; r2++) {
      int rl = w * 32 + r2;
      int row0 = m0 + rl;
      int bb = row0 >> 11, s = row0 & 2047;
      int swz = ((rl >> 2) & 7) << 4;
      int cl = lane, ch = 64 + lane;
      float xlo = kbuf[rl * 128 + ((((cl >> 4) << 4) ^ swz) | (cl & 15))];
      float xhi = kbuf[rl * 128 + ((((ch >> 4) << 4) ^ swz) | (ch & 15))];
      float ss2 = ssqb[rl] + ssqb[128 + rl];
      float r = rsqrtf(ss2 * (1.f / 128.f) + 1e-6f);
      float klo = xlo * r * (1.f + kwl);
      float khi = xhi * r * (1.f + kwh);
      const float* cs = rope + (size_t)s * 256;
      float clo = cs[lane], chi = cs[64 + lane];
      float slo = cs[128 + lane], shi = cs[192 + lane];
      float olo = klo * clo - khi * slo;       // K is NOT pre-scaled
      float ohi = khi * chi + klo * shi;
      size_t koff = (((size_t)bb * KVH + kv) * SS + s) * DD;
      Kb[koff + lane] = f2bf(olo);
      Kb[koff + 64 + lane] = f2bf(ohi);
      size_t poff = (((size_t)(bb * 2 * KVH + kv)) * SS + s) * DD;
      present[poff + lane] = olo;
      present[poff + 64 + lane] = ohi;
    }
  } else {
#pragma unroll
    for (int mi = 0; mi < 4; mi++)
#pragma unroll
      for (int ni = 0; ni < 4; ni++) {
        int row0 = m0 + wr + mi * 16 + ((lane >> 4) << 2);
        int vcol = (n0 - 512) + wc + ni * 16 + (lane & 15);
        int kv = vcol >> 7, d = vcol & 127;
        int bb = row0 >> 11, sp = row0 & 2047;
        size_t pbase = (((size_t)(bb * 2 * KVH + KVH + kv)) * SS + sp) * DD + d;
#pragma unroll
        for (int j = 0; j < 4; j++)
          present[pbase + (size_t)j * DD] = acc[mi][ni][j];
        s16x4 pk;
        pk[0] = (short)f2bf(acc[mi][ni][0]);
        pk[1] = (short)f2bf(acc[mi][ni][1]);
        pk[2] = (short)f2bf(acc[mi][ni][2]);
        pk[3] = (short)f2bf(acc[mi][ni][3]);
        *(s16x4*)(Vtb + ((size_t)(bb * KVH + kv) * DD + d) * SS + sp) = pk;
      }
  }
}

// ---------------------------------------------------------------- flash attention v5.1 (round-12 verbatim)
__global__ __launch_bounds__(256, 2) void attn_kernel(const u16t* __restrict__ Qb,   // (B,H,S,D) pre-scaled
                                                      const u16t* __restrict__ Kb,   // (B,KV,S,D)
                                                      const u16t* __restrict__ Vtb,  // (B,KV,D,S)
                                                      const u16t* __restrict__ Gs,   // (B,S,H*D)
                                                      u16t* __restrict__ AttG) {     // (B,S,H*D)
  __shared__ __align__(16) char Ks[2 * 16384];  // 64 rows x 256B, chunk xor (r&7)
  __shared__ __align__(16) char Vs[2 * 16384];  // V^T: 128 rows x 128B, chunk xor (d&7)
  __shared__ __align__(16) char Ps[4 * 2048];   // per-wave P: [q:16][k-granule xor (q&7)]

  int tid = threadIdx.x, lane = tid & 63, w = tid >> 6;
  int x = blockIdx.x & 7;          // XCD grouping: each XCD owns one (b,kv)
  int b = x >> 2, kv = x & 3;
  int rr = blockIdx.x >> 3;        // 0..63
  int h = kv * 4 + (rr & 3);
  int p = rr >> 2;                 // 0..15: pair {31-p, p}

  const u16t* Kbase = Kb + (((size_t)(b * KVH + kv)) * SS) * DD;
  const u16t* Vbase = Vtb + (((size_t)(b * KVH + kv)) * DD) * SS;

  auto stageK = [&](int kt, int buf) {
#pragma unroll
    for (int i = 0; i < 4; i++) {
      int idx = i * 256 + tid;
      int r_ = idx >> 4, c_ = idx & 15;
      gload_lds16(Kbase + (size_t)(kt * 64 + r_) * DD + (c_ ^ (r_ & 7)) * 8,
                  Ks + buf * 16384 + idx * 16);
    }
  };
  auto stageV = [&](int kt, int buf) {
#pragma unroll
    for (int i = 0; i < 4; i++) {
      int idx = i * 256 + tid;
      int r_ = idx >> 3, c_ = idx & 7;
      gload_lds16(Vbase + (size_t)r_ * SS + kt * 64 + (c_ ^ (r_ & 7)) * 8,
                  Vs + buf * 16384 + idx * 16);
    }
  };

  const f32x4 fz = {0.f, 0.f, 0.f, 0.f};
  int g = lane >> 4;
  int q15 = lane & 15;
  int q7 = q15 & 7;
  char* pq = Ps + w * 2048 + q15 * 128;   // this lane's q-row in P
  int cur = 0;

  int ka[4][4];
#pragma unroll
  for (int ni = 0; ni < 4; ni++)
#pragma unroll
    for (int ks = 0; ks < 4; ks++)
      ka[ni][ks] = (ni * 16 + q15) * 256 + (((ks * 4 + g) ^ q7) << 4);
  int va[2][8];
#pragma unroll
  for (int ks2 = 0; ks2 < 2; ks2++)
#pragma unroll
    for (int f = 0; f < 8; f++)
      va[ks2][f] = (f * 16 + q15) * 128 + (((ks2 * 4 + g) ^ q7) << 4);
  int pr_[2];
#pragma unroll
  for (int ks2 = 0; ks2 < 2; ks2++) pr_[ks2] = ((ks2 * 4 + g) ^ q7) << 4;
  int pw_[4];
#pragma unroll
  for (int ni = 0; ni < 4; ni++)
    pw_[ni] = (((ni * 2 + (g >> 1)) ^ q7) << 4) + ((g & 1) << 3);

  stageK(0, 0);
  stageV(0, 0);

  for (int seg = 0; seg < 2; seg++) {
    int qt = (seg == 0) ? (31 - p) : p;
    const u16t* Qbase = Qb + (((size_t)(b * HH + h)) * SS + qt * 64) * DD;
    s16x8 qf[4];
    {
      const u16t* qrow = Qbase + (size_t)(w * 16 + q15) * DD + g * 8;
#pragma unroll
      for (int ks = 0; ks < 4; ks++) qf[ks] = *(const s16x8*)(qrow + ks * 32);
    }
    f32x4 acco[8];
#pragma unroll
    for (int f = 0; f < 8; f++) acco[f] = fz;
    float mrun = -INFINITY, lrun = 0.f;

    if (seg == 0) {
      asm volatile("s_waitcnt vmcnt(0)" ::: "memory");
      __builtin_amdgcn_s_barrier();
    }

    for (int kt = 0; kt <= qt; kt++) {
      bool havenext = (kt < qt) || (seg == 0);
      if (havenext) {
        int nk = (kt < qt) ? (kt + 1) : 0;
        stageK(nk, cur ^ 1);
        stageV(nk, cur ^ 1);
      }
      const char* kc = Ks + (cur << 14);
      const char* vc = Vs + (cur << 14);
      f32x4 accs[4];
#pragma unroll
      for (int ni = 0; ni < 4; ni++) accs[ni] = fz;
#pragma unroll
      for (int ni = 0; ni < 4; ni++)
#pragma unroll
        for (int ks = 0; ks < 4; ks++) {
          s16x8 bfk = *(const s16x8*)(kc + ka[ni][ks]);
          accs[ni] = __builtin_amdgcn_mfma_f32_16x16x32_bf16(bfk, qf[ks], accs[ni], 0, 0, 0);
        }
      if (kt == qt) {
        int ql = w * 16 + q15;
#pragma unroll
        for (int ni = 0; ni < 4; ni++)
#pragma unroll
          for (int j = 0; j < 4; j++) {
            int kl = ni * 16 + (g << 2) + j;
            if (kl > ql) accs[ni][j] = -1e30f;
          }
      }
      f32x4 m4 = fmax4(fmax4(accs[0], accs[1]), fmax4(accs[2], accs[3]));
      float mt = fmaxf(fmaxf(m4[0], m4[1]), fmaxf(m4[2], m4[3]));
      mt = fmaxf(mt, __shfl_xor(mt, 16));
      mt = fmaxf(mt, __shfl_xor(mt, 32));
      float mnew = fmaxf(mrun, mt);
      float alpha = __builtin_amdgcn_exp2f(mrun - mnew);
      mrun = mnew;
#pragma unroll
      for (int ni = 0; ni < 4; ni++)
#pragma unroll
        for (int j = 0; j < 4; j++)
          accs[ni][j] = __builtin_amdgcn_exp2f(accs[ni][j] - mnew);
      f32x4 s4 = (accs[0] + accs[1]) + (accs[2] + accs[3]);
      float rs = (s4[0] + s4[1]) + (s4[2] + s4[3]);
      rs += __shfl_xor(rs, 16);
      rs += __shfl_xor(rs, 32);
      lrun = lrun * alpha + rs;
      float ar[4];
#pragma unroll
      for (int j = 0; j < 4; j++) ar[j] = __shfl(alpha, (g << 2) + j);
#pragma unroll
      for (int f = 0; f < 8; f++)
#pragma unroll
        for (int j = 0; j < 4; j++) acco[f][j] *= ar[j];

#pragma unroll
      for (int ni = 0; ni < 4; ni++) {
        uint2 pk;
        pk.x = cvtpk_bf16(accs[ni][0], accs[ni][1]);
        pk.y = cvtpk_bf16(accs[ni][2], accs[ni][3]);
        *(uint2*)(pq + pw_[ni]) = pk;
      }
#pragma unroll
      for (int ks2 = 0; ks2 < 2; ks2++) {
        s16x8 pa = *(const s16x8*)(pq + pr_[ks2]);
#pragma unroll
        for (int f = 0; f < 8; f++) {
          s16x8 vf = *(const s16x8*)(vc + va[ks2][f]);
          acco[f] = __builtin_amdgcn_mfma_f32_16x16x32_bf16(pa, vf, acco[f], 0, 0, 0);
        }
      }
      if (havenext) {
        asm volatile("s_waitcnt vmcnt(0)" ::: "memory");
        __builtin_amdgcn_s_barrier();
        cur ^= 1;
      }
    }
    float lr[4];
#pragma unroll
    for (int j = 0; j < 4; j++) lr[j] = __shfl(lrun, (g << 2) + j);
#pragma unroll
    for (int f = 0; f < 8; f++) {
      int d = f * 16 + q15;
#pragma unroll
      for (int j = 0; j < 4; j++) {
        int srow = qt * 64 + w * 16 + (g << 2) + j;
        float o = acco[f][j] / lr[j];
        size_t off = ((size_t)b * SS + srow) * (HH * DD) + h * DD + d;
        float gt = bf2f(Gs[off]);
        AttG[off] = f2bf(o * gt);
      }
    }
  }
}

// ---------------------------------------------------------------- launcher
extern "C" void kernel_launch(void* const* d_in, const int* in_sizes, int n_in,
                              void* d_out, int out_size, void* d_ws, size_t ws_size,
                              hipStream_t stream) {
  const float* hidden = (const float*)d_in[0];
  const float* rope   = (const float*)d_in[2];
  const float* Wq     = (const float*)d_in[5];
  const float* Wk     = (const float*)d_in[6];
  const float* Wv     = (const float*)d_in[7];
  const float* Wo     = (const float*)d_in[8];
  const float* qw     = (const float*)d_in[9];
  const float* kw     = (const float*)d_in[10];
  float* out = (float*)d_out;
  float* present = out + (size_t)BB * SS * HIDD; // 8,388,608

  char* ws = (char*)d_ws;
  u16t* Xb    = (u16t*)(ws);                              // 4096x2048 bf16   16.78MB
  u16t* Wt    = (u16t*)(ws + 16777216);                   // 5120x2048 bf16   20.97MB
  u16t* Wot   = (u16t*)(ws + 37748736);                   // 2048x2048 bf16    8.39MB
  u16t* Qb    = (u16t*)(ws + 88080384);                   // (B,H,S,D) bf16   16.78MB
  u16t* Kb    = (u16t*)(ws + 104857600);                  // (B,KV,S,D) bf16   4.19MB
  u16t* Vtb   = (u16t*)(ws + 109051904);                  // (B,KV,D,S) bf16   4.19MB
  u16t* Gs    = (u16t*)(ws + 113246208);                  // (B,S,H*D) bf16   16.78MB
  u16t* AttG  = Xb;  // alias: Xb dead after projections; AttG written by attention

  (void)hipFuncSetAttribute(reinterpret_cast<const void*>(gemm8q),
                            hipFuncAttributeMaxDynamicSharedMemorySize, 133120);
  (void)hipFuncSetAttribute(reinterpret_cast<const void*>(gemm_kv),
                            hipFuncAttributeMaxDynamicSharedMemorySize, 66560);
  (void)hipFuncSetAttribute(reinterpret_cast<const void*>(gemm8<128, float>),
                            hipFuncAttributeMaxDynamicSharedMemorySize, 98304);

  // 1+2. fused prep: cast hidden + weight transposes
  prep_all<<<4096 + 3584, 256, 0, stream>>>(hidden, Wq, Wk, Wv, Wo, Xb, Wt, Wot);
  // 3a. Q projection + fused RMSNorm/RoPE/gate: grid 256 = 1 block/CU
  gemm8q<<<(MM / 256) * (4096 / 256), 512, 133120, stream>>>(Xb, Wt, rope, qw, Qb, Gs, HIDD);
  // 3b. K+V projection with fused K-norm/rope + V epilogues; grid 256
  gemm_kv<<<(MM / 128) * (1024 / 128), 256, 66560, stream>>>(
      Xb, Wt + (size_t)4096 * HIDD, rope, kw, Kb, present, Vtb, HIDD);
  // 4. flash attention v5.1 (round-12 verbatim)
  attn_kernel<<<BB * HH * (SS / 128), 256, 0, stream>>>(Qb, Kb, Vtb, Gs, AttG);
  // 5. output projection -> d_out: 256x128 8-phase, grid 16x16 = 256 = 1 block/CU
  gemm8<128, float><<<(MM / 256) * (HIDD / 128), 512, 98304, stream>>>(AttG, Wot, out, MM, HIDD, HIDD);
}

// Round 20
// 249.202 us; speedup vs baseline: 1.1115x; 1.0345x over previous
//
#include <hip/hip_runtime.h>
#include <hip/hip_bf16.h>
#include <cstdint>
#include <cstddef>

// Problem constants
#define BB   2
#define SS   2048
#define HIDD 2048
#define HH   16
#define KVH  4
#define DD   128
#define NQKV 5120   // H*2*D + KV*D + KV*D = 4096 + 512 + 512
#define MM   4096   // B*S

typedef unsigned short u16t;
typedef __attribute__((ext_vector_type(8))) short s16x8;
typedef __attribute__((ext_vector_type(4))) short s16x4;
typedef __attribute__((ext_vector_type(4))) float f32x4;

__device__ __forceinline__ u16t f2bf(float f) {
  unsigned u = __float_as_uint(f);
  u += 0x7fffu + ((u >> 16) & 1u);
  return (u16t)(u >> 16);
}
__device__ __forceinline__ float bf2f(u16t h) {
  return __uint_as_float(((unsigned)h) << 16);
}
__device__ __forceinline__ void gload_lds16(const void* g, void* l) {
  __builtin_amdgcn_global_load_lds(
      (const __attribute__((address_space(1))) unsigned int*)g,
      (__attribute__((address_space(3))) unsigned int*)l, 16, 0, 0);
}
__device__ __forceinline__ unsigned cvtpk_bf16(float lo, float hi) {
  unsigned r;
  asm("v_cvt_pk_bf16_f32 %0, %1, %2" : "=v"(r) : "v"(lo), "v"(hi));
  return r;
}
__device__ __forceinline__ f32x4 fmax4(f32x4 a, f32x4 b) {
  f32x4 r;
  r[0] = fmaxf(a[0], b[0]); r[1] = fmaxf(a[1], b[1]);
  r[2] = fmaxf(a[2], b[2]); r[3] = fmaxf(a[3], b[3]);
  return r;
}
// counted vmcnt via literal asm (compiler-ordering fence through "memory" clobber).
// Round-11/14 lessons: __builtin_amdgcn_s_waitcnt is NOT a memory fence; and
// defer-max (T13) breaks correctness on this pipelined structure -- banned.
template <int N>
__device__ __forceinline__ void waitvm() {
  static_assert(N == 0 || N == 3 || N == 4 || N == 6 || N == 8, "add literal");
  if constexpr (N == 0)      asm volatile("s_waitcnt vmcnt(0)" ::: "memory");
  else if constexpr (N == 3) asm volatile("s_waitcnt vmcnt(3)" ::: "memory");
  else if constexpr (N == 4) asm volatile("s_waitcnt vmcnt(4)" ::: "memory");
  else if constexpr (N == 6) asm volatile("s_waitcnt vmcnt(6)" ::: "memory");
  else if constexpr (N == 8) asm volatile("s_waitcnt vmcnt(8)" ::: "memory");
}

// ----------------------------------------- fused prep: cast hidden + transpose-cast all weights
__global__ __launch_bounds__(256) void prep_all(const float* __restrict__ hidden,
                                                const float* __restrict__ Wq,
                                                const float* __restrict__ Wk,
                                                const float* __restrict__ Wv,
                                                const float* __restrict__ Wo,
                                                u16t* __restrict__ Xb,
                                                u16t* __restrict__ Wt,
                                                u16t* __restrict__ Wot) {
  __shared__ float lds[64 * 65];
  int bid = blockIdx.x;
  int t = threadIdx.x;
  if (bid < 4096) {
    size_t i = ((size_t)bid * 256 + t) * 8;
    f32x4 v0 = *(const f32x4*)(hidden + i);
    f32x4 v1 = *(const f32x4*)(hidden + i + 4);
    s16x8 o;
    o[0] = (short)f2bf(v0[0]); o[1] = (short)f2bf(v0[1]);
    o[2] = (short)f2bf(v0[2]); o[3] = (short)f2bf(v0[3]);
    o[4] = (short)f2bf(v1[0]); o[5] = (short)f2bf(v1[1]);
    o[6] = (short)f2bf(v1[2]); o[7] = (short)f2bf(v1[3]);
    *(s16x8*)(Xb + i) = o;
    return;
  }
  bid -= 4096;
  const float* src; u16t* dst; int N;
  if (bid < 2048)      { src = Wq; dst = Wt;                         N = 4096; }
  else if (bid < 2304) { src = Wk; dst = Wt + (size_t)4096 * HIDD;   N = 512;  bid -= 2048; }
  else if (bid < 2560) { src = Wv; dst = Wt + (size_t)4608 * HIDD;   N = 512;  bid -= 2304; }
  else                 { src = Wo; dst = Wot;                        N = 2048; bid -= 2560; }
  const int ktiles = HIDD / 64; // 32
  int n0 = (bid / ktiles) << 6;
  int k0 = (bid % ktiles) << 6;
#pragma unroll
  for (int i = 0; i < 16; i++) {
    int idx = i * 256 + t;
    int r = idx >> 6, c = idx & 63;
    lds[c * 65 + r] = src[(size_t)(k0 + r) * N + n0 + c];
  }
  __syncthreads();
#pragma unroll
  for (int i = 0; i < 2; i++) {
    int idx = i * 256 + t;
    int rr = idx >> 3, k8 = (idx & 7) * 8;
    s16x8 o;
#pragma unroll
    for (int e = 0; e < 8; e++) o[e] = (short)f2bf(lds[rr * 65 + k8 + e]);
    *(s16x8*)(dst + (size_t)(n0 + rr) * HIDD + k0 + k8) = o;
  }
}

// ---------------------------------------------------------------- shared GEMM pieces
__device__ __forceinline__ s16x8 ldsfrag(const char* half, int r, int g) {
  return *(const s16x8*)(half + r * 64 + ((g ^ ((r >> 1) & 3)) << 4));
}
template <int NL>
__device__ __forceinline__ void stage_half(char* ldsbase, const u16t* gbase,
                                           int K, int kcol, int tid) {
#pragma unroll
  for (int i = 0; i < NL; i++) {
    int o16 = i * 512 + tid;
    int r = o16 >> 2;
    int cs = (o16 & 3) ^ ((r >> 1) & 3);
    gload_lds16(gbase + (size_t)r * K + kcol + cs * 8, ldsbase + o16 * 16);
  }
}

// ---------------------------------------------------------------- 256xBN 8-phase bf16 GEMM
// (used for O-proj with BN=128). grid = (M/256)*(n/BN); M/256 must be 16.
template <int BN, typename CT>
__global__ __launch_bounds__(512, 2) void gemm8(const u16t* __restrict__ A,
                                                const u16t* __restrict__ Bt,
                                                CT* __restrict__ C,
                                                int M, int N, int K) {
  constexpr int NLB = BN / 128;            // B-half loads/thread
  constexpr int AHALF = 16384, ASLOT = 32768;
  constexpr int BHALF = BN * 64, BSLOT = 2 * BHALF;
  constexpr int PAIR = 2 + NLB;            // loads per (A,B) half-tile pair
  constexpr int NI = BN / 64;              // B frags per wave
  extern __shared__ __align__(16) char lds[];
  char* As = lds;
  char* Bs = lds + 2 * ASLOT;
  int tid = threadIdx.x, lane = tid & 63, w = tid >> 6;
  int wm = w >> 2, wn = w & 3;
  int cpx = gridDim.x >> 3;                       // grid % 8 == 0
  int wgid = (blockIdx.x & 7) * cpx + (blockIdx.x >> 3);
  int bm = wgid & 15, bn = wgid >> 4;             // M/256 == 16
  int m0 = bm << 8, n0 = bn * BN;
  const u16t* Ag = A + (size_t)m0 * K;
  const u16t* Bg = Bt + (size_t)n0 * K;
  const int NT = K >> 6;

  stage_half<2>(As, Ag, K, 0, tid);
  stage_half<NLB>(Bs, Bg, K, 0, tid);
  stage_half<2>(As + AHALF, Ag, K, 32, tid);
  stage_half<NLB>(Bs + BHALF, Bg, K, 32, tid);
  stage_half<2>(As + ASLOT, Ag, K, 64, tid);
  stage_half<NLB>(Bs + BSLOT, Bg, K, 64, tid);
  waitvm<2 * PAIR>();
  __builtin_amdgcn_s_barrier();

  const f32x4 fz = {0.f, 0.f, 0.f, 0.f};
  f32x4 acc[8][NI];
#pragma unroll
  for (int i = 0; i < 8; i++)
#pragma unroll
    for (int j = 0; j < NI; j++) acc[i][j] = fz;
  s16x8 afr[4], bfr[NI];
  int g = lane >> 4;
  int rA = (lane & 15) + wm * 128;
  int rB = (lane & 15) + wn * (BN / 4);

  for (int kt = 0; kt < NT; kt++) {
    int cur = kt & 1;
    char* Acur = As + cur * ASLOT;
    char* Bcur = Bs + cur * BSLOT;
    char* Anxt = As + (cur ^ 1) * ASLOT;
    char* Bnxt = Bs + (cur ^ 1) * BSLOT;
#pragma unroll
    for (int ni = 0; ni < NI; ni++) bfr[ni] = ldsfrag(Bcur, rB + ni * 16, g);
#pragma unroll
    for (int mi = 0; mi < 4; mi++) afr[mi] = ldsfrag(Acur, rA + mi * 16, g);
    if (kt + 1 < NT) stage_half<2>(Anxt + AHALF, Ag, K, (kt + 1) * 64 + 32, tid);
    __builtin_amdgcn_s_barrier();
    asm volatile("s_waitcnt lgkmcnt(0)" ::: "memory");
    __builtin_amdgcn_s_setprio(1);
#pragma unroll
    for (int mi = 0; mi < 4; mi++)
#pragma unroll
      for (int ni = 0; ni < NI; ni++)
        acc[mi][ni] = __builtin_amdgcn_mfma_f32_16x16x32_bf16(afr[mi], bfr[ni], acc[mi][ni], 0, 0, 0);
    __builtin_amdgcn_s_setprio(0);
    __builtin_amdgcn_s_barrier();
#pragma unroll
    for (int mi = 0; mi < 4; mi++) afr[mi] = ldsfrag(Acur, rA + 64 + mi * 16, g);
    if (kt + 1 < NT) stage_half<NLB>(Bnxt + BHALF, Bg, K, (kt + 1) * 64 + 32, tid);
    __builtin_amdgcn_s_barrier();
    asm volatile("s_waitcnt lgkmcnt(0)" ::: "memory");
    __builtin_amdgcn_s_setprio(1);
#pragma unroll
    for (int mi = 0; mi < 4; mi++)
#pragma unroll
      for (int ni = 0; ni < NI; ni++)
        acc[4 + mi][ni] = __builtin_amdgcn_mfma_f32_16x16x32_bf16(afr[mi], bfr[ni], acc[4 + mi][ni], 0, 0, 0);
    __builtin_amdgcn_s_setprio(0);
    if (kt + 1 < NT) waitvm<2 * PAIR>();
    else             waitvm<0>();
    __builtin_amdgcn_s_barrier();
#pragma unroll
    for (int ni = 0; ni < NI; ni++) bfr[ni] = ldsfrag(Bcur + BHALF, rB + ni * 16, g);
#pragma unroll
    for (int mi = 0; mi < 4; mi++) afr[mi] = ldsfrag(Acur + AHALF, rA + mi * 16, g);
    if (kt + 2 < NT) stage_half<2>(Acur, Ag, K, (kt + 2) * 64, tid);
    __builtin_amdgcn_s_barrier();
    asm volatile("s_waitcnt lgkmcnt(0)" ::: "memory");
    __builtin_amdgcn_s_setprio(1);
#pragma unroll
    for (int mi = 0; mi < 4; mi++)
#pragma unroll
      for (int ni = 0; ni < NI; ni++)
        acc[mi][ni] = __builtin_amdgcn_mfma_f32_16x16x32_bf16(afr[mi], bfr[ni], acc[mi][ni], 0, 0, 0);
    __builtin_amdgcn_s_setprio(0);
    __builtin_amdgcn_s_barrier();
#pragma unroll
    for (int mi = 0; mi < 4; mi++) afr[mi] = ldsfrag(Acur + AHALF, rA + 64 + mi * 16, g);
    if (kt + 2 < NT) stage_half<NLB>(Bcur, Bg, K, (kt + 2) * 64, tid);
    __builtin_amdgcn_s_barrier();
    asm volatile("s_waitcnt lgkmcnt(0)" ::: "memory");
    __builtin_amdgcn_s_setprio(1);
#pragma unroll
    for (int mi = 0; mi < 4; mi++)
#pragma unroll
      for (int ni = 0; ni < NI; ni++)
        acc[4 + mi][ni] = __builtin_amdgcn_mfma_f32_16x16x32_bf16(afr[mi], bfr[ni], acc[4 + mi][ni], 0, 0, 0);
    __builtin_amdgcn_s_setprio(0);
    if (kt < NT - 1) {
      if (kt + 2 < NT) waitvm<2 * PAIR>();
      else             waitvm<PAIR>();
    }
    __builtin_amdgcn_s_barrier();
  }
#pragma unroll
  for (int mi = 0; mi < 8; mi++)
#pragma unroll
    for (int ni = 0; ni < NI; ni++) {
      int row0 = m0 + wm * 128 + mi * 16 + ((lane >> 4) << 2);
      int col = n0 + wn * (BN / 4) + ni * 16 + (lane & 15);
#pragma unroll
      for (int j = 0; j < 4; j++) {
        if constexpr (sizeof(CT) == 2)
          C[(size_t)(row0 + j) * N + col] = f2bf(acc[mi][ni][j]);
        else
          C[(size_t)(row0 + j) * N + col] = acc[mi][ni][j];
      }
    }
}

// ---------------------------------------------------------------- Q projection GEMM + fused norm/rope/gate
// BN=256: each block's 256-col tile = one head's [query(0..127) | gate(128..255)].
// Epilogue v2: register ssq + q15 butterflies -> ssqb; qbuf LDS round-trip; per-row
// norm+rope with no shuffles.
__global__ __launch_bounds__(512, 2) void gemm8q(const u16t* __restrict__ A,
                                                 const u16t* __restrict__ Bt,
                                                 const float* __restrict__ rope,
                                                 const float* __restrict__ qw,
                                                 u16t* __restrict__ Qb,   // (B,H,S,D)
                                                 u16t* __restrict__ Gs,   // (B,S,H*D)
                                                 int K) {
  constexpr int NLB = 2, AHALF = 16384, ASLOT = 32768;
  constexpr int BHALF = 16384, BSLOT = 32768;
  constexpr int PAIR = 4, NI = 4;
  extern __shared__ __align__(16) char lds[];
  char* As = lds;
  char* Bs = lds + 2 * ASLOT;
  int tid = threadIdx.x, lane = tid & 63, w = tid >> 6;
  int wm = w >> 2, wn = w & 3;
  int cpx = gridDim.x >> 3;
  int wgid = (blockIdx.x & 7) * cpx + (blockIdx.x >> 3);
  int bm = wgid & 15, bn = wgid >> 4;             // bn = head h
  int m0 = bm << 8, n0 = bn << 8;
  const u16t* Ag = A + (size_t)m0 * K;
  const u16t* Bg = Bt + (size_t)n0 * K;
  const int NT = K >> 6;

  stage_half<2>(As, Ag, K, 0, tid);
  stage_half<NLB>(Bs, Bg, K, 0, tid);
  stage_half<2>(As + AHALF, Ag, K, 32, tid);
  stage_half<NLB>(Bs + BHALF, Bg, K, 32, tid);
  stage_half<2>(As + ASLOT, Ag, K, 64, tid);
  stage_half<NLB>(Bs + BSLOT, Bg, K, 64, tid);
  waitvm<2 * PAIR>();
  __builtin_amdgcn_s_barrier();

  const f32x4 fz = {0.f, 0.f, 0.f, 0.f};
  f32x4 acc[8][NI];
#pragma unroll
  for (int i = 0; i < 8; i++)
#pragma unroll
    for (int j = 0; j < NI; j++) acc[i][j] = fz;
  s16x8 afr[4], bfr[NI];
  int g = lane >> 4;
  int rA = (lane & 15) + wm * 128;
  int rB = (lane & 15) + wn * 64;

  for (int kt = 0; kt < NT; kt++) {
    int cur = kt & 1;
    char* Acur = As + cur * ASLOT;
    char* Bcur = Bs + cur * BSLOT;
    char* Anxt = As + (cur ^ 1) * ASLOT;
    char* Bnxt = Bs + (cur ^ 1) * BSLOT;
#pragma unroll
    for (int ni = 0; ni < NI; ni++) bfr[ni] = ldsfrag(Bcur, rB + ni * 16, g);
#pragma unroll
    for (int mi = 0; mi < 4; mi++) afr[mi] = ldsfrag(Acur, rA + mi * 16, g);
    if (kt + 1 < NT) stage_half<2>(Anxt + AHALF, Ag, K, (kt + 1) * 64 + 32, tid);
    __builtin_amdgcn_s_barrier();
    asm volatile("s_waitcnt lgkmcnt(0)" ::: "memory");
    __builtin_amdgcn_s_setprio(1);
#pragma unroll
    for (int mi = 0; mi < 4; mi++)
#pragma unroll
      for (int ni = 0; ni < NI; ni++)
        acc[mi][ni] = __builtin_amdgcn_mfma_f32_16x16x32_bf16(afr[mi], bfr[ni], acc[mi][ni], 0, 0, 0);
    __builtin_amdgcn_s_setprio(0);
    __builtin_amdgcn_s_barrier();
#pragma unroll
    for (int mi = 0; mi < 4; mi++) afr[mi] = ldsfrag(Acur, rA + 64 + mi * 16, g);
    if (kt + 1 < NT) stage_half<NLB>(Bnxt + BHALF, Bg, K, (kt + 1) * 64 + 32, tid);
    __builtin_amdgcn_s_barrier();
    asm volatile("s_waitcnt lgkmcnt(0)" ::: "memory");
    __builtin_amdgcn_s_setprio(1);
#pragma unroll
    for (int mi = 0; mi < 4; mi++)
#pragma unroll
      for (int ni = 0; ni < NI; ni++)
        acc[4 + mi][ni] = __builtin_amdgcn_mfma_f32_16x16x32_bf16(afr[mi], bfr[ni], acc[4 + mi][ni], 0, 0, 0);
    __builtin_amdgcn_s_setprio(0);
    if (kt + 1 < NT) waitvm<2 * PAIR>();
    else             waitvm<0>();
    __builtin_amdgcn_s_barrier();
#pragma unroll
    for (int ni = 0; ni < NI; ni++) bfr[ni] = ldsfrag(Bcur + BHALF, rB + ni * 16, g);
#pragma unroll
    for (int mi = 0; mi < 4; mi++) afr[mi] = ldsfrag(Acur + AHALF, rA + mi * 16, g);
    if (kt + 2 < NT) stage_half<2>(Acur, Ag, K, (kt + 2) * 64, tid);
    __builtin_amdgcn_s_barrier();
    asm volatile("s_waitcnt lgkmcnt(0)" ::: "memory");
    __builtin_amdgcn_s_setprio(1);
#pragma unroll
    for (int mi = 0; mi < 4; mi++)
#pragma unroll
      for (int ni = 0; ni < NI; ni++)
        acc[mi][ni] = __builtin_amdgcn_mfma_f32_16x16x32_bf16(afr[mi], bfr[ni], acc[mi][ni], 0, 0, 0);
    __builtin_amdgcn_s_setprio(0);
    __builtin_amdgcn_s_barrier();
#pragma unroll
    for (int mi = 0; mi < 4; mi++) afr[mi] = ldsfrag(Acur + AHALF, rA + 64 + mi * 16, g);
    if (kt + 2 < NT) stage_half<NLB>(Bcur, Bg, K, (kt + 2) * 64, tid);
    __builtin_amdgcn_s_barrier();
    asm volatile("s_waitcnt lgkmcnt(0)" ::: "memory");
    __builtin_amdgcn_s_setprio(1);
#pragma unroll
    for (int mi = 0; mi < 4; mi++)
#pragma unroll
      for (int ni = 0; ni < NI; ni++)
        acc[4 + mi][ni] = __builtin_amdgcn_mfma_f32_16x16x32_bf16(afr[mi], bfr[ni], acc[4 + mi][ni], 0, 0, 0);
    __builtin_amdgcn_s_setprio(0);
    if (kt < NT - 1) {
      if (kt + 2 < NT) waitvm<2 * PAIR>();
      else             waitvm<PAIR>();
    }
    __builtin_amdgcn_s_barrier();
  }

  // ---- fused epilogue v2 ------------------------------------------------
  int h = bn;
  float* qbuf = (float*)lds;                    // 256 rows x 128 f32, granule-swizzled
  float* ssqb = (float*)(lds + 131072);         // [2][256] partial sum-of-squares
  int q15 = lane & 15;
  if (wn < 2) {
    float ps[8][4];
#pragma unroll
    for (int mi = 0; mi < 8; mi++)
#pragma unroll
      for (int j = 0; j < 4; j++) {
        float s = 0.f;
#pragma unroll
        for (int ni = 0; ni < NI; ni++) { float v = acc[mi][ni][j]; s += v * v; }
        ps[mi][j] = s;
      }
#pragma unroll
    for (int d = 1; d < 16; d <<= 1)
#pragma unroll
      for (int mi = 0; mi < 8; mi++)
#pragma unroll
        for (int j = 0; j < 4; j++) ps[mi][j] += __shfl_xor(ps[mi][j], d);
#pragma unroll
    for (int mi = 0; mi < 8; mi++)
#pragma unroll
      for (int ni = 0; ni < NI; ni++) {
        int rl0 = wm * 128 + mi * 16 + ((lane >> 4) << 2);
        int c = wn * 64 + ni * 16 + q15;
        int gr = c >> 4;
#pragma unroll
        for (int j = 0; j < 4; j++) {
          int rl = rl0 + j;
          qbuf[rl * 128 + (((gr ^ ((rl >> 2) & 7)) << 4) | (c & 15))] = acc[mi][ni][j];
        }
      }
    if (q15 == 0) {
#pragma unroll
      for (int mi = 0; mi < 8; mi++)
#pragma unroll
        for (int j = 0; j < 4; j++) {
          int rl = wm * 128 + mi * 16 + (g << 2) + j;
          ssqb[wn * 256 + rl] = ps[mi][j];
        }
    }
  } else {
#pragma unroll
    for (int mi = 0; mi < 8; mi++)
#pragma unroll
      for (int ni = 0; ni < NI; ni++) {
        int row0 = m0 + wm * 128 + mi * 16 + ((lane >> 4) << 2);
        int d = (wn - 2) * 64 + ni * 16 + q15;
#pragma unroll
        for (int j = 0; j < 4; j++) {
          int bb = (row0 + j) >> 11, s = (row0 + j) & 2047;
          float gv = acc[mi][ni][j];
          Gs[((size_t)(bb * SS + s)) * (HH * DD) + h * DD + d] =
              f2bf(1.f / (1.f + __expf(-gv)));
        }
      }
  }
  __syncthreads();
  float qwl = qw[lane], qwh = qw[64 + lane];
  const float SC = 0.08838834764831845f * 1.4426950408889634f;
#pragma unroll 4
  for (int r2 = 0; r2 < 32; r2++) {
    int rl = w * 32 + r2;
    int row0 = m0 + rl;
    int bb = row0 >> 11, s = row0 & 2047;
    int swz = ((rl >> 2) & 7) << 4;
    int cl = lane, ch = 64 + lane;
    float xlo = qbuf[rl * 128 + ((((cl >> 4) << 4) ^ swz) | (cl & 15))];
    float xhi = qbuf[rl * 128 + ((((ch >> 4) << 4) ^ swz) | (ch & 15))];
    float ss2 = ssqb[rl] + ssqb[256 + rl];
    float r = rsqrtf(ss2 * (1.f / 128.f) + 1e-6f);
    float qlo = xlo * r * (1.f + qwl);
    float qhi = xhi * r * (1.f + qwh);
    const float* cs = rope + (size_t)s * 256;
    float clo = cs[lane], chi = cs[64 + lane];
    float slo = cs[128 + lane], shi = cs[192 + lane];
    float olo = (qlo * clo - qhi * slo) * SC;
    float ohi = (qhi * chi + qlo * shi) * SC;
    size_t qoff = (((size_t)bb * HH + h) * SS + s) * DD;
    Qb[qoff + lane] = f2bf(olo);
    Qb[qoff + 64 + lane] = f2bf(ohi);
  }
}

// ---------------------------------------------------------------- KV projection GEMM v2 (8 waves)
// 512 threads, 8 waves as 2 M-rows x 4 N-cols (64x32 out per wave, acc[4][2]).
// Grid 256 = 1 block/CU but 2 waves/SIMD (the proven m97 overlap regime; the
// 4-wave version ran at 1 wave/SIMD -- latency-exposed).
// bn 0..3 = K head -> fused RMSNorm+RoPE -> Kb (bf16) + present-K (f32).
// bn 4..7 = V-heads -> present (f32) + Vtb (bf16) from registers.
__global__ __launch_bounds__(512) void gemm_kv(const u16t* __restrict__ A,
                                               const u16t* __restrict__ Bt,
                                               const float* __restrict__ rope,
                                               const float* __restrict__ kw,
                                               u16t* __restrict__ Kb,
                                               float* __restrict__ present,
                                               u16t* __restrict__ Vtb,
                                               int K) {
  extern __shared__ __align__(16) char lds[];
  char* As = lds;            // 8KB (128 rows x 64B)
  char* Bs = lds + 8192;     // 8KB
  int tid = threadIdx.x;
  int lane = tid & 63;
  int w = tid >> 6;                          // 0..7
  int cpx = gridDim.x >> 3;
  int wgid = ((int)blockIdx.x & 7) * cpx + ((int)blockIdx.x >> 3);
  const int mtiles = MM >> 7;                 // 32
  int bm = wgid % mtiles;
  int bn = wgid / mtiles;                     // 0..7
  int m0 = bm << 7, n0 = bn << 7;
  int wr = (w >> 2) * 64, wc = (w & 3) * 32;  // 2x4 wave map

  const f32x4 fz = {0.f, 0.f, 0.f, 0.f};
  f32x4 acc[4][2];
#pragma unroll
  for (int i = 0; i < 4; i++)
#pragma unroll
    for (int j = 0; j < 2; j++) acc[i][j] = fz;

  for (int k0 = 0; k0 < K; k0 += 32) {
    __syncthreads();
    {
      int idx = tid;                          // 512 x 16B = 8KB: one round each
      int r = idx >> 2, c = idx & 3;
      int csrc = c ^ ((r >> 1) & 3);
      gload_lds16(A + (size_t)(m0 + r) * K + k0 + csrc * 8, As + idx * 16);
      gload_lds16(Bt + (size_t)(n0 + r) * K + k0 + csrc * 8, Bs + idx * 16);
    }
    __syncthreads();
    s16x8 af[4], bf[2];
    int g = lane >> 4;
#pragma unroll
    for (int mi = 0; mi < 4; mi++) {
      int r = wr + mi * 16 + (lane & 15);
      af[mi] = *(const s16x8*)(As + r * 64 + ((g ^ ((r >> 1) & 3)) << 4));
    }
#pragma unroll
    for (int ni = 0; ni < 2; ni++) {
      int r = wc + ni * 16 + (lane & 15);
      bf[ni] = *(const s16x8*)(Bs + r * 64 + ((g ^ ((r >> 1) & 3)) << 4));
    }
#pragma unroll
    for (int mi = 0; mi < 4; mi++)
#pragma unroll
      for (int ni = 0; ni < 2; ni++)
        acc[mi][ni] = __builtin_amdgcn_mfma_f32_16x16x32_bf16(af[mi], bf[ni], acc[mi][ni], 0, 0, 0);
  }
  if (bn < 4) {
    // ---- fused K epilogue: RMSNorm + RoPE (head kv = bn) ----
    int kv = bn;
    int q15 = lane & 15, g = lane >> 4;
    __syncthreads();                        // protect As/Bs before reuse as kbuf
    float* kbuf = (float*)lds;              // 128 rows x 128 f32 (64KB), granule-swz
    float* ssqb = (float*)(lds + 65536);    // [4][128] quarter-column partials
    float ps[4][4];
#pragma unroll
    for (int mi = 0; mi < 4; mi++)
#pragma unroll
      for (int j = 0; j < 4; j++) {
        float s = 0.f;
#pragma unroll
        for (int ni = 0; ni < 2; ni++) { float v = acc[mi][ni][j]; s += v * v; }
        ps[mi][j] = s;
      }
#pragma unroll
    for (int d = 1; d < 16; d <<= 1)
#pragma unroll
      for (int mi = 0; mi < 4; mi++)
#pragma unroll
        for (int j = 0; j < 4; j++) ps[mi][j] += __shfl_xor(ps[mi][j], d);
#pragma unroll
    for (int mi = 0; mi < 4; mi++)
#pragma unroll
      for (int ni = 0; ni < 2; ni++) {
        int rl0 = wr + mi * 16 + (g << 2);
        int c = wc + ni * 16 + q15;
        int gr = c >> 4;
#pragma unroll
        for (int j = 0; j < 4; j++) {
          int rl = rl0 + j;
          kbuf[rl * 128 + (((gr ^ ((rl >> 2) & 7)) << 4) | (c & 15))] = acc[mi][ni][j];
        }
      }
    if (q15 == 0) {
#pragma unroll
      for (int mi = 0; mi < 4; mi++)
#pragma unroll
        for (int j = 0; j < 4; j++) {
          int rl = wr + mi * 16 + (g << 2) + j;
          ssqb[(w & 3) * 128 + rl] = ps[mi][j];
        }
    }
    __syncthreads();
    float kwl = kw[lane], kwh = kw[64 + lane];
#pragma unroll 4
    for (int r2 = 0; r2 < 16; r2++) {
      int rl = w * 16 + r2;                 // 8 waves x 16 rows = 128
      int row0 = m0 + rl;
      int bb = row0 >> 11, s = row0 & 2047;
      int swz = ((rl >> 2) & 7) << 4;
      int cl = lane, ch = 64 + lane;
      float xlo = kbuf[rl * 128 + ((((cl >> 4) << 4) ^ swz) | (cl & 15))];
      float xhi = kbuf[rl * 128 + ((((ch >> 4) << 4) ^ swz) | (ch & 15))];
      float ss2 = ssqb[rl] + ssqb[128 + rl] + ssqb[256 + rl] + ssqb[384 + rl];
      float r = rsqrtf(ss2 * (1.f / 128.f) + 1e-6f);
      float klo = xlo * r * (1.f + kwl);
      float khi = xhi * r * (1.f + kwh);
      const float* cs = rope + (size_t)s * 256;
      float clo = cs[lane], chi = cs[64 + lane];
      float slo = cs[128 + lane], shi = cs[192 + lane];
      float olo = klo * clo - khi * slo;       // K is NOT pre-scaled
      float ohi = khi * chi + klo * shi;
      size_t koff = (((size_t)bb * KVH + kv) * SS + s) * DD;
      Kb[koff + lane] = f2bf(olo);
      Kb[koff + 64 + lane] = f2bf(ohi);
      size_t poff = (((size_t)(bb * 2 * KVH + kv)) * SS + s) * DD;
      present[poff + lane] = olo;
      present[poff + 64 + lane] = ohi;
    }
  } else {
#pragma unroll
    for (int mi = 0; mi < 4; mi++)
#pragma unroll
      for (int ni = 0; ni < 2; ni++) {
        int row0 = m0 + wr + mi * 16 + ((lane >> 4) << 2);
        int vcol = (n0 - 512) + wc + ni * 16 + (lane & 15);
        int kv = vcol >> 7, d = vcol & 127;
        int bb = row0 >> 11, sp = row0 & 2047;
        size_t pbase = (((size_t)(bb * 2 * KVH + KVH + kv)) * SS + sp) * DD + d;
#pragma unroll
        for (int j = 0; j < 4; j++)
          present[pbase + (size_t)j * DD] = acc[mi][ni][j];
        s16x4 pk;
        pk[0] = (short)f2bf(acc[mi][ni][0]);
        pk[1] = (short)f2bf(acc[mi][ni][1]);
        pk[2] = (short)f2bf(acc[mi][ni][2]);
        pk[3] = (short)f2bf(acc[mi][ni][3]);
        *(s16x4*)(Vtb + ((size_t)(bb * KVH + kv) * DD + d) * SS + sp) = pk;
      }
  }
}

// ---------------------------------------------------------------- flash attention v5.1 (round-12 verbatim)
__global__ __launch_bounds__(256, 2) void attn_kernel(const u16t* __restrict__ Qb,   // (B,H,S,D) pre-scaled
                                                      const u16t* __restrict__ Kb,   // (B,KV,S,D)
                                                      const u16t* __restrict__ Vtb,  // (B,KV,D,S)
                                                      const u16t* __restrict__ Gs,   // (B,S,H*D)
                                                      u16t* __restrict__ AttG) {     // (B,S,H*D)
  __shared__ __align__(16) char Ks[2 * 16384];  // 64 rows x 256B, chunk xor (r&7)
  __shared__ __align__(16) char Vs[2 * 16384];  // V^T: 128 rows x 128B, chunk xor (d&7)
  __shared__ __align__(16) char Ps[4 * 2048];   // per-wave P: [q:16][k-granule xor (q&7)]

  int tid = threadIdx.x, lane = tid & 63, w = tid >> 6;
  int x = blockIdx.x & 7;          // XCD grouping: each XCD owns one (b,kv)
  int b = x >> 2, kv = x & 3;
  int rr = blockIdx.x >> 3;        // 0..63
  int h = kv * 4 + (rr & 3);
  int p = rr >> 2;                 // 0..15: pair {31-p, p}

  const u16t* Kbase = Kb + (((size_t)(b * KVH + kv)) * SS) * DD;
  const u16t* Vbase = Vtb + (((size_t)(b * KVH + kv)) * DD) * SS;

  auto stageK = [&](int kt, int buf) {
#pragma unroll
    for (int i = 0; i < 4; i++) {
      int idx = i * 256 + tid;
      int r_ = idx >> 4, c_ = idx & 15;
      gload_lds16(Kbase + (size_t)(kt * 64 + r_) * DD + (c_ ^ (r_ & 7)) * 8,
                  Ks + buf * 16384 + idx * 16);
    }
  };
  auto stageV = [&](int kt, int buf) {
#pragma unroll
    for (int i = 0; i < 4; i++) {
      int idx = i * 256 + tid;
      int r_ = idx >> 3, c_ = idx & 7;
      gload_lds16(Vbase + (size_t)r_ * SS + kt * 64 + (c_ ^ (r_ & 7)) * 8,
                  Vs + buf * 16384 + idx * 16);
    }
  };

  const f32x4 fz = {0.f, 0.f, 0.f, 0.f};
  int g = lane >> 4;
  int q15 = lane & 15;
  int q7 = q15 & 7;
  char* pq = Ps + w * 2048 + q15 * 128;   // this lane's q-row in P
  int cur = 0;

  int ka[4][4];
#pragma unroll
  for (int ni = 0; ni < 4; ni++)
#pragma unroll
    for (int ks = 0; ks < 4; ks++)
      ka[ni][ks] = (ni * 16 + q15) * 256 + (((ks * 4 + g) ^ q7) << 4);
  int va[2][8];
#pragma unroll
  for (int ks2 = 0; ks2 < 2; ks2++)
#pragma unroll
    for (int f = 0; f < 8; f++)
      va[ks2][f] = (f * 16 + q15) * 128 + (((ks2 * 4 + g) ^ q7) << 4);
  int pr_[2];
#pragma unroll
  for (int ks2 = 0; ks2 < 2; ks2++) pr_[ks2] = ((ks2 * 4 + g) ^ q7) << 4;
  int pw_[4];
#pragma unroll
  for (int ni = 0; ni < 4; ni++)
    pw_[ni] = (((ni * 2 + (g >> 1)) ^ q7) << 4) + ((g & 1) << 3);

  stageK(0, 0);
  stageV(0, 0);

  for (int seg = 0; seg < 2; seg++) {
    int qt = (seg == 0) ? (31 - p) : p;
    const u16t* Qbase = Qb + (((size_t)(b * HH + h)) * SS + qt * 64) * DD;
    s16x8 qf[4];
    {
      const u16t* qrow = Qbase + (size_t)(w * 16 + q15) * DD + g * 8;
#pragma unroll
      for (int ks = 0; ks < 4; ks++) qf[ks] = *(const s16x8*)(qrow + ks * 32);
    }
    f32x4 acco[8];
#pragma unroll
    for (int f = 0; f < 8; f++) acco[f] = fz;
    float mrun = -INFINITY, lrun = 0.f;

    if (seg == 0) {
      asm volatile("s_waitcnt vmcnt(0)" ::: "memory");
      __builtin_amdgcn_s_barrier();
    }

    for (int kt = 0; kt <= qt; kt++) {
      bool havenext = (kt < qt) || (seg == 0);
      if (havenext) {
        int nk = (kt < qt) ? (kt + 1) : 0;
        stageK(nk, cur ^ 1);
        stageV(nk, cur ^ 1);
      }
      const char* kc = Ks + (cur << 14);
      const char* vc = Vs + (cur << 14);
      f32x4 accs[4];
#pragma unroll
      for (int ni = 0; ni < 4; ni++) accs[ni] = fz;
#pragma unroll
      for (int ni = 0; ni < 4; ni++)
#pragma unroll
        for (int ks = 0; ks < 4; ks++) {
          s16x8 bfk = *(const s16x8*)(kc + ka[ni][ks]);
          accs[ni] = __builtin_amdgcn_mfma_f32_16x16x32_bf16(bfk, qf[ks], accs[ni], 0, 0, 0);
        }
      if (kt == qt) {
        int ql = w * 16 + q15;
#pragma unroll
        for (int ni = 0; ni < 4; ni++)
#pragma unroll
          for (int j = 0; j < 4; j++) {
            int kl = ni * 16 + (g << 2) + j;
            if (kl > ql) accs[ni][j] = -1e30f;
          }
      }
      f32x4 m4 = fmax4(fmax4(accs[0], accs[1]), fmax4(accs[2], accs[3]));
      float mt = fmaxf(fmaxf(m4[0], m4[1]), fmaxf(m4[2], m4[3]));
      mt = fmaxf(mt, __shfl_xor(mt, 16));
      mt = fmaxf(mt, __shfl_xor(mt, 32));
      float mnew = fmaxf(mrun, mt);
      float alpha = __builtin_amdgcn_exp2f(mrun - mnew);
      mrun = mnew;
#pragma unroll
      for (int ni = 0; ni < 4; ni++)
#pragma unroll
        for (int j = 0; j < 4; j++)
          accs[ni][j] = __builtin_amdgcn_exp2f(accs[ni][j] - mnew);
      f32x4 s4 = (accs[0] + accs[1]) + (accs[2] + accs[3]);
      float rs = (s4[0] + s4[1]) + (s4[2] + s4[3]);
      rs += __shfl_xor(rs, 16);
      rs += __shfl_xor(rs, 32);
      lrun = lrun * alpha + rs;
      float ar[4];
#pragma unroll
      for (int j = 0; j < 4; j++) ar[j] = __shfl(alpha, (g << 2) + j);
#pragma unroll
      for (int f = 0; f < 8; f++)
#pragma unroll
        for (int j = 0; j < 4; j++) acco[f][j] *= ar[j];

#pragma unroll
      for (int ni = 0; ni < 4; ni++) {
        uint2 pk;
        pk.x = cvtpk_bf16(accs[ni][0], accs[ni][1]);
        pk.y = cvtpk_bf16(accs[ni][2], accs[ni][3]);
        *(uint2*)(pq + pw_[ni]) = pk;
      }
#pragma unroll
      for (int ks2 = 0; ks2 < 2; ks2++) {
        s16x8 pa = *(const s16x8*)(pq + pr_[ks2]);
#pragma unroll
        for (int f = 0; f < 8; f++) {
          s16x8 vf = *(const s16x8*)(vc + va[ks2][f]);
          acco[f] = __builtin_amdgcn_mfma_f32_16x16x32_bf16(pa, vf, acco[f], 0, 0, 0);
        }
      }
      if (havenext) {
        asm volatile("s_waitcnt vmcnt(0)" ::: "memory");
        __builtin_amdgcn_s_barrier();
        cur ^= 1;
      }
    }
    float lr[4];
#pragma unroll
    for (int j = 0; j < 4; j++) lr[j] = __shfl(lrun, (g << 2) + j);
#pragma unroll
    for (int f = 0; f < 8; f++) {
      int d = f * 16 + q15;
#pragma unroll
      for (int j = 0; j < 4; j++) {
        int srow = qt * 64 + w * 16 + (g << 2) + j;
        float o = acco[f][j] / lr[j];
        size_t off = ((size_t)b * SS + srow) * (HH * DD) + h * DD + d;
        float gt = bf2f(Gs[off]);
        AttG[off] = f2bf(o * gt);
      }
    }
  }
}

// ---------------------------------------------------------------- launcher
extern "C" void kernel_launch(void* const* d_in, const int* in_sizes, int n_in,
                              void* d_out, int out_size, void* d_ws, size_t ws_size,
                              hipStream_t stream) {
  const float* hidden = (const float*)d_in[0];
  const float* rope   = (const float*)d_in[2];
  const float* Wq     = (const float*)d_in[5];
  const float* Wk     = (const float*)d_in[6];
  const float* Wv     = (const float*)d_in[7];
  const float* Wo     = (const float*)d_in[8];
  const float* qw     = (const float*)d_in[9];
  const float* kw     = (const float*)d_in[10];
  float* out = (float*)d_out;
  float* present = out + (size_t)BB * SS * HIDD; // 8,388,608

  char* ws = (char*)d_ws;
  u16t* Xb    = (u16t*)(ws);                              // 4096x2048 bf16   16.78MB
  u16t* Wt    = (u16t*)(ws + 16777216);                   // 5120x2048 bf16   20.97MB
  u16t* Wot   = (u16t*)(ws + 37748736);                   // 2048x2048 bf16    8.39MB
  u16t* Qb    = (u16t*)(ws + 88080384);                   // (B,H,S,D) bf16   16.78MB
  u16t* Kb    = (u16t*)(ws + 104857600);                  // (B,KV,S,D) bf16   4.19MB
  u16t* Vtb   = (u16t*)(ws + 109051904);                  // (B,KV,D,S) bf16   4.19MB
  u16t* Gs    = (u16t*)(ws + 113246208);                  // (B,S,H*D) bf16   16.78MB
  u16t* AttG  = Xb;  // alias: Xb dead after projections; AttG written by attention

  (void)hipFuncSetAttribute(reinterpret_cast<const void*>(gemm8q),
                            hipFuncAttributeMaxDynamicSharedMemorySize, 133120);
  (void)hipFuncSetAttribute(reinterpret_cast<const void*>(gemm_kv),
                            hipFuncAttributeMaxDynamicSharedMemorySize, 67584);
  (void)hipFuncSetAttribute(reinterpret_cast<const void*>(gemm8<128, float>),
                            hipFuncAttributeMaxDynamicSharedMemorySize, 98304);

  // 1+2. fused prep: cast hidden + weight transposes
  prep_all<<<4096 + 3584, 256, 0, stream>>>(hidden, Wq, Wk, Wv, Wo, Xb, Wt, Wot);
  // 3a. Q projection + fused RMSNorm/RoPE/gate: grid 256 = 1 block/CU
  gemm8q<<<(MM / 256) * (4096 / 256), 512, 133120, stream>>>(Xb, Wt, rope, qw, Qb, Gs, HIDD);
  // 3b. K+V projection v2 (8 waves = 2 waves/SIMD) with fused K-norm/rope + V epilogues
  gemm_kv<<<(MM / 128) * (1024 / 128), 512, 67584, stream>>>(
      Xb, Wt + (size_t)4096 * HIDD, rope, kw, Kb, present, Vtb, HIDD);
  // 4. flash attention v5.1 (round-12 verbatim)
  attn_kernel<<<BB * HH * (SS / 128), 256, 0, stream>>>(Qb, Kb, Vtb, Gs, AttG);
  // 5. output projection -> d_out: 256x128 8-phase, grid 16x16 = 256 = 1 block/CU
  gemm8<128, float><<<(MM / 256) * (HIDD / 128), 512, 98304, stream>>>(AttG, Wot, out, MM, HIDD, HIDD);
}

// Round 21
// 248.614 us; speedup vs baseline: 1.1141x; 1.0024x over previous
//
#include <hip/hip_runtime.h>
#include <hip/hip_bf16.h>
#include <cstdint>
#include <cstddef>

// Problem constants
#define BB   2
#define SS   2048
#define HIDD 2048
#define HH   16
#define KVH  4
#define DD   128
#define NQKV 5120   // H*2*D + KV*D + KV*D = 4096 + 512 + 512
#define MM   4096   // B*S

typedef unsigned short u16t;
typedef __attribute__((ext_vector_type(8))) short s16x8;
typedef __attribute__((ext_vector_type(4))) short s16x4;
typedef __attribute__((ext_vector_type(4))) float f32x4;

__device__ __forceinline__ u16t f2bf(float f) {
  unsigned u = __float_as_uint(f);
  u += 0x7fffu + ((u >> 16) & 1u);
  return (u16t)(u >> 16);
}
__device__ __forceinline__ float bf2f(u16t h) {
  return __uint_as_float(((unsigned)h) << 16);
}
__device__ __forceinline__ void gload_lds16(const void* g, void* l) {
  __builtin_amdgcn_global_load_lds(
      (const __attribute__((address_space(1))) unsigned int*)g,
      (__attribute__((address_space(3))) unsigned int*)l, 16, 0, 0);
}
__device__ __forceinline__ unsigned cvtpk_bf16(float lo, float hi) {
  unsigned r;
  asm("v_cvt_pk_bf16_f32 %0, %1, %2" : "=v"(r) : "v"(lo), "v"(hi));
  return r;
}
__device__ __forceinline__ f32x4 fmax4(f32x4 a, f32x4 b) {
  f32x4 r;
  r[0] = fmaxf(a[0], b[0]); r[1] = fmaxf(a[1], b[1]);
  r[2] = fmaxf(a[2], b[2]); r[3] = fmaxf(a[3], b[3]);
  return r;
}
// counted vmcnt via literal asm (compiler-ordering fence through "memory" clobber).
// Round-11/14 lessons: __builtin_amdgcn_s_waitcnt is NOT a memory fence; and
// defer-max (T13) breaks correctness on this pipelined structure -- banned.
template <int N>
__device__ __forceinline__ void waitvm() {
  static_assert(N == 0 || N == 3 || N == 4 || N == 6 || N == 8, "add literal");
  if constexpr (N == 0)      asm volatile("s_waitcnt vmcnt(0)" ::: "memory");
  else if constexpr (N == 3) asm volatile("s_waitcnt vmcnt(3)" ::: "memory");
  else if constexpr (N == 4) asm volatile("s_waitcnt vmcnt(4)" ::: "memory");
  else if constexpr (N == 6) asm volatile("s_waitcnt vmcnt(6)" ::: "memory");
  else if constexpr (N == 8) asm volatile("s_waitcnt vmcnt(8)" ::: "memory");
}

// ----------------------------------------- fused prep: cast hidden + transpose-cast all weights
__global__ __launch_bounds__(256) void prep_all(const float* __restrict__ hidden,
                                                const float* __restrict__ Wq,
                                                const float* __restrict__ Wk,
                                                const float* __restrict__ Wv,
                                                const float* __restrict__ Wo,
                                                u16t* __restrict__ Xb,
                                                u16t* __restrict__ Wt,
                                                u16t* __restrict__ Wot) {
  __shared__ float lds[64 * 65];
  int bid = blockIdx.x;
  int t = threadIdx.x;
  if (bid < 4096) {
    size_t i = ((size_t)bid * 256 + t) * 8;
    f32x4 v0 = *(const f32x4*)(hidden + i);
    f32x4 v1 = *(const f32x4*)(hidden + i + 4);
    s16x8 o;
    o[0] = (short)f2bf(v0[0]); o[1] = (short)f2bf(v0[1]);
    o[2] = (short)f2bf(v0[2]); o[3] = (short)f2bf(v0[3]);
    o[4] = (short)f2bf(v1[0]); o[5] = (short)f2bf(v1[1]);
    o[6] = (short)f2bf(v1[2]); o[7] = (short)f2bf(v1[3]);
    *(s16x8*)(Xb + i) = o;
    return;
  }
  bid -= 4096;
  const float* src; u16t* dst; int N;
  if (bid < 2048)      { src = Wq; dst = Wt;                         N = 4096; }
  else if (bid < 2304) { src = Wk; dst = Wt + (size_t)4096 * HIDD;   N = 512;  bid -= 2048; }
  else if (bid < 2560) { src = Wv; dst = Wt + (size_t)4608 * HIDD;   N = 512;  bid -= 2304; }
  else                 { src = Wo; dst = Wot;                        N = 2048; bid -= 2560; }
  const int ktiles = HIDD / 64; // 32
  int n0 = (bid / ktiles) << 6;
  int k0 = (bid % ktiles) << 6;
#pragma unroll
  for (int i = 0; i < 16; i++) {
    int idx = i * 256 + t;
    int r = idx >> 6, c = idx & 63;
    lds[c * 65 + r] = src[(size_t)(k0 + r) * N + n0 + c];
  }
  __syncthreads();
#pragma unroll
  for (int i = 0; i < 2; i++) {
    int idx = i * 256 + t;
    int rr = idx >> 3, k8 = (idx & 7) * 8;
    s16x8 o;
#pragma unroll
    for (int e = 0; e < 8; e++) o[e] = (short)f2bf(lds[rr * 65 + k8 + e]);
    *(s16x8*)(dst + (size_t)(n0 + rr) * HIDD + k0 + k8) = o;
  }
}

// ---------------------------------------------------------------- shared GEMM pieces
__device__ __forceinline__ s16x8 ldsfrag(const char* half, int r, int g) {
  return *(const s16x8*)(half + r * 64 + ((g ^ ((r >> 1) & 3)) << 4));
}
template <int NL>
__device__ __forceinline__ void stage_half(char* ldsbase, const u16t* gbase,
                                           int K, int kcol, int tid) {
#pragma unroll
  for (int i = 0; i < NL; i++) {
    int o16 = i * 512 + tid;
    int r = o16 >> 2;
    int cs = (o16 & 3) ^ ((r >> 1) & 3);
    gload_lds16(gbase + (size_t)r * K + kcol + cs * 8, ldsbase + o16 * 16);
  }
}

// ---------------------------------------------------------------- 256xBN 8-phase bf16 GEMM
// (used for O-proj with BN=128). grid = (M/256)*(n/BN); M/256 must be 16.
template <int BN, typename CT>
__global__ __launch_bounds__(512, 2) void gemm8(const u16t* __restrict__ A,
                                                const u16t* __restrict__ Bt,
                                                CT* __restrict__ C,
                                                int M, int N, int K) {
  constexpr int NLB = BN / 128;            // B-half loads/thread
  constexpr int AHALF = 16384, ASLOT = 32768;
  constexpr int BHALF = BN * 64, BSLOT = 2 * BHALF;
  constexpr int PAIR = 2 + NLB;            // loads per (A,B) half-tile pair
  constexpr int NI = BN / 64;              // B frags per wave
  extern __shared__ __align__(16) char lds[];
  char* As = lds;
  char* Bs = lds + 2 * ASLOT;
  int tid = threadIdx.x, lane = tid & 63, w = tid >> 6;
  int wm = w >> 2, wn = w & 3;
  int cpx = gridDim.x >> 3;                       // grid % 8 == 0
  int wgid = (blockIdx.x & 7) * cpx + (blockIdx.x >> 3);
  int bm = wgid & 15, bn = wgid >> 4;             // M/256 == 16
  int m0 = bm << 8, n0 = bn * BN;
  const u16t* Ag = A + (size_t)m0 * K;
  const u16t* Bg = Bt + (size_t)n0 * K;
  const int NT = K >> 6;

  stage_half<2>(As, Ag, K, 0, tid);
  stage_half<NLB>(Bs, Bg, K, 0, tid);
  stage_half<2>(As + AHALF, Ag, K, 32, tid);
  stage_half<NLB>(Bs + BHALF, Bg, K, 32, tid);
  stage_half<2>(As + ASLOT, Ag, K, 64, tid);
  stage_half<NLB>(Bs + BSLOT, Bg, K, 64, tid);
  waitvm<2 * PAIR>();
  __builtin_amdgcn_s_barrier();

  const f32x4 fz = {0.f, 0.f, 0.f, 0.f};
  f32x4 acc[8][NI];
#pragma unroll
  for (int i = 0; i < 8; i++)
#pragma unroll
    for (int j = 0; j < NI; j++) acc[i][j] = fz;
  s16x8 afr[4], bfr[NI];
  int g = lane >> 4;
  int rA = (lane & 15) + wm * 128;
  int rB = (lane & 15) + wn * (BN / 4);

  for (int kt = 0; kt < NT; kt++) {
    int cur = kt & 1;
    char* Acur = As + cur * ASLOT;
    char* Bcur = Bs + cur * BSLOT;
    char* Anxt = As + (cur ^ 1) * ASLOT;
    char* Bnxt = Bs + (cur ^ 1) * BSLOT;
#pragma unroll
    for (int ni = 0; ni < NI; ni++) bfr[ni] = ldsfrag(Bcur, rB + ni * 16, g);
#pragma unroll
    for (int mi = 0; mi < 4; mi++) afr[mi] = ldsfrag(Acur, rA + mi * 16, g);
    if (kt + 1 < NT) stage_half<2>(Anxt + AHALF, Ag, K, (kt + 1) * 64 + 32, tid);
    __builtin_amdgcn_s_barrier();
    asm volatile("s_waitcnt lgkmcnt(0)" ::: "memory");
    __builtin_amdgcn_s_setprio(1);
#pragma unroll
    for (int mi = 0; mi < 4; mi++)
#pragma unroll
      for (int ni = 0; ni < NI; ni++)
        acc[mi][ni] = __builtin_amdgcn_mfma_f32_16x16x32_bf16(afr[mi], bfr[ni], acc[mi][ni], 0, 0, 0);
    __builtin_amdgcn_s_setprio(0);
    __builtin_amdgcn_s_barrier();
#pragma unroll
    for (int mi = 0; mi < 4; mi++) afr[mi] = ldsfrag(Acur, rA + 64 + mi * 16, g);
    if (kt + 1 < NT) stage_half<NLB>(Bnxt + BHALF, Bg, K, (kt + 1) * 64 + 32, tid);
    __builtin_amdgcn_s_barrier();
    asm volatile("s_waitcnt lgkmcnt(0)" ::: "memory");
    __builtin_amdgcn_s_setprio(1);
#pragma unroll
    for (int mi = 0; mi < 4; mi++)
#pragma unroll
      for (int ni = 0; ni < NI; ni++)
        acc[4 + mi][ni] = __builtin_amdgcn_mfma_f32_16x16x32_bf16(afr[mi], bfr[ni], acc[4 + mi][ni], 0, 0, 0);
    __builtin_amdgcn_s_setprio(0);
    if (kt + 1 < NT) waitvm<2 * PAIR>();
    else             waitvm<0>();
    __builtin_amdgcn_s_barrier();
#pragma unroll
    for (int ni = 0; ni < NI; ni++) bfr[ni] = ldsfrag(Bcur + BHALF, rB + ni * 16, g);
#pragma unroll
    for (int mi = 0; mi < 4; mi++) afr[mi] = ldsfrag(Acur + AHALF, rA + mi * 16, g);
    if (kt + 2 < NT) stage_half<2>(Acur, Ag, K, (kt + 2) * 64, tid);
    __builtin_amdgcn_s_barrier();
    asm volatile("s_waitcnt lgkmcnt(0)" ::: "memory");
    __builtin_amdgcn_s_setprio(1);
#pragma unroll
    for (int mi = 0; mi < 4; mi++)
#pragma unroll
      for (int ni = 0; ni < NI; ni++)
        acc[mi][ni] = __builtin_amdgcn_mfma_f32_16x16x32_bf16(afr[mi], bfr[ni], acc[mi][ni], 0, 0, 0);
    __builtin_amdgcn_s_setprio(0);
    __builtin_amdgcn_s_barrier();
#pragma unroll
    for (int mi = 0; mi < 4; mi++) afr[mi] = ldsfrag(Acur + AHALF, rA + 64 + mi * 16, g);
    if (kt + 2 < NT) stage_half<NLB>(Bcur, Bg, K, (kt + 2) * 64, tid);
    __builtin_amdgcn_s_barrier();
    asm volatile("s_waitcnt lgkmcnt(0)" ::: "memory");
    __builtin_amdgcn_s_setprio(1);
#pragma unroll
    for (int mi = 0; mi < 4; mi++)
#pragma unroll
      for (int ni = 0; ni < NI; ni++)
        acc[4 + mi][ni] = __builtin_amdgcn_mfma_f32_16x16x32_bf16(afr[mi], bfr[ni], acc[4 + mi][ni], 0, 0, 0);
    __builtin_amdgcn_s_setprio(0);
    if (kt < NT - 1) {
      if (kt + 2 < NT) waitvm<2 * PAIR>();
      else             waitvm<PAIR>();
    }
    __builtin_amdgcn_s_barrier();
  }
#pragma unroll
  for (int mi = 0; mi < 8; mi++)
#pragma unroll
    for (int ni = 0; ni < NI; ni++) {
      int row0 = m0 + wm * 128 + mi * 16 + ((lane >> 4) << 2);
      int col = n0 + wn * (BN / 4) + ni * 16 + (lane & 15);
#pragma unroll
      for (int j = 0; j < 4; j++) {
        if constexpr (sizeof(CT) == 2)
          C[(size_t)(row0 + j) * N + col] = f2bf(acc[mi][ni][j]);
        else
          C[(size_t)(row0 + j) * N + col] = acc[mi][ni][j];
      }
    }
}

// ---------------------------------------------------------------- Q projection GEMM + fused norm/rope/gate
// BN=256: each block's 256-col tile = one head's [query(0..127) | gate(128..255)].
// Epilogue v2: register ssq + q15 butterflies -> ssqb; qbuf LDS round-trip; per-row
// norm+rope with no shuffles.
__global__ __launch_bounds__(512, 2) void gemm8q(const u16t* __restrict__ A,
                                                 const u16t* __restrict__ Bt,
                                                 const float* __restrict__ rope,
                                                 const float* __restrict__ qw,
                                                 u16t* __restrict__ Qb,   // (B,H,S,D)
                                                 u16t* __restrict__ Gs,   // (B,S,H*D)
                                                 int K) {
  constexpr int NLB = 2, AHALF = 16384, ASLOT = 32768;
  constexpr int BHALF = 16384, BSLOT = 32768;
  constexpr int PAIR = 4, NI = 4;
  extern __shared__ __align__(16) char lds[];
  char* As = lds;
  char* Bs = lds + 2 * ASLOT;
  int tid = threadIdx.x, lane = tid & 63, w = tid >> 6;
  int wm = w >> 2, wn = w & 3;
  int cpx = gridDim.x >> 3;
  int wgid = (blockIdx.x & 7) * cpx + (blockIdx.x >> 3);
  int bm = wgid & 15, bn = wgid >> 4;             // bn = head h
  int m0 = bm << 8, n0 = bn << 8;
  const u16t* Ag = A + (size_t)m0 * K;
  const u16t* Bg = Bt + (size_t)n0 * K;
  const int NT = K >> 6;

  stage_half<2>(As, Ag, K, 0, tid);
  stage_half<NLB>(Bs, Bg, K, 0, tid);
  stage_half<2>(As + AHALF, Ag, K, 32, tid);
  stage_half<NLB>(Bs + BHALF, Bg, K, 32, tid);
  stage_half<2>(As + ASLOT, Ag, K, 64, tid);
  stage_half<NLB>(Bs + BSLOT, Bg, K, 64, tid);
  waitvm<2 * PAIR>();
  __builtin_amdgcn_s_barrier();

  const f32x4 fz = {0.f, 0.f, 0.f, 0.f};
  f32x4 acc[8][NI];
#pragma unroll
  for (int i = 0; i < 8; i++)
#pragma unroll
    for (int j = 0; j < NI; j++) acc[i][j] = fz;
  s16x8 afr[4], bfr[NI];
  int g = lane >> 4;
  int rA = (lane & 15) + wm * 128;
  int rB = (lane & 15) + wn * 64;

  for (int kt = 0; kt < NT; kt++) {
    int cur = kt & 1;
    char* Acur = As + cur * ASLOT;
    char* Bcur = Bs + cur * BSLOT;
    char* Anxt = As + (cur ^ 1) * ASLOT;
    char* Bnxt = Bs + (cur ^ 1) * BSLOT;
#pragma unroll
    for (int ni = 0; ni < NI; ni++) bfr[ni] = ldsfrag(Bcur, rB + ni * 16, g);
#pragma unroll
    for (int mi = 0; mi < 4; mi++) afr[mi] = ldsfrag(Acur, rA + mi * 16, g);
    if (kt + 1 < NT) stage_half<2>(Anxt + AHALF, Ag, K, (kt + 1) * 64 + 32, tid);
    __builtin_amdgcn_s_barrier();
    asm volatile("s_waitcnt lgkmcnt(0)" ::: "memory");
    __builtin_amdgcn_s_setprio(1);
#pragma unroll
    for (int mi = 0; mi < 4; mi++)
#pragma unroll
      for (int ni = 0; ni < NI; ni++)
        acc[mi][ni] = __builtin_amdgcn_mfma_f32_16x16x32_bf16(afr[mi], bfr[ni], acc[mi][ni], 0, 0, 0);
    __builtin_amdgcn_s_setprio(0);
    __builtin_amdgcn_s_barrier();
#pragma unroll
    for (int mi = 0; mi < 4; mi++) afr[mi] = ldsfrag(Acur, rA + 64 + mi * 16, g);
    if (kt + 1 < NT) stage_half<NLB>(Bnxt + BHALF, Bg, K, (kt + 1) * 64 + 32, tid);
    __builtin_amdgcn_s_barrier();
    asm volatile("s_waitcnt lgkmcnt(0)" ::: "memory");
    __builtin_amdgcn_s_setprio(1);
#pragma unroll
    for (int mi = 0; mi < 4; mi++)
#pragma unroll
      for (int ni = 0; ni < NI; ni++)
        acc[4 + mi][ni] = __builtin_amdgcn_mfma_f32_16x16x32_bf16(afr[mi], bfr[ni], acc[4 + mi][ni], 0, 0, 0);
    __builtin_amdgcn_s_setprio(0);
    if (kt + 1 < NT) waitvm<2 * PAIR>();
    else             waitvm<0>();
    __builtin_amdgcn_s_barrier();
#pragma unroll
    for (int ni = 0; ni < NI; ni++) bfr[ni] = ldsfrag(Bcur + BHALF, rB + ni * 16, g);
#pragma unroll
    for (int mi = 0; mi < 4; mi++) afr[mi] = ldsfrag(Acur + AHALF, rA + mi * 16, g);
    if (kt + 2 < NT) stage_half<2>(Acur, Ag, K, (kt + 2) * 64, tid);
    __builtin_amdgcn_s_barrier();
    asm volatile("s_waitcnt lgkmcnt(0)" ::: "memory");
    __builtin_amdgcn_s_setprio(1);
#pragma unroll
    for (int mi = 0; mi < 4; mi++)
#pragma unroll
      for (int ni = 0; ni < NI; ni++)
        acc[mi][ni] = __builtin_amdgcn_mfma_f32_16x16x32_bf16(afr[mi], bfr[ni], acc[mi][ni], 0, 0, 0);
    __builtin_amdgcn_s_setprio(0);
    __builtin_amdgcn_s_barrier();
#pragma unroll
    for (int mi = 0; mi < 4; mi++) afr[mi] = ldsfrag(Acur + AHALF, rA + 64 + mi * 16, g);
    if (kt + 2 < NT) stage_half<NLB>(Bcur, Bg, K, (kt + 2) * 64, tid);
    __builtin_amdgcn_s_barrier();
    asm volatile("s_waitcnt lgkmcnt(0)" ::: "memory");
    __builtin_amdgcn_s_setprio(1);
#pragma unroll
    for (int mi = 0; mi < 4; mi++)
#pragma unroll
      for (int ni = 0; ni < NI; ni++)
        acc[4 + mi][ni] = __builtin_amdgcn_mfma_f32_16x16x32_bf16(afr[mi], bfr[ni], acc[4 + mi][ni], 0, 0, 0);
    __builtin_amdgcn_s_setprio(0);
    if (kt < NT - 1) {
      if (kt + 2 < NT) waitvm<2 * PAIR>();
      else             waitvm<PAIR>();
    }
    __builtin_amdgcn_s_barrier();
  }

  // ---- fused epilogue v2 ------------------------------------------------
  int h = bn;
  float* qbuf = (float*)lds;                    // 256 rows x 128 f32, granule-swizzled
  float* ssqb = (float*)(lds + 131072);         // [2][256] partial sum-of-squares
  int q15 = lane & 15;
  if (wn < 2) {
    float ps[8][4];
#pragma unroll
    for (int mi = 0; mi < 8; mi++)
#pragma unroll
      for (int j = 0; j < 4; j++) {
        float s = 0.f;
#pragma unroll
        for (int ni = 0; ni < NI; ni++) { float v = acc[mi][ni][j]; s += v * v; }
        ps[mi][j] = s;
      }
#pragma unroll
    for (int d = 1; d < 16; d <<= 1)
#pragma unroll
      for (int mi = 0; mi < 8; mi++)
#pragma unroll
        for (int j = 0; j < 4; j++) ps[mi][j] += __shfl_xor(ps[mi][j], d);
#pragma unroll
    for (int mi = 0; mi < 8; mi++)
#pragma unroll
      for (int ni = 0; ni < NI; ni++) {
        int rl0 = wm * 128 + mi * 16 + ((lane >> 4) << 2);
        int c = wn * 64 + ni * 16 + q15;
        int gr = c >> 4;
#pragma unroll
        for (int j = 0; j < 4; j++) {
          int rl = rl0 + j;
          qbuf[rl * 128 + (((gr ^ ((rl >> 2) & 7)) << 4) | (c & 15))] = acc[mi][ni][j];
        }
      }
    if (q15 == 0) {
#pragma unroll
      for (int mi = 0; mi < 8; mi++)
#pragma unroll
        for (int j = 0; j < 4; j++) {
          int rl = wm * 128 + mi * 16 + (g << 2) + j;
          ssqb[wn * 256 + rl] = ps[mi][j];
        }
    }
  } else {
#pragma unroll
    for (int mi = 0; mi < 8; mi++)
#pragma unroll
      for (int ni = 0; ni < NI; ni++) {
        int row0 = m0 + wm * 128 + mi * 16 + ((lane >> 4) << 2);
        int d = (wn - 2) * 64 + ni * 16 + q15;
#pragma unroll
        for (int j = 0; j < 4; j++) {
          int bb = (row0 + j) >> 11, s = (row0 + j) & 2047;
          float gv = acc[mi][ni][j];
          Gs[((size_t)(bb * SS + s)) * (HH * DD) + h * DD + d] =
              f2bf(1.f / (1.f + __expf(-gv)));
        }
      }
  }
  __syncthreads();
  float qwl = qw[lane], qwh = qw[64 + lane];
  const float SC = 0.08838834764831845f * 1.4426950408889634f;
#pragma unroll 4
  for (int r2 = 0; r2 < 32; r2++) {
    int rl = w * 32 + r2;
    int row0 = m0 + rl;
    int bb = row0 >> 11, s = row0 & 2047;
    int swz = ((rl >> 2) & 7) << 4;
    int cl = lane, ch = 64 + lane;
    float xlo = qbuf[rl * 128 + ((((cl >> 4) << 4) ^ swz) | (cl & 15))];
    float xhi = qbuf[rl * 128 + ((((ch >> 4) << 4) ^ swz) | (ch & 15))];
    float ss2 = ssqb[rl] + ssqb[256 + rl];
    float r = rsqrtf(ss2 * (1.f / 128.f) + 1e-6f);
    float qlo = xlo * r * (1.f + qwl);
    float qhi = xhi * r * (1.f + qwh);
    const float* cs = rope + (size_t)s * 256;
    float clo = cs[lane], chi = cs[64 + lane];
    float slo = cs[128 + lane], shi = cs[192 + lane];
    float olo = (qlo * clo - qhi * slo) * SC;
    float ohi = (qhi * chi + qlo * shi) * SC;
    size_t qoff = (((size_t)bb * HH + h) * SS + s) * DD;
    Qb[qoff + lane] = f2bf(olo);
    Qb[qoff + 64 + lane] = f2bf(ohi);
  }
}

// ---------------------------------------------------------------- KV projection GEMM v2 (8 waves)
// 512 threads, 8 waves as 2 M-rows x 4 N-cols (64x32 out per wave, acc[4][2]).
// Grid 256 = 1 block/CU but 2 waves/SIMD (the proven m97 overlap regime).
// bn 0..3 = K head -> fused RMSNorm+RoPE -> Kb (bf16) + present-K (f32).
// bn 4..7 = V-heads -> present (f32) + Vtb (bf16) from registers.
__global__ __launch_bounds__(512) void gemm_kv(const u16t* __restrict__ A,
                                               const u16t* __restrict__ Bt,
                                               const float* __restrict__ rope,
                                               const float* __restrict__ kw,
                                               u16t* __restrict__ Kb,
                                               float* __restrict__ present,
                                               u16t* __restrict__ Vtb,
                                               int K) {
  extern __shared__ __align__(16) char lds[];
  char* As = lds;            // 8KB (128 rows x 64B)
  char* Bs = lds + 8192;     // 8KB
  int tid = threadIdx.x;
  int lane = tid & 63;
  int w = tid >> 6;                          // 0..7
  int cpx = gridDim.x >> 3;
  int wgid = ((int)blockIdx.x & 7) * cpx + ((int)blockIdx.x >> 3);
  const int mtiles = MM >> 7;                 // 32
  int bm = wgid % mtiles;
  int bn = wgid / mtiles;                     // 0..7
  int m0 = bm << 7, n0 = bn << 7;
  int wr = (w >> 2) * 64, wc = (w & 3) * 32;  // 2x4 wave map

  const f32x4 fz = {0.f, 0.f, 0.f, 0.f};
  f32x4 acc[4][2];
#pragma unroll
  for (int i = 0; i < 4; i++)
#pragma unroll
    for (int j = 0; j < 2; j++) acc[i][j] = fz;

  for (int k0 = 0; k0 < K; k0 += 32) {
    __syncthreads();
    {
      int idx = tid;                          // 512 x 16B = 8KB: one round each
      int r = idx >> 2, c = idx & 3;
      int csrc = c ^ ((r >> 1) & 3);
      gload_lds16(A + (size_t)(m0 + r) * K + k0 + csrc * 8, As + idx * 16);
      gload_lds16(Bt + (size_t)(n0 + r) * K + k0 + csrc * 8, Bs + idx * 16);
    }
    __syncthreads();
    s16x8 af[4], bf[2];
    int g = lane >> 4;
#pragma unroll
    for (int mi = 0; mi < 4; mi++) {
      int r = wr + mi * 16 + (lane & 15);
      af[mi] = *(const s16x8*)(As + r * 64 + ((g ^ ((r >> 1) & 3)) << 4));
    }
#pragma unroll
    for (int ni = 0; ni < 2; ni++) {
      int r = wc + ni * 16 + (lane & 15);
      bf[ni] = *(const s16x8*)(Bs + r * 64 + ((g ^ ((r >> 1) & 3)) << 4));
    }
#pragma unroll
    for (int mi = 0; mi < 4; mi++)
#pragma unroll
      for (int ni = 0; ni < 2; ni++)
        acc[mi][ni] = __builtin_amdgcn_mfma_f32_16x16x32_bf16(af[mi], bf[ni], acc[mi][ni], 0, 0, 0);
  }
  if (bn < 4) {
    // ---- fused K epilogue: RMSNorm + RoPE (head kv = bn) ----
    int kv = bn;
    int q15 = lane & 15, g = lane >> 4;
    __syncthreads();                        // protect As/Bs before reuse as kbuf
    float* kbuf = (float*)lds;              // 128 rows x 128 f32 (64KB), granule-swz
    float* ssqb = (float*)(lds + 65536);    // [4][128] quarter-column partials
    float ps[4][4];
#pragma unroll
    for (int mi = 0; mi < 4; mi++)
#pragma unroll
      for (int j = 0; j < 4; j++) {
        float s = 0.f;
#pragma unroll
        for (int ni = 0; ni < 2; ni++) { float v = acc[mi][ni][j]; s += v * v; }
        ps[mi][j] = s;
      }
#pragma unroll
    for (int d = 1; d < 16; d <<= 1)
#pragma unroll
      for (int mi = 0; mi < 4; mi++)
#pragma unroll
        for (int j = 0; j < 4; j++) ps[mi][j] += __shfl_xor(ps[mi][j], d);
#pragma unroll
    for (int mi = 0; mi < 4; mi++)
#pragma unroll
      for (int ni = 0; ni < 2; ni++) {
        int rl0 = wr + mi * 16 + (g << 2);
        int c = wc + ni * 16 + q15;
        int gr = c >> 4;
#pragma unroll
        for (int j = 0; j < 4; j++) {
          int rl = rl0 + j;
          kbuf[rl * 128 + (((gr ^ ((rl >> 2) & 7)) << 4) | (c & 15))] = acc[mi][ni][j];
        }
      }
    if (q15 == 0) {
#pragma unroll
      for (int mi = 0; mi < 4; mi++)
#pragma unroll
        for (int j = 0; j < 4; j++) {
          int rl = wr + mi * 16 + (g << 2) + j;
          ssqb[(w & 3) * 128 + rl] = ps[mi][j];
        }
    }
    __syncthreads();
    float kwl = kw[lane], kwh = kw[64 + lane];
#pragma unroll 4
    for (int r2 = 0; r2 < 16; r2++) {
      int rl = w * 16 + r2;                 // 8 waves x 16 rows = 128
      int row0 = m0 + rl;
      int bb = row0 >> 11, s = row0 & 2047;
      int swz = ((rl >> 2) & 7) << 4;
      int cl = lane, ch = 64 + lane;
      float xlo = kbuf[rl * 128 + ((((cl >> 4) << 4) ^ swz) | (cl & 15))];
      float xhi = kbuf[rl * 128 + ((((ch >> 4) << 4) ^ swz) | (ch & 15))];
      float ss2 = ssqb[rl] + ssqb[128 + rl] + ssqb[256 + rl] + ssqb[384 + rl];
      float r = rsqrtf(ss2 * (1.f / 128.f) + 1e-6f);
      float klo = xlo * r * (1.f + kwl);
      float khi = xhi * r * (1.f + kwh);
      const float* cs = rope + (size_t)s * 256;
      float clo = cs[lane], chi = cs[64 + lane];
      float slo = cs[128 + lane], shi = cs[192 + lane];
      float olo = klo * clo - khi * slo;       // K is NOT pre-scaled
      float ohi = khi * chi + klo * shi;
      size_t koff = (((size_t)bb * KVH + kv) * SS + s) * DD;
      Kb[koff + lane] = f2bf(olo);
      Kb[koff + 64 + lane] = f2bf(ohi);
      size_t poff = (((size_t)(bb * 2 * KVH + kv)) * SS + s) * DD;
      present[poff + lane] = olo;
      present[poff + 64 + lane] = ohi;
    }
  } else {
#pragma unroll
    for (int mi = 0; mi < 4; mi++)
#pragma unroll
      for (int ni = 0; ni < 2; ni++) {
        int row0 = m0 + wr + mi * 16 + ((lane >> 4) << 2);
        int vcol = (n0 - 512) + wc + ni * 16 + (lane & 15);
        int kv = vcol >> 7, d = vcol & 127;
        int bb = row0 >> 11, sp = row0 & 2047;
        size_t pbase = (((size_t)(bb * 2 * KVH + KVH + kv)) * SS + sp) * DD + d;
#pragma unroll
        for (int j = 0; j < 4; j++)
          present[pbase + (size_t)j * DD] = acc[mi][ni][j];
        s16x4 pk;
        pk[0] = (short)f2bf(acc[mi][ni][0]);
        pk[1] = (short)f2bf(acc[mi][ni][1]);
        pk[2] = (short)f2bf(acc[mi][ni][2]);
        pk[3] = (short)f2bf(acc[mi][ni][3]);
        *(s16x4*)(Vtb + ((size_t)(bb * KVH + kv) * DD + d) * SS + sp) = pk;
      }
  }
}

// ---------------------------------------------------------------- flash attention v5.3
// Round-12 v5.1 structure + T5 setprio around MFMA clusters (waves within a tile
// run QK->softmax->PV unsynchronized, 2 blocks/CU -> phase diversity to arbitrate;
// m191-regime) + rcp instead of per-element divide in the epilogue.
__global__ __launch_bounds__(256, 2) void attn_kernel(const u16t* __restrict__ Qb,   // (B,H,S,D) pre-scaled
                                                      const u16t* __restrict__ Kb,   // (B,KV,S,D)
                                                      const u16t* __restrict__ Vtb,  // (B,KV,D,S)
                                                      const u16t* __restrict__ Gs,   // (B,S,H*D)
                                                      u16t* __restrict__ AttG) {     // (B,S,H*D)
  __shared__ __align__(16) char Ks[2 * 16384];  // 64 rows x 256B, chunk xor (r&7)
  __shared__ __align__(16) char Vs[2 * 16384];  // V^T: 128 rows x 128B, chunk xor (d&7)
  __shared__ __align__(16) char Ps[4 * 2048];   // per-wave P: [q:16][k-granule xor (q&7)]

  int tid = threadIdx.x, lane = tid & 63, w = tid >> 6;
  int x = blockIdx.x & 7;          // XCD grouping: each XCD owns one (b,kv)
  int b = x >> 2, kv = x & 3;
  int rr = blockIdx.x >> 3;        // 0..63
  int h = kv * 4 + (rr & 3);
  int p = rr >> 2;                 // 0..15: pair {31-p, p}

  const u16t* Kbase = Kb + (((size_t)(b * KVH + kv)) * SS) * DD;
  const u16t* Vbase = Vtb + (((size_t)(b * KVH + kv)) * DD) * SS;

  auto stageK = [&](int kt, int buf) {
#pragma unroll
    for (int i = 0; i < 4; i++) {
      int idx = i * 256 + tid;
      int r_ = idx >> 4, c_ = idx & 15;
      gload_lds16(Kbase + (size_t)(kt * 64 + r_) * DD + (c_ ^ (r_ & 7)) * 8,
                  Ks + buf * 16384 + idx * 16);
    }
  };
  auto stageV = [&](int kt, int buf) {
#pragma unroll
    for (int i = 0; i < 4; i++) {
      int idx = i * 256 + tid;
      int r_ = idx >> 3, c_ = idx & 7;
      gload_lds16(Vbase + (size_t)r_ * SS + kt * 64 + (c_ ^ (r_ & 7)) * 8,
                  Vs + buf * 16384 + idx * 16);
    }
  };

  const f32x4 fz = {0.f, 0.f, 0.f, 0.f};
  int g = lane >> 4;
  int q15 = lane & 15;
  int q7 = q15 & 7;
  char* pq = Ps + w * 2048 + q15 * 128;   // this lane's q-row in P
  int cur = 0;

  int ka[4][4];
#pragma unroll
  for (int ni = 0; ni < 4; ni++)
#pragma unroll
    for (int ks = 0; ks < 4; ks++)
      ka[ni][ks] = (ni * 16 + q15) * 256 + (((ks * 4 + g) ^ q7) << 4);
  int va[2][8];
#pragma unroll
  for (int ks2 = 0; ks2 < 2; ks2++)
#pragma unroll
    for (int f = 0; f < 8; f++)
      va[ks2][f] = (f * 16 + q15) * 128 + (((ks2 * 4 + g) ^ q7) << 4);
  int pr_[2];
#pragma unroll
  for (int ks2 = 0; ks2 < 2; ks2++) pr_[ks2] = ((ks2 * 4 + g) ^ q7) << 4;
  int pw_[4];
#pragma unroll
  for (int ni = 0; ni < 4; ni++)
    pw_[ni] = (((ni * 2 + (g >> 1)) ^ q7) << 4) + ((g & 1) << 3);

  stageK(0, 0);
  stageV(0, 0);

  for (int seg = 0; seg < 2; seg++) {
    int qt = (seg == 0) ? (31 - p) : p;
    const u16t* Qbase = Qb + (((size_t)(b * HH + h)) * SS + qt * 64) * DD;
    s16x8 qf[4];
    {
      const u16t* qrow = Qbase + (size_t)(w * 16 + q15) * DD + g * 8;
#pragma unroll
      for (int ks = 0; ks < 4; ks++) qf[ks] = *(const s16x8*)(qrow + ks * 32);
    }
    f32x4 acco[8];
#pragma unroll
    for (int f = 0; f < 8; f++) acco[f] = fz;
    float mrun = -INFINITY, lrun = 0.f;

    if (seg == 0) {
      asm volatile("s_waitcnt vmcnt(0)" ::: "memory");
      __builtin_amdgcn_s_barrier();
    }

    for (int kt = 0; kt <= qt; kt++) {
      bool havenext = (kt < qt) || (seg == 0);
      if (havenext) {
        int nk = (kt < qt) ? (kt + 1) : 0;
        stageK(nk, cur ^ 1);
        stageV(nk, cur ^ 1);
      }
      const char* kc = Ks + (cur << 14);
      const char* vc = Vs + (cur << 14);
      f32x4 accs[4];
#pragma unroll
      for (int ni = 0; ni < 4; ni++) accs[ni] = fz;
      __builtin_amdgcn_s_setprio(1);
#pragma unroll
      for (int ni = 0; ni < 4; ni++)
#pragma unroll
        for (int ks = 0; ks < 4; ks++) {
          s16x8 bfk = *(const s16x8*)(kc + ka[ni][ks]);
          accs[ni] = __builtin_amdgcn_mfma_f32_16x16x32_bf16(bfk, qf[ks], accs[ni], 0, 0, 0);
        }
      __builtin_amdgcn_s_setprio(0);
      if (kt == qt) {
        int ql = w * 16 + q15;
#pragma unroll
        for (int ni = 0; ni < 4; ni++)
#pragma unroll
          for (int j = 0; j < 4; j++) {
            int kl = ni * 16 + (g << 2) + j;
            if (kl > ql) accs[ni][j] = -1e30f;
          }
      }
      f32x4 m4 = fmax4(fmax4(accs[0], accs[1]), fmax4(accs[2], accs[3]));
      float mt = fmaxf(fmaxf(m4[0], m4[1]), fmaxf(m4[2], m4[3]));
      mt = fmaxf(mt, __shfl_xor(mt, 16));
      mt = fmaxf(mt, __shfl_xor(mt, 32));
      float mnew = fmaxf(mrun, mt);
      float alpha = __builtin_amdgcn_exp2f(mrun - mnew);
      mrun = mnew;
#pragma unroll
      for (int ni = 0; ni < 4; ni++)
#pragma unroll
        for (int j = 0; j < 4; j++)
          accs[ni][j] = __builtin_amdgcn_exp2f(accs[ni][j] - mnew);
      f32x4 s4 = (accs[0] + accs[1]) + (accs[2] + accs[3]);
      float rs = (s4[0] + s4[1]) + (s4[2] + s4[3]);
      rs += __shfl_xor(rs, 16);
      rs += __shfl_xor(rs, 32);
      lrun = lrun * alpha + rs;
      float ar[4];
#pragma unroll
      for (int j = 0; j < 4; j++) ar[j] = __shfl(alpha, (g << 2) + j);
#pragma unroll
      for (int f = 0; f < 8; f++)
#pragma unroll
        for (int j = 0; j < 4; j++) acco[f][j] *= ar[j];

#pragma unroll
      for (int ni = 0; ni < 4; ni++) {
        uint2 pk;
        pk.x = cvtpk_bf16(accs[ni][0], accs[ni][1]);
        pk.y = cvtpk_bf16(accs[ni][2], accs[ni][3]);
        *(uint2*)(pq + pw_[ni]) = pk;
      }
      __builtin_amdgcn_s_setprio(1);
#pragma unroll
      for (int ks2 = 0; ks2 < 2; ks2++) {
        s16x8 pa = *(const s16x8*)(pq + pr_[ks2]);
#pragma unroll
        for (int f = 0; f < 8; f++) {
          s16x8 vf = *(const s16x8*)(vc + va[ks2][f]);
          acco[f] = __builtin_amdgcn_mfma_f32_16x16x32_bf16(pa, vf, acco[f], 0, 0, 0);
        }
      }
      __builtin_amdgcn_s_setprio(0);
      if (havenext) {
        asm volatile("s_waitcnt vmcnt(0)" ::: "memory");
        __builtin_amdgcn_s_barrier();
        cur ^= 1;
      }
    }
    float lr[4], ri[4];
#pragma unroll
    for (int j = 0; j < 4; j++) {
      lr[j] = __shfl(lrun, (g << 2) + j);
      ri[j] = __builtin_amdgcn_rcpf(lr[j]);
    }
#pragma unroll
    for (int f = 0; f < 8; f++) {
      int d = f * 16 + q15;
#pragma unroll
      for (int j = 0; j < 4; j++) {
        int srow = qt * 64 + w * 16 + (g << 2) + j;
        float o = acco[f][j] * ri[j];
        size_t off = ((size_t)b * SS + srow) * (HH * DD) + h * DD + d;
        float gt = bf2f(Gs[off]);
        AttG[off] = f2bf(o * gt);
      }
    }
  }
}

// ---------------------------------------------------------------- launcher
extern "C" void kernel_launch(void* const* d_in, const int* in_sizes, int n_in,
                              void* d_out, int out_size, void* d_ws, size_t ws_size,
                              hipStream_t stream) {
  const float* hidden = (const float*)d_in[0];
  const float* rope   = (const float*)d_in[2];
  const float* Wq     = (const float*)d_in[5];
  const float* Wk     = (const float*)d_in[6];
  const float* Wv     = (const float*)d_in[7];
  const float* Wo     = (const float*)d_in[8];
  const float* qw     = (const float*)d_in[9];
  const float* kw     = (const float*)d_in[10];
  float* out = (float*)d_out;
  float* present = out + (size_t)BB * SS * HIDD; // 8,388,608

  char* ws = (char*)d_ws;
  u16t* Xb    = (u16t*)(ws);                              // 4096x2048 bf16   16.78MB
  u16t* Wt    = (u16t*)(ws + 16777216);                   // 5120x2048 bf16   20.97MB
  u16t* Wot   = (u16t*)(ws + 37748736);                   // 2048x2048 bf16    8.39MB
  u16t* Qb    = (u16t*)(ws + 88080384);                   // (B,H,S,D) bf16   16.78MB
  u16t* Kb    = (u16t*)(ws + 104857600);                  // (B,KV,S,D) bf16   4.19MB
  u16t* Vtb   = (u16t*)(ws + 109051904);                  // (B,KV,D,S) bf16   4.19MB
  u16t* Gs    = (u16t*)(ws + 113246208);                  // (B,S,H*D) bf16   16.78MB
  u16t* AttG  = Xb;  // alias: Xb dead after projections; AttG written by attention

  (void)hipFuncSetAttribute(reinterpret_cast<const void*>(gemm8q),
                            hipFuncAttributeMaxDynamicSharedMemorySize, 133120);
  (void)hipFuncSetAttribute(reinterpret_cast<const void*>(gemm_kv),
                            hipFuncAttributeMaxDynamicSharedMemorySize, 67584);
  (void)hipFuncSetAttribute(reinterpret_cast<const void*>(gemm8<128, float>),
                            hipFuncAttributeMaxDynamicSharedMemorySize, 98304);

  // 1+2. fused prep: cast hidden + weight transposes
  prep_all<<<4096 + 3584, 256, 0, stream>>>(hidden, Wq, Wk, Wv, Wo, Xb, Wt, Wot);
  // 3a. Q projection + fused RMSNorm/RoPE/gate: grid 256 = 1 block/CU
  gemm8q<<<(MM / 256) * (4096 / 256), 512, 133120, stream>>>(Xb, Wt, rope, qw, Qb, Gs, HIDD);
  // 3b. K+V projection v2 (8 waves = 2 waves/SIMD) with fused K-norm/rope + V epilogues
  gemm_kv<<<(MM / 128) * (1024 / 128), 512, 67584, stream>>>(
      Xb, Wt + (size_t)4096 * HIDD, rope, kw, Kb, present, Vtb, HIDD);
  // 4. flash attention v5.3 (T5 setprio + rcp epilogue)
  attn_kernel<<<BB * HH * (SS / 128), 256, 0, stream>>>(Qb, Kb, Vtb, Gs, AttG);
  // 5. output projection -> d_out: 256x128 8-phase, grid 16x16 = 256 = 1 block/CU
  gemm8<128, float><<<(MM / 256) * (HIDD / 128), 512, 98304, stream>>>(AttG, Wot, out, MM, HIDD, HIDD);
}

// Round 22
// 248.007 us; speedup vs baseline: 1.1168x; 1.0025x over previous
//
#include <hip/hip_runtime.h>
#include <hip/hip_bf16.h>
#include <cstdint>
#include <cstddef>

// Problem constants
#define BB   2
#define SS   2048
#define HIDD 2048
#define HH   16
#define KVH  4
#define DD   128
#define NQKV 5120   // H*2*D + KV*D + KV*D = 4096 + 512 + 512
#define MM   4096   // B*S

typedef unsigned short u16t;
typedef __attribute__((ext_vector_type(8))) short s16x8;
typedef __attribute__((ext_vector_type(4))) short s16x4;
typedef __attribute__((ext_vector_type(4))) float f32x4;

__device__ __forceinline__ u16t f2bf(float f) {
  unsigned u = __float_as_uint(f);
  u += 0x7fffu + ((u >> 16) & 1u);
  return (u16t)(u >> 16);
}
__device__ __forceinline__ float bf2f(u16t h) {
  return __uint_as_float(((unsigned)h) << 16);
}
__device__ __forceinline__ void gload_lds16(const void* g, void* l) {
  __builtin_amdgcn_global_load_lds(
      (const __attribute__((address_space(1))) unsigned int*)g,
      (__attribute__((address_space(3))) unsigned int*)l, 16, 0, 0);
}
__device__ __forceinline__ unsigned cvtpk_bf16(float lo, float hi) {
  unsigned r;
  asm("v_cvt_pk_bf16_f32 %0, %1, %2" : "=v"(r) : "v"(lo), "v"(hi));
  return r;
}
__device__ __forceinline__ f32x4 fmax4(f32x4 a, f32x4 b) {
  f32x4 r;
  r[0] = fmaxf(a[0], b[0]); r[1] = fmaxf(a[1], b[1]);
  r[2] = fmaxf(a[2], b[2]); r[3] = fmaxf(a[3], b[3]);
  return r;
}
// counted vmcnt via literal asm (compiler-ordering fence through "memory" clobber).
// Round-11/14 lessons: __builtin_amdgcn_s_waitcnt is NOT a memory fence; and
// defer-max (T13) breaks correctness on this pipelined structure -- banned.
template <int N>
__device__ __forceinline__ void waitvm() {
  static_assert(N == 0 || N == 3 || N == 4 || N == 6 || N == 8, "add literal");
  if constexpr (N == 0)      asm volatile("s_waitcnt vmcnt(0)" ::: "memory");
  else if constexpr (N == 3) asm volatile("s_waitcnt vmcnt(3)" ::: "memory");
  else if constexpr (N == 4) asm volatile("s_waitcnt vmcnt(4)" ::: "memory");
  else if constexpr (N == 6) asm volatile("s_waitcnt vmcnt(6)" ::: "memory");
  else if constexpr (N == 8) asm volatile("s_waitcnt vmcnt(8)" ::: "memory");
}

// ----------------------------------------- fused prep: cast hidden + transpose-cast all weights
// blocks [0,4096): cast hidden f32->bf16, 8 elem/thread (s16x8 stores)
// blocks [4096, ...): 64x64 transpose-cast tiles; loads vectorized f32x4 (16B/lane),
// LDS stores at stride 65 (65 mod 32 = 1 -> bank-safe), output stores s16x8.
__global__ __launch_bounds__(256) void prep_all(const float* __restrict__ hidden,
                                                const float* __restrict__ Wq,
                                                const float* __restrict__ Wk,
                                                const float* __restrict__ Wv,
                                                const float* __restrict__ Wo,
                                                u16t* __restrict__ Xb,
                                                u16t* __restrict__ Wt,
                                                u16t* __restrict__ Wot) {
  __shared__ float lds[64 * 65];
  int bid = blockIdx.x;
  int t = threadIdx.x;
  if (bid < 4096) {
    size_t i = ((size_t)bid * 256 + t) * 8;
    f32x4 v0 = *(const f32x4*)(hidden + i);
    f32x4 v1 = *(const f32x4*)(hidden + i + 4);
    s16x8 o;
    o[0] = (short)f2bf(v0[0]); o[1] = (short)f2bf(v0[1]);
    o[2] = (short)f2bf(v0[2]); o[3] = (short)f2bf(v0[3]);
    o[4] = (short)f2bf(v1[0]); o[5] = (short)f2bf(v1[1]);
    o[6] = (short)f2bf(v1[2]); o[7] = (short)f2bf(v1[3]);
    *(s16x8*)(Xb + i) = o;
    return;
  }
  bid -= 4096;
  const float* src; u16t* dst; int N;
  if (bid < 2048)      { src = Wq; dst = Wt;                         N = 4096; }
  else if (bid < 2304) { src = Wk; dst = Wt + (size_t)4096 * HIDD;   N = 512;  bid -= 2048; }
  else if (bid < 2560) { src = Wv; dst = Wt + (size_t)4608 * HIDD;   N = 512;  bid -= 2304; }
  else                 { src = Wo; dst = Wot;                        N = 2048; bid -= 2560; }
  const int ktiles = HIDD / 64; // 32
  int n0 = (bid / ktiles) << 6;
  int k0 = (bid % ktiles) << 6;
  // load 64x64 f32 tile with f32x4: idx over 64 rows x 16 chunks
#pragma unroll
  for (int i = 0; i < 4; i++) {
    int idx = i * 256 + t;
    int r = idx >> 4, c4 = (idx & 15) << 2;
    f32x4 v = *(const f32x4*)(src + (size_t)(k0 + r) * N + n0 + c4);
#pragma unroll
    for (int e = 0; e < 4; e++) lds[(c4 + e) * 65 + r] = v[e];
  }
  __syncthreads();
#pragma unroll
  for (int i = 0; i < 2; i++) {
    int idx = i * 256 + t;
    int rr = idx >> 3, k8 = (idx & 7) * 8;
    s16x8 o;
#pragma unroll
    for (int e = 0; e < 8; e++) o[e] = (short)f2bf(lds[rr * 65 + k8 + e]);
    *(s16x8*)(dst + (size_t)(n0 + rr) * HIDD + k0 + k8) = o;
  }
}

// ---------------------------------------------------------------- shared GEMM pieces
__device__ __forceinline__ s16x8 ldsfrag(const char* half, int r, int g) {
  return *(const s16x8*)(half + r * 64 + ((g ^ ((r >> 1) & 3)) << 4));
}
template <int NL>
__device__ __forceinline__ void stage_half(char* ldsbase, const u16t* gbase,
                                           int K, int kcol, int tid) {
#pragma unroll
  for (int i = 0; i < NL; i++) {
    int o16 = i * 512 + tid;
    int r = o16 >> 2;
    int cs = (o16 & 3) ^ ((r >> 1) & 3);
    gload_lds16(gbase + (size_t)r * K + kcol + cs * 8, ldsbase + o16 * 16);
  }
}

// ---------------------------------------------------------------- 256xBN 8-phase bf16 GEMM
// (used for O-proj with BN=128). grid = (M/256)*(n/BN); M/256 must be 16.
template <int BN, typename CT>
__global__ __launch_bounds__(512, 2) void gemm8(const u16t* __restrict__ A,
                                                const u16t* __restrict__ Bt,
                                                CT* __restrict__ C,
                                                int M, int N, int K) {
  constexpr int NLB = BN / 128;            // B-half loads/thread
  constexpr int AHALF = 16384, ASLOT = 32768;
  constexpr int BHALF = BN * 64, BSLOT = 2 * BHALF;
  constexpr int PAIR = 2 + NLB;            // loads per (A,B) half-tile pair
  constexpr int NI = BN / 64;              // B frags per wave
  extern __shared__ __align__(16) char lds[];
  char* As = lds;
  char* Bs = lds + 2 * ASLOT;
  int tid = threadIdx.x, lane = tid & 63, w = tid >> 6;
  int wm = w >> 2, wn = w & 3;
  int cpx = gridDim.x >> 3;                       // grid % 8 == 0
  int wgid = (blockIdx.x & 7) * cpx + (blockIdx.x >> 3);
  int bm = wgid & 15, bn = wgid >> 4;             // M/256 == 16
  int m0 = bm << 8, n0 = bn * BN;
  const u16t* Ag = A + (size_t)m0 * K;
  const u16t* Bg = Bt + (size_t)n0 * K;
  const int NT = K >> 6;

  stage_half<2>(As, Ag, K, 0, tid);
  stage_half<NLB>(Bs, Bg, K, 0, tid);
  stage_half<2>(As + AHALF, Ag, K, 32, tid);
  stage_half<NLB>(Bs + BHALF, Bg, K, 32, tid);
  stage_half<2>(As + ASLOT, Ag, K, 64, tid);
  stage_half<NLB>(Bs + BSLOT, Bg, K, 64, tid);
  waitvm<2 * PAIR>();
  __builtin_amdgcn_s_barrier();

  const f32x4 fz = {0.f, 0.f, 0.f, 0.f};
  f32x4 acc[8][NI];
#pragma unroll
  for (int i = 0; i < 8; i++)
#pragma unroll
    for (int j = 0; j < NI; j++) acc[i][j] = fz;
  s16x8 afr[4], bfr[NI];
  int g = lane >> 4;
  int rA = (lane & 15) + wm * 128;
  int rB = (lane & 15) + wn * (BN / 4);

  for (int kt = 0; kt < NT; kt++) {
    int cur = kt & 1;
    char* Acur = As + cur * ASLOT;
    char* Bcur = Bs + cur * BSLOT;
    char* Anxt = As + (cur ^ 1) * ASLOT;
    char* Bnxt = Bs + (cur ^ 1) * BSLOT;
#pragma unroll
    for (int ni = 0; ni < NI; ni++) bfr[ni] = ldsfrag(Bcur, rB + ni * 16, g);
#pragma unroll
    for (int mi = 0; mi < 4; mi++) afr[mi] = ldsfrag(Acur, rA + mi * 16, g);
    if (kt + 1 < NT) stage_half<2>(Anxt + AHALF, Ag, K, (kt + 1) * 64 + 32, tid);
    __builtin_amdgcn_s_barrier();
    asm volatile("s_waitcnt lgkmcnt(0)" ::: "memory");
    __builtin_amdgcn_s_setprio(1);
#pragma unroll
    for (int mi = 0; mi < 4; mi++)
#pragma unroll
      for (int ni = 0; ni < NI; ni++)
        acc[mi][ni] = __builtin_amdgcn_mfma_f32_16x16x32_bf16(afr[mi], bfr[ni], acc[mi][ni], 0, 0, 0);
    __builtin_amdgcn_s_setprio(0);
    __builtin_amdgcn_s_barrier();
#pragma unroll
    for (int mi = 0; mi < 4; mi++) afr[mi] = ldsfrag(Acur, rA + 64 + mi * 16, g);
    if (kt + 1 < NT) stage_half<NLB>(Bnxt + BHALF, Bg, K, (kt + 1) * 64 + 32, tid);
    __builtin_amdgcn_s_barrier();
    asm volatile("s_waitcnt lgkmcnt(0)" ::: "memory");
    __builtin_amdgcn_s_setprio(1);
#pragma unroll
    for (int mi = 0; mi < 4; mi++)
#pragma unroll
      for (int ni = 0; ni < NI; ni++)
        acc[4 + mi][ni] = __builtin_amdgcn_mfma_f32_16x16x32_bf16(afr[mi], bfr[ni], acc[4 + mi][ni], 0, 0, 0);
    __builtin_amdgcn_s_setprio(0);
    if (kt + 1 < NT) waitvm<2 * PAIR>();
    else             waitvm<0>();
    __builtin_amdgcn_s_barrier();
#pragma unroll
    for (int ni = 0; ni < NI; ni++) bfr[ni] = ldsfrag(Bcur + BHALF, rB + ni * 16, g);
#pragma unroll
    for (int mi = 0; mi < 4; mi++) afr[mi] = ldsfrag(Acur + AHALF, rA + mi * 16, g);
    if (kt + 2 < NT) stage_half<2>(Acur, Ag, K, (kt + 2) * 64, tid);
    __builtin_amdgcn_s_barrier();
    asm volatile("s_waitcnt lgkmcnt(0)" ::: "memory");
    __builtin_amdgcn_s_setprio(1);
#pragma unroll
    for (int mi = 0; mi < 4; mi++)
#pragma unroll
      for (int ni = 0; ni < NI; ni++)
        acc[mi][ni] = __builtin_amdgcn_mfma_f32_16x16x32_bf16(afr[mi], bfr[ni], acc[mi][ni], 0, 0, 0);
    __builtin_amdgcn_s_setprio(0);
    __builtin_amdgcn_s_barrier();
#pragma unroll
    for (int mi = 0; mi < 4; mi++) afr[mi] = ldsfrag(Acur + AHALF, rA + 64 + mi * 16, g);
    if (kt + 2 < NT) stage_half<NLB>(Bcur, Bg, K, (kt + 2) * 64, tid);
    __builtin_amdgcn_s_barrier();
    asm volatile("s_waitcnt lgkmcnt(0)" ::: "memory");
    __builtin_amdgcn_s_setprio(1);
#pragma unroll
    for (int mi = 0; mi < 4; mi++)
#pragma unroll
      for (int ni = 0; ni < NI; ni++)
        acc[4 + mi][ni] = __builtin_amdgcn_mfma_f32_16x16x32_bf16(afr[mi], bfr[ni], acc[4 + mi][ni], 0, 0, 0);
    __builtin_amdgcn_s_setprio(0);
    if (kt < NT - 1) {
      if (kt + 2 < NT) waitvm<2 * PAIR>();
      else             waitvm<PAIR>();
    }
    __builtin_amdgcn_s_barrier();
  }
#pragma unroll
  for (int mi = 0; mi < 8; mi++)
#pragma unroll
    for (int ni = 0; ni < NI; ni++) {
      int row0 = m0 + wm * 128 + mi * 16 + ((lane >> 4) << 2);
      int col = n0 + wn * (BN / 4) + ni * 16 + (lane & 15);
#pragma unroll
      for (int j = 0; j < 4; j++) {
        if constexpr (sizeof(CT) == 2)
          C[(size_t)(row0 + j) * N + col] = f2bf(acc[mi][ni][j]);
        else
          C[(size_t)(row0 + j) * N + col] = acc[mi][ni][j];
      }
    }
}

// ---------------------------------------------------------------- Q projection GEMM + fused norm/rope/gate
// BN=256: each block's 256-col tile = one head's [query(0..127) | gate(128..255)].
// Epilogue v2: register ssq + q15 butterflies -> ssqb; qbuf LDS round-trip; per-row
// norm+rope with no shuffles.
__global__ __launch_bounds__(512, 2) void gemm8q(const u16t* __restrict__ A,
                                                 const u16t* __restrict__ Bt,
                                                 const float* __restrict__ rope,
                                                 const float* __restrict__ qw,
                                                 u16t* __restrict__ Qb,   // (B,H,S,D)
                                                 u16t* __restrict__ Gs,   // (B,S,H*D)
                                                 int K) {
  constexpr int NLB = 2, AHALF = 16384, ASLOT = 32768;
  constexpr int BHALF = 16384, BSLOT = 32768;
  constexpr int PAIR = 4, NI = 4;
  extern __shared__ __align__(16) char lds[];
  char* As = lds;
  char* Bs = lds + 2 * ASLOT;
  int tid = threadIdx.x, lane = tid & 63, w = tid >> 6;
  int wm = w >> 2, wn = w & 3;
  int cpx = gridDim.x >> 3;
  int wgid = (blockIdx.x & 7) * cpx + (blockIdx.x >> 3);
  int bm = wgid & 15, bn = wgid >> 4;             // bn = head h
  int m0 = bm << 8, n0 = bn << 8;
  const u16t* Ag = A + (size_t)m0 * K;
  const u16t* Bg = Bt + (size_t)n0 * K;
  const int NT = K >> 6;

  stage_half<2>(As, Ag, K, 0, tid);
  stage_half<NLB>(Bs, Bg, K, 0, tid);
  stage_half<2>(As + AHALF, Ag, K, 32, tid);
  stage_half<NLB>(Bs + BHALF, Bg, K, 32, tid);
  stage_half<2>(As + ASLOT, Ag, K, 64, tid);
  stage_half<NLB>(Bs + BSLOT, Bg, K, 64, tid);
  waitvm<2 * PAIR>();
  __builtin_amdgcn_s_barrier();

  const f32x4 fz = {0.f, 0.f, 0.f, 0.f};
  f32x4 acc[8][NI];
#pragma unroll
  for (int i = 0; i < 8; i++)
#pragma unroll
    for (int j = 0; j < NI; j++) acc[i][j] = fz;
  s16x8 afr[4], bfr[NI];
  int g = lane >> 4;
  int rA = (lane & 15) + wm * 128;
  int rB = (lane & 15) + wn * 64;

  for (int kt = 0; kt < NT; kt++) {
    int cur = kt & 1;
    char* Acur = As + cur * ASLOT;
    char* Bcur = Bs + cur * BSLOT;
    char* Anxt = As + (cur ^ 1) * ASLOT;
    char* Bnxt = Bs + (cur ^ 1) * BSLOT;
#pragma unroll
    for (int ni = 0; ni < NI; ni++) bfr[ni] = ldsfrag(Bcur, rB + ni * 16, g);
#pragma unroll
    for (int mi = 0; mi < 4; mi++) afr[mi] = ldsfrag(Acur, rA + mi * 16, g);
    if (kt + 1 < NT) stage_half<2>(Anxt + AHALF, Ag, K, (kt + 1) * 64 + 32, tid);
    __builtin_amdgcn_s_barrier();
    asm volatile("s_waitcnt lgkmcnt(0)" ::: "memory");
    __builtin_amdgcn_s_setprio(1);
#pragma unroll
    for (int mi = 0; mi < 4; mi++)
#pragma unroll
      for (int ni = 0; ni < NI; ni++)
        acc[mi][ni] = __builtin_amdgcn_mfma_f32_16x16x32_bf16(afr[mi], bfr[ni], acc[mi][ni], 0, 0, 0);
    __builtin_amdgcn_s_setprio(0);
    __builtin_amdgcn_s_barrier();
#pragma unroll
    for (int mi = 0; mi < 4; mi++) afr[mi] = ldsfrag(Acur, rA + 64 + mi * 16, g);
    if (kt + 1 < NT) stage_half<NLB>(Bnxt + BHALF, Bg, K, (kt + 1) * 64 + 32, tid);
    __builtin_amdgcn_s_barrier();
    asm volatile("s_waitcnt lgkmcnt(0)" ::: "memory");
    __builtin_amdgcn_s_setprio(1);
#pragma unroll
    for (int mi = 0; mi < 4; mi++)
#pragma unroll
      for (int ni = 0; ni < NI; ni++)
        acc[4 + mi][ni] = __builtin_amdgcn_mfma_f32_16x16x32_bf16(afr[mi], bfr[ni], acc[4 + mi][ni], 0, 0, 0);
    __builtin_amdgcn_s_setprio(0);
    if (kt + 1 < NT) waitvm<2 * PAIR>();
    else             waitvm<0>();
    __builtin_amdgcn_s_barrier();
#pragma unroll
    for (int ni = 0; ni < NI; ni++) bfr[ni] = ldsfrag(Bcur + BHALF, rB + ni * 16, g);
#pragma unroll
    for (int mi = 0; mi < 4; mi++) afr[mi] = ldsfrag(Acur + AHALF, rA + mi * 16, g);
    if (kt + 2 < NT) stage_half<2>(Acur, Ag, K, (kt + 2) * 64, tid);
    __builtin_amdgcn_s_barrier();
    asm volatile("s_waitcnt lgkmcnt(0)" ::: "memory");
    __builtin_amdgcn_s_setprio(1);
#pragma unroll
    for (int mi = 0; mi < 4; mi++)
#pragma unroll
      for (int ni = 0; ni < NI; ni++)
        acc[mi][ni] = __builtin_amdgcn_mfma_f32_16x16x32_bf16(afr[mi], bfr[ni], acc[mi][ni], 0, 0, 0);
    __builtin_amdgcn_s_setprio(0);
    __builtin_amdgcn_s_barrier();
#pragma unroll
    for (int mi = 0; mi < 4; mi++) afr[mi] = ldsfrag(Acur + AHALF, rA + 64 + mi * 16, g);
    if (kt + 2 < NT) stage_half<NLB>(Bcur, Bg, K, (kt + 2) * 64, tid);
    __builtin_amdgcn_s_barrier();
    asm volatile("s_waitcnt lgkmcnt(0)" ::: "memory");
    __builtin_amdgcn_s_setprio(1);
#pragma unroll
    for (int mi = 0; mi < 4; mi++)
#pragma unroll
      for (int ni = 0; ni < NI; ni++)
        acc[4 + mi][ni] = __builtin_amdgcn_mfma_f32_16x16x32_bf16(afr[mi], bfr[ni], acc[4 + mi][ni], 0, 0, 0);
    __builtin_amdgcn_s_setprio(0);
    if (kt < NT - 1) {
      if (kt + 2 < NT) waitvm<2 * PAIR>();
      else             waitvm<PAIR>();
    }
    __builtin_amdgcn_s_barrier();
  }

  // ---- fused epilogue v2 ------------------------------------------------
  int h = bn;
  float* qbuf = (float*)lds;                    // 256 rows x 128 f32, granule-swizzled
  float* ssqb = (float*)(lds + 131072);         // [2][256] partial sum-of-squares
  int q15 = lane & 15;
  if (wn < 2) {
    float ps[8][4];
#pragma unroll
    for (int mi = 0; mi < 8; mi++)
#pragma unroll
      for (int j = 0; j < 4; j++) {
        float s = 0.f;
#pragma unroll
        for (int ni = 0; ni < NI; ni++) { float v = acc[mi][ni][j]; s += v * v; }
        ps[mi][j] = s;
      }
#pragma unroll
    for (int d = 1; d < 16; d <<= 1)
#pragma unroll
      for (int mi = 0; mi < 8; mi++)
#pragma unroll
        for (int j = 0; j < 4; j++) ps[mi][j] += __shfl_xor(ps[mi][j], d);
#pragma unroll
    for (int mi = 0; mi < 8; mi++)
#pragma unroll
      for (int ni = 0; ni < NI; ni++) {
        int rl0 = wm * 128 + mi * 16 + ((lane >> 4) << 2);
        int c = wn * 64 + ni * 16 + q15;
        int gr = c >> 4;
#pragma unroll
        for (int j = 0; j < 4; j++) {
          int rl = rl0 + j;
          qbuf[rl * 128 + (((gr ^ ((rl >> 2) & 7)) << 4) | (c & 15))] = acc[mi][ni][j];
        }
      }
    if (q15 == 0) {
#pragma unroll
      for (int mi = 0; mi < 8; mi++)
#pragma unroll
        for (int j = 0; j < 4; j++) {
          int rl = wm * 128 + mi * 16 + (g << 2) + j;
          ssqb[wn * 256 + rl] = ps[mi][j];
        }
    }
  } else {
#pragma unroll
    for (int mi = 0; mi < 8; mi++)
#pragma unroll
      for (int ni = 0; ni < NI; ni++) {
        int row0 = m0 + wm * 128 + mi * 16 + ((lane >> 4) << 2);
        int d = (wn - 2) * 64 + ni * 16 + q15;
#pragma unroll
        for (int j = 0; j < 4; j++) {
          int bb = (row0 + j) >> 11, s = (row0 + j) & 2047;
          float gv = acc[mi][ni][j];
          Gs[((size_t)(bb * SS + s)) * (HH * DD) + h * DD + d] =
              f2bf(1.f / (1.f + __expf(-gv)));
        }
      }
  }
  __syncthreads();
  float qwl = qw[lane], qwh = qw[64 + lane];
  const float SC = 0.08838834764831845f * 1.4426950408889634f;
#pragma unroll 4
  for (int r2 = 0; r2 < 32; r2++) {
    int rl = w * 32 + r2;
    int row0 = m0 + rl;
    int bb = row0 >> 11, s = row0 & 2047;
    int swz = ((rl >> 2) & 7) << 4;
    int cl = lane, ch = 64 + lane;
    float xlo = qbuf[rl * 128 + ((((cl >> 4) << 4) ^ swz) | (cl & 15))];
    float xhi = qbuf[rl * 128 + ((((ch >> 4) << 4) ^ swz) | (ch & 15))];
    float ss2 = ssqb[rl] + ssqb[256 + rl];
    float r = rsqrtf(ss2 * (1.f / 128.f) + 1e-6f);
    float qlo = xlo * r * (1.f + qwl);
    float qhi = xhi * r * (1.f + qwh);
    const float* cs = rope + (size_t)s * 256;
    float clo = cs[lane], chi = cs[64 + lane];
    float slo = cs[128 + lane], shi = cs[192 + lane];
    float olo = (qlo * clo - qhi * slo) * SC;
    float ohi = (qhi * chi + qlo * shi) * SC;
    size_t qoff = (((size_t)bb * HH + h) * SS + s) * DD;
    Qb[qoff + lane] = f2bf(olo);
    Qb[qoff + 64 + lane] = f2bf(ohi);
  }
}

// ---------------------------------------------------------------- KV projection GEMM v2 (8 waves)
// 512 threads, 8 waves as 2 M-rows x 4 N-cols (64x32 out per wave, acc[4][2]).
// Grid 256 = 1 block/CU but 2 waves/SIMD (the proven m97 overlap regime).
// bn 0..3 = K head -> fused RMSNorm+RoPE -> Kb (bf16) + present-K (f32).
// bn 4..7 = V-heads -> present (f32) + Vtb (bf16) from registers.
__global__ __launch_bounds__(512) void gemm_kv(const u16t* __restrict__ A,
                                               const u16t* __restrict__ Bt,
                                               const float* __restrict__ rope,
                                               const float* __restrict__ kw,
                                               u16t* __restrict__ Kb,
                                               float* __restrict__ present,
                                               u16t* __restrict__ Vtb,
                                               int K) {
  extern __shared__ __align__(16) char lds[];
  char* As = lds;            // 8KB (128 rows x 64B)
  char* Bs = lds + 8192;     // 8KB
  int tid = threadIdx.x;
  int lane = tid & 63;
  int w = tid >> 6;                          // 0..7
  int cpx = gridDim.x >> 3;
  int wgid = ((int)blockIdx.x & 7) * cpx + ((int)blockIdx.x >> 3);
  const int mtiles = MM >> 7;                 // 32
  int bm = wgid % mtiles;
  int bn = wgid / mtiles;                     // 0..7
  int m0 = bm << 7, n0 = bn << 7;
  int wr = (w >> 2) * 64, wc = (w & 3) * 32;  // 2x4 wave map

  const f32x4 fz = {0.f, 0.f, 0.f, 0.f};
  f32x4 acc[4][2];
#pragma unroll
  for (int i = 0; i < 4; i++)
#pragma unroll
    for (int j = 0; j < 2; j++) acc[i][j] = fz;

  for (int k0 = 0; k0 < K; k0 += 32) {
    __syncthreads();
    {
      int idx = tid;                          // 512 x 16B = 8KB: one round each
      int r = idx >> 2, c = idx & 3;
      int csrc = c ^ ((r >> 1) & 3);
      gload_lds16(A + (size_t)(m0 + r) * K + k0 + csrc * 8, As + idx * 16);
      gload_lds16(Bt + (size_t)(n0 + r) * K + k0 + csrc * 8, Bs + idx * 16);
    }
    __syncthreads();
    s16x8 af[4], bf[2];
    int g = lane >> 4;
#pragma unroll
    for (int mi = 0; mi < 4; mi++) {
      int r = wr + mi * 16 + (lane & 15);
      af[mi] = *(const s16x8*)(As + r * 64 + ((g ^ ((r >> 1) & 3)) << 4));
    }
#pragma unroll
    for (int ni = 0; ni < 2; ni++) {
      int r = wc + ni * 16 + (lane & 15);
      bf[ni] = *(const s16x8*)(Bs + r * 64 + ((g ^ ((r >> 1) & 3)) << 4));
    }
#pragma unroll
    for (int mi = 0; mi < 4; mi++)
#pragma unroll
      for (int ni = 0; ni < 2; ni++)
        acc[mi][ni] = __builtin_amdgcn_mfma_f32_16x16x32_bf16(af[mi], bf[ni], acc[mi][ni], 0, 0, 0);
  }
  if (bn < 4) {
    // ---- fused K epilogue: RMSNorm + RoPE (head kv = bn) ----
    int kv = bn;
    int q15 = lane & 15, g = lane >> 4;
    __syncthreads();                        // protect As/Bs before reuse as kbuf
    float* kbuf = (float*)lds;              // 128 rows x 128 f32 (64KB), granule-swz
    float* ssqb = (float*)(lds + 65536);    // [4][128] quarter-column partials
    float ps[4][4];
#pragma unroll
    for (int mi = 0; mi < 4; mi++)
#pragma unroll
      for (int j = 0; j < 4; j++) {
        float s = 0.f;
#pragma unroll
        for (int ni = 0; ni < 2; ni++) { float v = acc[mi][ni][j]; s += v * v; }
        ps[mi][j] = s;
      }
#pragma unroll
    for (int d = 1; d < 16; d <<= 1)
#pragma unroll
      for (int mi = 0; mi < 4; mi++)
#pragma unroll
        for (int j = 0; j < 4; j++) ps[mi][j] += __shfl_xor(ps[mi][j], d);
#pragma unroll
    for (int mi = 0; mi < 4; mi++)
#pragma unroll
      for (int ni = 0; ni < 2; ni++) {
        int rl0 = wr + mi * 16 + (g << 2);
        int c = wc + ni * 16 + q15;
        int gr = c >> 4;
#pragma unroll
        for (int j = 0; j < 4; j++) {
          int rl = rl0 + j;
          kbuf[rl * 128 + (((gr ^ ((rl >> 2) & 7)) << 4) | (c & 15))] = acc[mi][ni][j];
        }
      }
    if (q15 == 0) {
#pragma unroll
      for (int mi = 0; mi < 4; mi++)
#pragma unroll
        for (int j = 0; j < 4; j++) {
          int rl = wr + mi * 16 + (g << 2) + j;
          ssqb[(w & 3) * 128 + rl] = ps[mi][j];
        }
    }
    __syncthreads();
    float kwl = kw[lane], kwh = kw[64 + lane];
#pragma unroll 4
    for (int r2 = 0; r2 < 16; r2++) {
      int rl = w * 16 + r2;                 // 8 waves x 16 rows = 128
      int row0 = m0 + rl;
      int bb = row0 >> 11, s = row0 & 2047;
      int swz = ((rl >> 2) & 7) << 4;
      int cl = lane, ch = 64 + lane;
      float xlo = kbuf[rl * 128 + ((((cl >> 4) << 4) ^ swz) | (cl & 15))];
      float xhi = kbuf[rl * 128 + ((((ch >> 4) << 4) ^ swz) | (ch & 15))];
      float ss2 = ssqb[rl] + ssqb[128 + rl] + ssqb[256 + rl] + ssqb[384 + rl];
      float r = rsqrtf(ss2 * (1.f / 128.f) + 1e-6f);
      float klo = xlo * r * (1.f + kwl);
      float khi = xhi * r * (1.f + kwh);
      const float* cs = rope + (size_t)s * 256;
      float clo = cs[lane], chi = cs[64 + lane];
      float slo = cs[128 + lane], shi = cs[192 + lane];
      float olo = klo * clo - khi * slo;       // K is NOT pre-scaled
      float ohi = khi * chi + klo * shi;
      size_t koff = (((size_t)bb * KVH + kv) * SS + s) * DD;
      Kb[koff + lane] = f2bf(olo);
      Kb[koff + 64 + lane] = f2bf(ohi);
      size_t poff = (((size_t)(bb * 2 * KVH + kv)) * SS + s) * DD;
      present[poff + lane] = olo;
      present[poff + 64 + lane] = ohi;
    }
  } else {
#pragma unroll
    for (int mi = 0; mi < 4; mi++)
#pragma unroll
      for (int ni = 0; ni < 2; ni++) {
        int row0 = m0 + wr + mi * 16 + ((lane >> 4) << 2);
        int vcol = (n0 - 512) + wc + ni * 16 + (lane & 15);
        int kv = vcol >> 7, d = vcol & 127;
        int bb = row0 >> 11, sp = row0 & 2047;
        size_t pbase = (((size_t)(bb * 2 * KVH + KVH + kv)) * SS + sp) * DD + d;
#pragma unroll
        for (int j = 0; j < 4; j++)
          present[pbase + (size_t)j * DD] = acc[mi][ni][j];
        s16x4 pk;
        pk[0] = (short)f2bf(acc[mi][ni][0]);
        pk[1] = (short)f2bf(acc[mi][ni][1]);
        pk[2] = (short)f2bf(acc[mi][ni][2]);
        pk[3] = (short)f2bf(acc[mi][ni][3]);
        *(s16x4*)(Vtb + ((size_t)(bb * KVH + kv) * DD + d) * SS + sp) = pk;
      }
  }
}

// ---------------------------------------------------------------- flash attention v5.3
// Round-12 v5.1 structure + T5 setprio around MFMA clusters + rcp epilogue.
__global__ __launch_bounds__(256, 2) void attn_kernel(const u16t* __restrict__ Qb,   // (B,H,S,D) pre-scaled
                                                      const u16t* __restrict__ Kb,   // (B,KV,S,D)
                                                      const u16t* __restrict__ Vtb,  // (B,KV,D,S)
                                                      const u16t* __restrict__ Gs,   // (B,S,H*D)
                                                      u16t* __restrict__ AttG) {     // (B,S,H*D)
  __shared__ __align__(16) char Ks[2 * 16384];  // 64 rows x 256B, chunk xor (r&7)
  __shared__ __align__(16) char Vs[2 * 16384];  // V^T: 128 rows x 128B, chunk xor (d&7)
  __shared__ __align__(16) char Ps[4 * 2048];   // per-wave P: [q:16][k-granule xor (q&7)]

  int tid = threadIdx.x, lane = tid & 63, w = tid >> 6;
  int x = blockIdx.x & 7;          // XCD grouping: each XCD owns one (b,kv)
  int b = x >> 2, kv = x & 3;
  int rr = blockIdx.x >> 3;        // 0..63
  int h = kv * 4 + (rr & 3);
  int p = rr >> 2;                 // 0..15: pair {31-p, p}

  const u16t* Kbase = Kb + (((size_t)(b * KVH + kv)) * SS) * DD;
  const u16t* Vbase = Vtb + (((size_t)(b * KVH + kv)) * DD) * SS;

  auto stageK = [&](int kt, int buf) {
#pragma unroll
    for (int i = 0; i < 4; i++) {
      int idx = i * 256 + tid;
      int r_ = idx >> 4, c_ = idx & 15;
      gload_lds16(Kbase + (size_t)(kt * 64 + r_) * DD + (c_ ^ (r_ & 7)) * 8,
                  Ks + buf * 16384 + idx * 16);
    }
  };
  auto stageV = [&](int kt, int buf) {
#pragma unroll
    for (int i = 0; i < 4; i++) {
      int idx = i * 256 + tid;
      int r_ = idx >> 3, c_ = idx & 7;
      gload_lds16(Vbase + (size_t)r_ * SS + kt * 64 + (c_ ^ (r_ & 7)) * 8,
                  Vs + buf * 16384 + idx * 16);
    }
  };

  const f32x4 fz = {0.f, 0.f, 0.f, 0.f};
  int g = lane >> 4;
  int q15 = lane & 15;
  int q7 = q15 & 7;
  char* pq = Ps + w * 2048 + q15 * 128;   // this lane's q-row in P
  int cur = 0;

  int ka[4][4];
#pragma unroll
  for (int ni = 0; ni < 4; ni++)
#pragma unroll
    for (int ks = 0; ks < 4; ks++)
      ka[ni][ks] = (ni * 16 + q15) * 256 + (((ks * 4 + g) ^ q7) << 4);
  int va[2][8];
#pragma unroll
  for (int ks2 = 0; ks2 < 2; ks2++)
#pragma unroll
    for (int f = 0; f < 8; f++)
      va[ks2][f] = (f * 16 + q15) * 128 + (((ks2 * 4 + g) ^ q7) << 4);
  int pr_[2];
#pragma unroll
  for (int ks2 = 0; ks2 < 2; ks2++) pr_[ks2] = ((ks2 * 4 + g) ^ q7) << 4;
  int pw_[4];
#pragma unroll
  for (int ni = 0; ni < 4; ni++)
    pw_[ni] = (((ni * 2 + (g >> 1)) ^ q7) << 4) + ((g & 1) << 3);

  stageK(0, 0);
  stageV(0, 0);

  for (int seg = 0; seg < 2; seg++) {
    int qt = (seg == 0) ? (31 - p) : p;
    const u16t* Qbase = Qb + (((size_t)(b * HH + h)) * SS + qt * 64) * DD;
    s16x8 qf[4];
    {
      const u16t* qrow = Qbase + (size_t)(w * 16 + q15) * DD + g * 8;
#pragma unroll
      for (int ks = 0; ks < 4; ks++) qf[ks] = *(const s16x8*)(qrow + ks * 32);
    }
    f32x4 acco[8];
#pragma unroll
    for (int f = 0; f < 8; f++) acco[f] = fz;
    float mrun = -INFINITY, lrun = 0.f;

    if (seg == 0) {
      asm volatile("s_waitcnt vmcnt(0)" ::: "memory");
      __builtin_amdgcn_s_barrier();
    }

    for (int kt = 0; kt <= qt; kt++) {
      bool havenext = (kt < qt) || (seg == 0);
      if (havenext) {
        int nk = (kt < qt) ? (kt + 1) : 0;
        stageK(nk, cur ^ 1);
        stageV(nk, cur ^ 1);
      }
      const char* kc = Ks + (cur << 14);
      const char* vc = Vs + (cur << 14);
      f32x4 accs[4];
#pragma unroll
      for (int ni = 0; ni < 4; ni++) accs[ni] = fz;
      __builtin_amdgcn_s_setprio(1);
#pragma unroll
      for (int ni = 0; ni < 4; ni++)
#pragma unroll
        for (int ks = 0; ks < 4; ks++) {
          s16x8 bfk = *(const s16x8*)(kc + ka[ni][ks]);
          accs[ni] = __builtin_amdgcn_mfma_f32_16x16x32_bf16(bfk, qf[ks], accs[ni], 0, 0, 0);
        }
      __builtin_amdgcn_s_setprio(0);
      if (kt == qt) {
        int ql = w * 16 + q15;
#pragma unroll
        for (int ni = 0; ni < 4; ni++)
#pragma unroll
          for (int j = 0; j < 4; j++) {
            int kl = ni * 16 + (g << 2) + j;
            if (kl > ql) accs[ni][j] = -1e30f;
          }
      }
      f32x4 m4 = fmax4(fmax4(accs[0], accs[1]), fmax4(accs[2], accs[3]));
      float mt = fmaxf(fmaxf(m4[0], m4[1]), fmaxf(m4[2], m4[3]));
      mt = fmaxf(mt, __shfl_xor(mt, 16));
      mt = fmaxf(mt, __shfl_xor(mt, 32));
      float mnew = fmaxf(mrun, mt);
      float alpha = __builtin_amdgcn_exp2f(mrun - mnew);
      mrun = mnew;
#pragma unroll
      for (int ni = 0; ni < 4; ni++)
#pragma unroll
        for (int j = 0; j < 4; j++)
          accs[ni][j] = __builtin_amdgcn_exp2f(accs[ni][j] - mnew);
      f32x4 s4 = (accs[0] + accs[1]) + (accs[2] + accs[3]);
      float rs = (s4[0] + s4[1]) + (s4[2] + s4[3]);
      rs += __shfl_xor(rs, 16);
      rs += __shfl_xor(rs, 32);
      lrun = lrun * alpha + rs;
      float ar[4];
#pragma unroll
      for (int j = 0; j < 4; j++) ar[j] = __shfl(alpha, (g << 2) + j);
#pragma unroll
      for (int f = 0; f < 8; f++)
#pragma unroll
        for (int j = 0; j < 4; j++) acco[f][j] *= ar[j];

#pragma unroll
      for (int ni = 0; ni < 4; ni++) {
        uint2 pk;
        pk.x = cvtpk_bf16(accs[ni][0], accs[ni][1]);
        pk.y = cvtpk_bf16(accs[ni][2], accs[ni][3]);
        *(uint2*)(pq + pw_[ni]) = pk;
      }
      __builtin_amdgcn_s_setprio(1);
#pragma unroll
      for (int ks2 = 0; ks2 < 2; ks2++) {
        s16x8 pa = *(const s16x8*)(pq + pr_[ks2]);
#pragma unroll
        for (int f = 0; f < 8; f++) {
          s16x8 vf = *(const s16x8*)(vc + va[ks2][f]);
          acco[f] = __builtin_amdgcn_mfma_f32_16x16x32_bf16(pa, vf, acco[f], 0, 0, 0);
        }
      }
      __builtin_amdgcn_s_setprio(0);
      if (havenext) {
        asm volatile("s_waitcnt vmcnt(0)" ::: "memory");
        __builtin_amdgcn_s_barrier();
        cur ^= 1;
      }
    }
    float lr[4], ri[4];
#pragma unroll
    for (int j = 0; j < 4; j++) {
      lr[j] = __shfl(lrun, (g << 2) + j);
      ri[j] = __builtin_amdgcn_rcpf(lr[j]);
    }
#pragma unroll
    for (int f = 0; f < 8; f++) {
      int d = f * 16 + q15;
#pragma unroll
      for (int j = 0; j < 4; j++) {
        int srow = qt * 64 + w * 16 + (g << 2) + j;
        float o = acco[f][j] * ri[j];
        size_t off = ((size_t)b * SS + srow) * (HH * DD) + h * DD + d;
        float gt = bf2f(Gs[off]);
        AttG[off] = f2bf(o * gt);
      }
    }
  }
}

// ---------------------------------------------------------------- launcher
extern "C" void kernel_launch(void* const* d_in, const int* in_sizes, int n_in,
                              void* d_out, int out_size, void* d_ws, size_t ws_size,
                              hipStream_t stream) {
  const float* hidden = (const float*)d_in[0];
  const float* rope   = (const float*)d_in[2];
  const float* Wq     = (const float*)d_in[5];
  const float* Wk     = (const float*)d_in[6];
  const float* Wv     = (const float*)d_in[7];
  const float* Wo     = (const float*)d_in[8];
  const float* qw     = (const float*)d_in[9];
  const float* kw     = (const float*)d_in[10];
  float* out = (float*)d_out;
  float* present = out + (size_t)BB * SS * HIDD; // 8,388,608

  char* ws = (char*)d_ws;
  u16t* Xb    = (u16t*)(ws);                              // 4096x2048 bf16   16.78MB
  u16t* Wt    = (u16t*)(ws + 16777216);                   // 5120x2048 bf16   20.97MB
  u16t* Wot   = (u16t*)(ws + 37748736);                   // 2048x2048 bf16    8.39MB
  u16t* Qb    = (u16t*)(ws + 88080384);                   // (B,H,S,D) bf16   16.78MB
  u16t* Kb    = (u16t*)(ws + 104857600);                  // (B,KV,S,D) bf16   4.19MB
  u16t* Vtb   = (u16t*)(ws + 109051904);                  // (B,KV,D,S) bf16   4.19MB
  u16t* Gs    = (u16t*)(ws + 113246208);                  // (B,S,H*D) bf16   16.78MB
  u16t* AttG  = Xb;  // alias: Xb dead after projections; AttG written by attention

  (void)hipFuncSetAttribute(reinterpret_cast<const void*>(gemm8q),
                            hipFuncAttributeMaxDynamicSharedMemorySize, 133120);
  (void)hipFuncSetAttribute(reinterpret_cast<const void*>(gemm_kv),
                            hipFuncAttributeMaxDynamicSharedMemorySize, 67584);
  (void)hipFuncSetAttribute(reinterpret_cast<const void*>(gemm8<128, float>),
                            hipFuncAttributeMaxDynamicSharedMemorySize, 98304);

  // 1+2. fused prep: cast hidden + weight transposes (f32x4 loads)
  prep_all<<<4096 + 3584, 256, 0, stream>>>(hidden, Wq, Wk, Wv, Wo, Xb, Wt, Wot);
  // 3a. Q projection + fused RMSNorm/RoPE/gate: grid 256 = 1 block/CU
  gemm8q<<<(MM / 256) * (4096 / 256), 512, 133120, stream>>>(Xb, Wt, rope, qw, Qb, Gs, HIDD);
  // 3b. K+V projection v2 (8 waves = 2 waves/SIMD) with fused K-norm/rope + V epilogues
  gemm_kv<<<(MM / 128) * (1024 / 128), 512, 67584, stream>>>(
      Xb, Wt + (size_t)4096 * HIDD, rope, kw, Kb, present, Vtb, HIDD);
  // 4. flash attention v5.3 (T5 setprio + rcp epilogue)
  attn_kernel<<<BB * HH * (SS / 128), 256, 0, stream>>>(Qb, Kb, Vtb, Gs, AttG);
  // 5. output projection -> d_out: 256x128 8-phase, grid 16x16 = 256 = 1 block/CU
  gemm8<128, float><<<(MM / 256) * (HIDD / 128), 512, 98304, stream>>>(AttG, Wot, out, MM, HIDD, HIDD);
}